// Round 1
// baseline (1065.140 us; speedup 1.0000x reference)
//
#include <hip/hip_runtime.h>
#include <hip/hip_bf16.h>

#define B_    2
#define CIN_  5
#define H_    160
#define W_    160
#define N_    25600        // H*W
#define D_    48
#define NW_   32
#define WS_   800
#define HEADS_ 3
#define DH_   24
#define INNER_ 72
#define O3_   216

// ---------------- K0: e_diag / f_diag precompute ----------------
__global__ void k_diag(const float* __restrict__ Em, const float* __restrict__ Fm,
                       const float* __restrict__ we, const float* __restrict__ be,
                       const float* __restrict__ wf, const float* __restrict__ bf,
                       float* __restrict__ diag) {
    int t = threadIdx.x;
    if (t < 72) {
        int h = t / 24, d = t % 24;
        float se = be[d], sf = bf[d];
        for (int w = 0; w < 30; ++w) {
            se += Em[(h*24+d)*30 + w] * we[d*30 + w];
            sf += Fm[(h*24+d)*30 + w] * wf[d*30 + w];
        }
        diag[t]      = se;
        diag[72 + t] = sf;
    }
}

// ---------------- K1: conv3x3 + PReLU -> seqT [B,N,D] ----------------
__global__ __launch_bounds__(256) void k_conv(const float* __restrict__ x,
                                              const float* __restrict__ cw,
                                              const float* __restrict__ cb,
                                              const float* __restrict__ pa,
                                              float* __restrict__ seqT) {
    __shared__ float T[64][49];
    __shared__ float cwL[48*45];
    __shared__ float cbL[48];
    int t  = threadIdx.x;
    int blk = blockIdx.x;              // 0..799
    int b  = blk / 400;
    int n0 = (blk % 400) * 64;
    for (int f = t; f < 48*45; f += 256) cwL[f] = cw[f];
    if (t < 48) cbL[t] = cb[t];
    __syncthreads();

    int px = t & 63;
    int wv = t >> 6;                   // 0..3, handles oc [wv*12, wv*12+12)
    int n  = n0 + px;
    int y  = n / W_, xx = n % W_;
    float a = pa[0];

    float patch[45];
    #pragma unroll
    for (int ic = 0; ic < 5; ++ic)
      #pragma unroll
      for (int ky = 0; ky < 3; ++ky)
        #pragma unroll
        for (int kx = 0; kx < 3; ++kx) {
            int yy = y + ky - 1, xc = xx + kx - 1;
            float v = 0.f;
            if (yy >= 0 && yy < H_ && xc >= 0 && xc < W_)
                v = x[((size_t)(b*CIN_ + ic)*H_ + yy)*W_ + xc];
            patch[(ic*3+ky)*3+kx] = v;
        }
    for (int oi = 0; oi < 12; ++oi) {
        int oc = wv*12 + oi;
        float acc = cbL[oc];
        #pragma unroll
        for (int k = 0; k < 45; ++k) acc += patch[k] * cwL[oc*45 + k];
        acc = acc >= 0.f ? acc : a * acc;
        T[px][oc] = acc;
    }
    __syncthreads();
    for (int i = 0; i < 12; ++i) {
        int f = t + i*256;             // < 3072
        int p = f / 48, c = f % 48;
        seqT[(size_t)(b*N_ + n0 + p)*D_ + c] = T[p][c];
    }
}

// ---------------- K2: LN1 + QKV (+ K/V diag scaling) ----------------
__global__ __launch_bounds__(256) void k_ln_qkv(const float* __restrict__ seqT,
                                                const float* __restrict__ wqkv,
                                                const float* __restrict__ g1,
                                                const float* __restrict__ b1,
                                                const float* __restrict__ diag,
                                                float* __restrict__ Qb,
                                                float* __restrict__ Kb,
                                                float* __restrict__ Vb) {
    __shared__ float wqL[216*49];      // padded stride 49 (conflict-free)
    __shared__ float xnL[4][48];
    __shared__ float dg[144];
    __shared__ float gb[96];
    int t = threadIdx.x;
    for (int f = t; f < 216*48; f += 256) wqL[(f/48)*49 + (f%48)] = wqkv[f];
    if (t < 144) dg[t] = diag[t];
    if (t < 48) { gb[t] = g1[t]; gb[48+t] = b1[t]; }
    __syncthreads();

    int wv = t >> 6, lane = t & 63;
    int row0 = blockIdx.x * 16 + wv * 4;
    for (int rr = 0; rr < 4; ++rr) {
        int row = row0 + rr;
        float xv = (lane < 48) ? seqT[(size_t)row*D_ + lane] : 0.f;
        float s = xv, s2 = xv*xv;
        #pragma unroll
        for (int m = 32; m; m >>= 1) { s += __shfl_xor(s, m); s2 += __shfl_xor(s2, m); }
        float mean = s * (1.f/48.f);
        float var  = s2 * (1.f/48.f) - mean*mean;
        float rs   = rsqrtf(var + 1e-5f);
        if (lane < 48) xnL[wv][lane] = (xv - mean) * rs * gb[lane] + gb[48+lane];
        __syncthreads();

        int b = row / N_; int n = row % N_;
        int wwin = n / WS_; int iwin = n % WS_;
        size_t obase = ((size_t)((b*NW_ + wwin)*HEADS_)) * WS_ * DH_;
        #pragma unroll
        for (int rep = 0; rep < 4; ++rep) {
            int o = lane + rep*64;
            if (o < 216) {
                const float* wr = &wqL[o*49];
                float acc = 0.f;
                #pragma unroll
                for (int c = 0; c < 48; ++c) acc += xnL[wv][c] * wr[c];
                int h = o / 72, j = o % 72, part = j / 24, d = j % 24;
                size_t addr = obase + (size_t)h*WS_*DH_ + (size_t)iwin*DH_ + d;
                if      (part == 0) Qb[addr] = acc;
                else if (part == 1) Kb[addr] = acc * dg[h*24 + d];
                else                Vb[addr] = acc * dg[72 + h*24 + d];
            }
        }
        __syncthreads();
    }
}

// ---------------- K3: windowed attention, 1 thread = 1 query row ----------------
__global__ __launch_bounds__(256) void k_attn(const float* __restrict__ Qb,
                                              const float* __restrict__ Kb,
                                              const float* __restrict__ Vb,
                                              float* __restrict__ OWb) {
    int gq = blockIdx.x * 256 + threadIdx.x;   // 0..153599 exactly
    int wh = gq / WS_;                          // window-head 0..191
    int i  = gq % WS_;
    const float4* K4 = (const float4*)(Kb + (size_t)wh * WS_ * DH_);
    const float4* V4 = (const float4*)(Vb + (size_t)wh * WS_ * DH_);
    const float4* Q4 = (const float4*)(Qb + (size_t)wh * WS_ * DH_ + (size_t)i * DH_);
    const float SCALE = 0.20412414523193154f;   // 24^-0.5

    float4 q[6];
    #pragma unroll
    for (int c = 0; c < 6; ++c) {
        q[c] = Q4[c];
        q[c].x *= SCALE; q[c].y *= SCALE; q[c].z *= SCALE; q[c].w *= SCALE;
    }
    float4 o[6];
    #pragma unroll
    for (int c = 0; c < 6; ++c) { o[c].x = 0.f; o[c].y = 0.f; o[c].z = 0.f; o[c].w = 0.f; }
    float l = 0.f;

    #pragma unroll 2
    for (int j = 0; j < WS_; ++j) {
        float s = 0.f;
        #pragma unroll
        for (int c = 0; c < 6; ++c) {
            float4 kv = K4[j*6 + c];
            s += q[c].x*kv.x + q[c].y*kv.y + q[c].z*kv.z + q[c].w*kv.w;
        }
        float p = __expf(s);
        l += p;
        #pragma unroll
        for (int c = 0; c < 6; ++c) {
            float4 vv = V4[j*6 + c];
            o[c].x += p*vv.x; o[c].y += p*vv.y; o[c].z += p*vv.z; o[c].w += p*vv.w;
        }
    }
    float inv = 1.f / l;
    int b = wh / (NW_*HEADS_); int rem = wh % (NW_*HEADS_);
    int wwin = rem / HEADS_;   int h = rem % HEADS_;
    int n = wwin*WS_ + i;
    float4* dst = (float4*)(OWb + (size_t)(b*N_ + n)*INNER_ + h*DH_);
    #pragma unroll
    for (int c = 0; c < 6; ++c) {
        o[c].x *= inv; o[c].y *= inv; o[c].z *= inv; o[c].w *= inv;
        dst[c] = o[c];
    }
}

// ---------------- K4: to_out + residual + LN2 + MLP + residual + final linear ----------------
__global__ __launch_bounds__(256) void k_tail(const float* __restrict__ seqT,
                                              const float* __restrict__ OWb,
                                              const float* __restrict__ w_out,
                                              const float* __restrict__ b_out,
                                              const float* __restrict__ g2,
                                              const float* __restrict__ b2,
                                              const float* __restrict__ fw1,
                                              const float* __restrict__ fb1,
                                              const float* __restrict__ fw2,
                                              const float* __restrict__ fb2,
                                              const float* __restrict__ wfin,
                                              const float* __restrict__ bfin,
                                              float* __restrict__ att1,
                                              float* __restrict__ out2) {
    __shared__ float woL[48*73];
    __shared__ float f1L[48*49];
    __shared__ float f2L[48*49];
    __shared__ float wfL[96*49];
    __shared__ float bo[48], g2L[48], b2L[48], fb1L[48], fb2L[48], bfL[96];
    __shared__ float owL[4][72];
    __shared__ float ynL[4][48];
    __shared__ float h1L[4][48];
    __shared__ float a1L[4][48];
    int t = threadIdx.x;
    for (int f = t; f < 48*72; f += 256) woL[(f/72)*73 + f%72] = w_out[f];
    for (int f = t; f < 48*48; f += 256) {
        f1L[(f/48)*49 + f%48] = fw1[f];
        f2L[(f/48)*49 + f%48] = fw2[f];
    }
    for (int f = t; f < 96*48; f += 256) wfL[(f/48)*49 + f%48] = wfin[f];
    if (t < 48) { bo[t]=b_out[t]; g2L[t]=g2[t]; b2L[t]=b2[t]; fb1L[t]=fb1[t]; fb2L[t]=fb2[t]; }
    if (t < 96) bfL[t] = bfin[t];
    __syncthreads();

    int wv = t >> 6, lane = t & 63;
    int row0 = blockIdx.x*16 + wv*4;
    for (int rr = 0; rr < 4; ++rr) {
        int row = row0 + rr;
        float sv = (lane < 48) ? seqT[(size_t)row*D_ + lane] : 0.f;
        owL[wv][lane] = OWb[(size_t)row*INNER_ + lane];
        if (lane < 8) owL[wv][64+lane] = OWb[(size_t)row*INNER_ + 64 + lane];
        __syncthreads();

        float att = 0.f;
        if (lane < 48) {
            att = bo[lane];
            const float* wr = &woL[lane*73];
            #pragma unroll
            for (int f = 0; f < 72; ++f) att += owL[wv][f] * wr[f];
        }
        float s2 = sv + att;                     // lanes>=48: 0
        float a  = (lane < 48) ? s2 : 0.f;
        float aa = a*a;
        #pragma unroll
        for (int m = 32; m; m >>= 1) { a += __shfl_xor(a, m); aa += __shfl_xor(aa, m); }
        float mean = a * (1.f/48.f);
        float var  = aa * (1.f/48.f) - mean*mean;
        float rs   = rsqrtf(var + 1e-5f);
        if (lane < 48) ynL[wv][lane] = (s2 - mean) * rs * g2L[lane] + b2L[lane];
        __syncthreads();

        if (lane < 48) {
            float h1 = fb1L[lane];
            const float* wr = &f1L[lane*49];
            #pragma unroll
            for (int f = 0; f < 48; ++f) h1 += ynL[wv][f] * wr[f];
            h1 = h1 >= 0.f ? h1 : 0.01f*h1;
            h1L[wv][lane] = h1;
        }
        __syncthreads();

        if (lane < 48) {
            float h2 = fb2L[lane];
            const float* wr = &f2L[lane*49];
            #pragma unroll
            for (int f = 0; f < 48; ++f) h2 += h1L[wv][f] * wr[f];
            float a1 = s2 + h2;
            att1[(size_t)row*D_ + lane] = a1;
            a1L[wv][lane] = a1;
        }
        __syncthreads();

        #pragma unroll
        for (int rep = 0; rep < 2; ++rep) {
            int o = lane + rep*64;
            if (o < 96) {
                float acc = bfL[o];
                const float* wr = &wfL[o*49];
                #pragma unroll
                for (int f = 0; f < 48; ++f) acc += a1L[wv][f] * wr[f];
                out2[(size_t)row*96 + o] = acc;
            }
        }
        __syncthreads();
    }
}

// ---------------- K5: Highpass = seqT*(1+att1), transposed to [B,D,H,W] ----------------
__global__ __launch_bounds__(256) void k_highpass(const float* __restrict__ seqT,
                                                  const float* __restrict__ att1,
                                                  float* __restrict__ out1) {
    __shared__ float T[64][49];
    int blk = blockIdx.x;              // 0..799
    int b  = blk / 400;
    int n0 = (blk % 400) * 64;
    int t  = threadIdx.x;
    for (int i = 0; i < 12; ++i) {
        int f = t + i*256;             // < 3072
        int p = f / 48, c = f % 48;
        size_t idx = (size_t)(b*N_ + n0 + p)*D_ + c;
        T[p][c] = seqT[idx] * (1.f + att1[idx]);
    }
    __syncthreads();
    for (int i = 0; i < 12; ++i) {
        int g = t + i*256;
        int d = g / 64, nl = g % 64;
        out1[((size_t)b*D_ + d)*N_ + n0 + nl] = T[nl][d];
    }
}

extern "C" void kernel_launch(void* const* d_in, const int* in_sizes, int n_in,
                              void* d_out, int out_size, void* d_ws, size_t ws_size,
                              hipStream_t stream) {
    const float* x      = (const float*)d_in[0];
    const float* conv_w = (const float*)d_in[1];
    const float* conv_b = (const float*)d_in[2];
    const float* prelu_a= (const float*)d_in[3];
    const float* ln1_g  = (const float*)d_in[4];
    const float* ln1_b  = (const float*)d_in[5];
    const float* w_qkv  = (const float*)d_in[6];
    const float* E_mat  = (const float*)d_in[7];
    const float* F_mat  = (const float*)d_in[8];
    const float* w_e    = (const float*)d_in[9];
    const float* b_e    = (const float*)d_in[10];
    const float* w_f    = (const float*)d_in[11];
    const float* b_f    = (const float*)d_in[12];
    const float* w_out  = (const float*)d_in[13];
    const float* b_out  = (const float*)d_in[14];
    const float* ln2_g  = (const float*)d_in[15];
    const float* ln2_b  = (const float*)d_in[16];
    const float* ff_w1  = (const float*)d_in[17];
    const float* ff_b1  = (const float*)d_in[18];
    const float* ff_w2  = (const float*)d_in[19];
    const float* ff_b2  = (const float*)d_in[20];
    const float* w_fin  = (const float*)d_in[21];
    const float* b_fin  = (const float*)d_in[22];

    float* ws   = (float*)d_ws;
    float* seqT = ws;                          // 2,457,600
    float* Qb   = seqT + (size_t)B_*N_*D_;     // 3,686,400
    float* Kb   = Qb   + (size_t)B_*N_*INNER_;
    float* Vb   = Kb   + (size_t)B_*N_*INNER_;
    float* OWb  = Vb   + (size_t)B_*N_*INNER_;
    float* diag = OWb  + (size_t)B_*N_*INNER_; // 144
    float* att1 = Qb;                          // alias: Q dead after k_attn

    float* out1 = (float*)d_out;               // [B,D,H,W]
    float* out2 = out1 + (size_t)B_*D_*N_;     // [B,N,96]

    k_diag<<<1, 128, 0, stream>>>(E_mat, F_mat, w_e, b_e, w_f, b_f, diag);
    k_conv<<<800, 256, 0, stream>>>(x, conv_w, conv_b, prelu_a, seqT);
    k_ln_qkv<<<3200, 256, 0, stream>>>(seqT, w_qkv, ln1_g, ln1_b, diag, Qb, Kb, Vb);
    k_attn<<<600, 256, 0, stream>>>(Qb, Kb, Vb, OWb);
    k_tail<<<3200, 256, 0, stream>>>(seqT, OWb, w_out, b_out, ln2_g, ln2_b,
                                     ff_w1, ff_b1, ff_w2, ff_b2, w_fin, b_fin,
                                     att1, out2);
    k_highpass<<<800, 256, 0, stream>>>(seqT, att1, out1);
}

// Round 3
// 316.757 us; speedup vs baseline: 3.3626x; 3.3626x over previous
//
#include <hip/hip_runtime.h>
#include <hip/hip_bf16.h>

#define B_    2
#define CIN_  5
#define H_    160
#define W_    160
#define N_    25600        // H*W
#define D_    48
#define NW_   32
#define WS_   800
#define HEADS_ 3
#define DH_   24
#define INNER_ 72
#define O3_   216
#define NWH_  192          // B*NW*HEADS

typedef __bf16 bf16x8 __attribute__((ext_vector_type(8)));
typedef float  f32x4  __attribute__((ext_vector_type(4)));

// ---------------- K0: e_diag / f_diag precompute ----------------
__global__ void k_diag(const float* __restrict__ Em, const float* __restrict__ Fm,
                       const float* __restrict__ we, const float* __restrict__ be,
                       const float* __restrict__ wf, const float* __restrict__ bf,
                       float* __restrict__ diag) {
    int t = threadIdx.x;
    if (t < 72) {
        int h = t / 24, d = t % 24;
        float se = be[d], sf = bf[d];
        for (int w = 0; w < 30; ++w) {
            se += Em[(h*24+d)*30 + w] * we[d*30 + w];
            sf += Fm[(h*24+d)*30 + w] * wf[d*30 + w];
        }
        diag[t]      = se;
        diag[72 + t] = sf;
    }
}

// ---------------- K1: conv3x3 + PReLU -> seqT [B,N,D] ----------------
__global__ __launch_bounds__(256) void k_conv(const float* __restrict__ x,
                                              const float* __restrict__ cw,
                                              const float* __restrict__ cb,
                                              const float* __restrict__ pa,
                                              float* __restrict__ seqT) {
    __shared__ float T[64][49];
    __shared__ float cwL[48*45];
    __shared__ float cbL[48];
    int t  = threadIdx.x;
    int blk = blockIdx.x;              // 0..799
    int b  = blk / 400;
    int n0 = (blk % 400) * 64;
    for (int f = t; f < 48*45; f += 256) cwL[f] = cw[f];
    if (t < 48) cbL[t] = cb[t];
    __syncthreads();

    int px = t & 63;
    int wv = t >> 6;                   // 0..3, handles oc [wv*12, wv*12+12)
    int n  = n0 + px;
    int y  = n / W_, xx = n % W_;
    float a = pa[0];

    float patch[45];
    #pragma unroll
    for (int ic = 0; ic < 5; ++ic)
      #pragma unroll
      for (int ky = 0; ky < 3; ++ky)
        #pragma unroll
        for (int kx = 0; kx < 3; ++kx) {
            int yy = y + ky - 1, xc = xx + kx - 1;
            float v = 0.f;
            if (yy >= 0 && yy < H_ && xc >= 0 && xc < W_)
                v = x[((size_t)(b*CIN_ + ic)*H_ + yy)*W_ + xc];
            patch[(ic*3+ky)*3+kx] = v;
        }
    for (int oi = 0; oi < 12; ++oi) {
        int oc = wv*12 + oi;
        float acc = cbL[oc];
        #pragma unroll
        for (int k = 0; k < 45; ++k) acc += patch[k] * cwL[oc*45 + k];
        acc = acc >= 0.f ? acc : a * acc;
        T[px][oc] = acc;
    }
    __syncthreads();
    for (int i = 0; i < 12; ++i) {
        int f = t + i*256;             // < 3072
        int p = f / 48, c = f % 48;
        seqT[(size_t)(b*N_ + n0 + p)*D_ + c] = T[p][c];
    }
}

// ---------------- K2: LN1 + QKV -> bf16 Q,K (padded, scaled) + f32 V ----------------
__global__ __launch_bounds__(256) void k_ln_qkv(const float* __restrict__ seqT,
                                                const float* __restrict__ wqkv,
                                                const float* __restrict__ g1,
                                                const float* __restrict__ b1,
                                                const float* __restrict__ diag,
                                                __bf16* __restrict__ Qbf,
                                                __bf16* __restrict__ Kbf,
                                                float* __restrict__ Vf) {
    __shared__ float wqL[216*49];      // padded stride 49
    __shared__ float xnL[4][48];
    __shared__ float dg[144];
    __shared__ float gb[96];
    int t = threadIdx.x;
    for (int f = t; f < 216*48; f += 256) wqL[(f/48)*49 + (f%48)] = wqkv[f];
    if (t < 144) dg[t] = diag[t];
    if (t < 48) { gb[t] = g1[t]; gb[48+t] = b1[t]; }
    __syncthreads();

    const float SCALE = 0.20412414523193154f;   // 24^-0.5
    int wv = t >> 6, lane = t & 63;
    int row0 = blockIdx.x * 16 + wv * 4;
    for (int rr = 0; rr < 4; ++rr) {
        int row = row0 + rr;
        float xv = (lane < 48) ? seqT[(size_t)row*D_ + lane] : 0.f;
        float s = xv, s2 = xv*xv;
        #pragma unroll
        for (int m = 32; m; m >>= 1) { s += __shfl_xor(s, m); s2 += __shfl_xor(s2, m); }
        float mean = s * (1.f/48.f);
        float var  = s2 * (1.f/48.f) - mean*mean;
        float rs   = rsqrtf(var + 1e-5f);
        if (lane < 48) xnL[wv][lane] = (xv - mean) * rs * gb[lane] + gb[48+lane];
        __syncthreads();

        int b = row / N_; int n = row % N_;
        int wwin = n / WS_; int iwin = n % WS_;
        #pragma unroll
        for (int rep = 0; rep < 4; ++rep) {
            int o = lane + rep*64;
            if (o < 216) {
                const float* wr = &wqL[o*49];
                float acc = 0.f;
                #pragma unroll
                for (int c = 0; c < 48; ++c) acc += xnL[wv][c] * wr[c];
                int h = o / 72, j = o % 72, part = j / 24, d = j % 24;
                size_t rowq = (size_t)((b*NW_ + wwin)*HEADS_ + h)*WS_ + iwin;
                if      (part == 0) Qbf[rowq*32 + d] = (__bf16)(acc * SCALE);
                else if (part == 1) Kbf[rowq*32 + d] = (__bf16)(acc * dg[h*24 + d]);
                else                Vf [rowq*24 + d] = acc * dg[72 + h*24 + d];
            }
        }
        // zero-pad d=24..31 for Q and K (3 heads x 8 pads = 24 lanes)
        if (lane < 24) {
            int hh = lane >> 3, dd = 24 + (lane & 7);
            size_t rowp = (size_t)((b*NW_ + wwin)*HEADS_ + hh)*WS_ + iwin;
            Qbf[rowp*32 + dd] = (__bf16)0.f;
            Kbf[rowp*32 + dd] = (__bf16)0.f;
        }
        __syncthreads();
    }
}

// ---------------- K2b: transpose V -> bf16 Vt[wh][32][800] (rows 24..31 zero) ----------------
__global__ __launch_bounds__(256) void k_vt(const float* __restrict__ Vf,
                                            __bf16* __restrict__ Vt) {
    __shared__ float L[64*25];
    int bk = blockIdx.x;
    int wh = bk / 13, tile = bk % 13;
    int n0 = tile * 64;
    int nt = (n0 + 64 <= WS_) ? 64 : (WS_ - n0);   // 64 or 32
    int t = threadIdx.x;
    size_t base = ((size_t)wh*WS_ + n0)*24;
    for (int f = t; f < nt*24; f += 256)
        L[(f/24)*25 + (f%24)] = Vf[base + f];
    __syncthreads();
    for (int e = t; e < 2048; e += 256) {
        int d = e >> 6, n = e & 63;
        if (n < nt)
            Vt[(size_t)wh*32*WS_ + (size_t)d*WS_ + n0 + n] =
                (d < 24) ? (__bf16)L[n*25 + d] : (__bf16)0.f;
    }
}

// ---------------- K3: MFMA windowed attention (1 wave = 16 queries) ----------------
__global__ __launch_bounds__(256) void k_attn(const __bf16* __restrict__ Qbf,
                                              const __bf16* __restrict__ Kbf,
                                              const __bf16* __restrict__ Vt,
                                              float* __restrict__ OWb) {
    __shared__ __bf16 Plds[4][16*40];          // per-wave 16x32 P tile, stride 40
    int t = threadIdx.x;
    int wv = t >> 6, lane = t & 63;
    int g = lane >> 4, s = lane & 15;
    int task = blockIdx.x * 4 + wv;            // 0..9599 exactly
    int wh = task / 50, qt = task % 50;
    int q0 = qt * 16;

    const bf16x8* Qp = (const bf16x8*)(Qbf + ((size_t)wh*WS_ + q0)*32);
    const bf16x8* Kp = (const bf16x8*)(Kbf + (size_t)wh*WS_*32);
    const bf16x8* Vp = (const bf16x8*)(Vt  + (size_t)wh*32*WS_);
    __bf16* myP = Plds[wv];

    // A-frag: row = lane&15 (query), k = (lane>>4)*8 + idx  -> Qp[s*4 + g]
    bf16x8 qa = Qp[s*4 + g];

    f32x4 o0 = {0.f,0.f,0.f,0.f}, o1 = {0.f,0.f,0.f,0.f};
    float ps[4] = {0.f,0.f,0.f,0.f};

    for (int c = 0; c < 25; ++c) {
        // ---- QK^T: keys c*32 .. c*32+31 (two 16-key tiles) ----
        bf16x8 ka0 = Kp[(c*32 +      s)*4 + g];
        bf16x8 ka1 = Kp[(c*32 + 16 + s)*4 + g];
        f32x4 s0 = {0.f,0.f,0.f,0.f}, s1 = {0.f,0.f,0.f,0.f};
        s0 = __builtin_amdgcn_mfma_f32_16x16x32_bf16(qa, ka0, s0, 0, 0, 0);
        s1 = __builtin_amdgcn_mfma_f32_16x16x32_bf16(qa, ka1, s1, 0, 0, 0);
        // C layout: row(query) = g*4+r, col(key-in-tile) = s
        #pragma unroll
        for (int r = 0; r < 4; ++r) {
            float p0 = __expf(s0[r]);
            float p1 = __expf(s1[r]);
            ps[r] += p0 + p1;
            myP[(g*4+r)*40 +      s] = (__bf16)p0;
            myP[(g*4+r)*40 + 16 + s] = (__bf16)p1;
        }
        // ---- P·V: A-frag P[row=s][j=8g..8g+7], B-frag Vt rows d ----
        bf16x8 pa  = *(const bf16x8*)&myP[s*40 + 8*g];
        bf16x8 vb0 = Vp[(     s)*100 + c*4 + g];   // d = s
        bf16x8 vb1 = Vp[(16 + s)*100 + c*4 + g];   // d = 16+s (rows >=24 are zero)
        o0 = __builtin_amdgcn_mfma_f32_16x16x32_bf16(pa, vb0, o0, 0, 0, 0);
        o1 = __builtin_amdgcn_mfma_f32_16x16x32_bf16(pa, vb1, o1, 0, 0, 0);
    }

    // row-sum reduce across the 16 lanes of each group (bits 0..3)
    #pragma unroll
    for (int r = 0; r < 4; ++r) {
        float v = ps[r];
        v += __shfl_xor(v, 1); v += __shfl_xor(v, 2);
        v += __shfl_xor(v, 4); v += __shfl_xor(v, 8);
        ps[r] = 1.f / v;
    }

    int bw = wh / 3, h = wh % 3;
    int b = bw >> 5, w = bw & 31;
    #pragma unroll
    for (int r = 0; r < 4; ++r) {
        int n = w*WS_ + q0 + g*4 + r;
        size_t addr = (size_t)(b*N_ + n)*INNER_ + h*DH_;
        OWb[addr + s] = o0[r] * ps[r];
        if (s < 8) OWb[addr + 16 + s] = o1[r] * ps[r];
    }
}

// ---------------- K4: to_out + residual + LN2 + MLP + residual + final linear ----------------
__global__ __launch_bounds__(256) void k_tail(const float* __restrict__ seqT,
                                              const float* __restrict__ OWb,
                                              const float* __restrict__ w_out,
                                              const float* __restrict__ b_out,
                                              const float* __restrict__ g2,
                                              const float* __restrict__ b2,
                                              const float* __restrict__ fw1,
                                              const float* __restrict__ fb1,
                                              const float* __restrict__ fw2,
                                              const float* __restrict__ fb2,
                                              const float* __restrict__ wfin,
                                              const float* __restrict__ bfin,
                                              float* __restrict__ att1,
                                              float* __restrict__ out2) {
    __shared__ float woL[48*73];
    __shared__ float f1L[48*49];
    __shared__ float f2L[48*49];
    __shared__ float wfL[96*49];
    __shared__ float bo[48], g2L[48], b2L[48], fb1L[48], fb2L[48], bfL[96];
    __shared__ float owL[4][72];
    __shared__ float ynL[4][48];
    __shared__ float h1L[4][48];
    __shared__ float a1L[4][48];
    int t = threadIdx.x;
    for (int f = t; f < 48*72; f += 256) woL[(f/72)*73 + f%72] = w_out[f];
    for (int f = t; f < 48*48; f += 256) {
        f1L[(f/48)*49 + f%48] = fw1[f];
        f2L[(f/48)*49 + f%48] = fw2[f];
    }
    for (int f = t; f < 96*48; f += 256) wfL[(f/48)*49 + f%48] = wfin[f];
    if (t < 48) { bo[t]=b_out[t]; g2L[t]=g2[t]; b2L[t]=b2[t]; fb1L[t]=fb1[t]; fb2L[t]=fb2[t]; }
    if (t < 96) bfL[t] = bfin[t];
    __syncthreads();

    int wv = t >> 6, lane = t & 63;
    int row0 = blockIdx.x*16 + wv*4;
    for (int rr = 0; rr < 4; ++rr) {
        int row = row0 + rr;
        float sv = (lane < 48) ? seqT[(size_t)row*D_ + lane] : 0.f;
        owL[wv][lane] = OWb[(size_t)row*INNER_ + lane];
        if (lane < 8) owL[wv][64+lane] = OWb[(size_t)row*INNER_ + 64 + lane];
        __syncthreads();

        float att = 0.f;
        if (lane < 48) {
            att = bo[lane];
            const float* wr = &woL[lane*73];
            #pragma unroll
            for (int f = 0; f < 72; ++f) att += owL[wv][f] * wr[f];
        }
        float s2 = sv + att;
        float a  = (lane < 48) ? s2 : 0.f;
        float aa = a*a;
        #pragma unroll
        for (int m = 32; m; m >>= 1) { a += __shfl_xor(a, m); aa += __shfl_xor(aa, m); }
        float mean = a * (1.f/48.f);
        float var  = aa * (1.f/48.f) - mean*mean;
        float rs   = rsqrtf(var + 1e-5f);
        if (lane < 48) ynL[wv][lane] = (s2 - mean) * rs * g2L[lane] + b2L[lane];
        __syncthreads();

        if (lane < 48) {
            float h1 = fb1L[lane];
            const float* wr = &f1L[lane*49];
            #pragma unroll
            for (int f = 0; f < 48; ++f) h1 += ynL[wv][f] * wr[f];
            h1 = h1 >= 0.f ? h1 : 0.01f*h1;
            h1L[wv][lane] = h1;
        }
        __syncthreads();

        if (lane < 48) {
            float h2 = fb2L[lane];
            const float* wr = &f2L[lane*49];
            #pragma unroll
            for (int f = 0; f < 48; ++f) h2 += h1L[wv][f] * wr[f];
            float a1 = s2 + h2;
            att1[(size_t)row*D_ + lane] = a1;
            a1L[wv][lane] = a1;
        }
        __syncthreads();

        #pragma unroll
        for (int rep = 0; rep < 2; ++rep) {
            int o = lane + rep*64;
            if (o < 96) {
                float acc = bfL[o];
                const float* wr = &wfL[o*49];
                #pragma unroll
                for (int f = 0; f < 48; ++f) acc += a1L[wv][f] * wr[f];
                out2[(size_t)row*96 + o] = acc;
            }
        }
        __syncthreads();
    }
}

// ---------------- K5: Highpass = seqT*(1+att1), transposed to [B,D,H,W] ----------------
__global__ __launch_bounds__(256) void k_highpass(const float* __restrict__ seqT,
                                                  const float* __restrict__ att1,
                                                  float* __restrict__ out1) {
    __shared__ float T[64][49];
    int blk = blockIdx.x;              // 0..799
    int b  = blk / 400;
    int n0 = (blk % 400) * 64;
    int t  = threadIdx.x;
    for (int i = 0; i < 12; ++i) {
        int f = t + i*256;             // < 3072
        int p = f / 48, c = f % 48;
        size_t idx = (size_t)(b*N_ + n0 + p)*D_ + c;
        T[p][c] = seqT[idx] * (1.f + att1[idx]);
    }
    __syncthreads();
    for (int i = 0; i < 12; ++i) {
        int g = t + i*256;
        int d = g / 64, nl = g % 64;
        out1[((size_t)b*D_ + d)*N_ + n0 + nl] = T[nl][d];
    }
}

extern "C" void kernel_launch(void* const* d_in, const int* in_sizes, int n_in,
                              void* d_out, int out_size, void* d_ws, size_t ws_size,
                              hipStream_t stream) {
    const float* x      = (const float*)d_in[0];
    const float* conv_w = (const float*)d_in[1];
    const float* conv_b = (const float*)d_in[2];
    const float* prelu_a= (const float*)d_in[3];
    const float* ln1_g  = (const float*)d_in[4];
    const float* ln1_b  = (const float*)d_in[5];
    const float* w_qkv  = (const float*)d_in[6];
    const float* E_mat  = (const float*)d_in[7];
    const float* F_mat  = (const float*)d_in[8];
    const float* w_e    = (const float*)d_in[9];
    const float* b_e    = (const float*)d_in[10];
    const float* w_f    = (const float*)d_in[11];
    const float* b_f    = (const float*)d_in[12];
    const float* w_out  = (const float*)d_in[13];
    const float* b_out  = (const float*)d_in[14];
    const float* ln2_g  = (const float*)d_in[15];
    const float* ln2_b  = (const float*)d_in[16];
    const float* ff_w1  = (const float*)d_in[17];
    const float* ff_b1  = (const float*)d_in[18];
    const float* ff_w2  = (const float*)d_in[19];
    const float* ff_b2  = (const float*)d_in[20];
    const float* w_fin  = (const float*)d_in[21];
    const float* b_fin  = (const float*)d_in[22];

    float* ws   = (float*)d_ws;
    float*  seqT = ws;                                   // 2,457,600 f32
    float*  diag = seqT + (size_t)B_*N_*D_;              // 144 f32
    __bf16* Qbf  = (__bf16*)(diag + 144);                // 192*800*32 bf16
    __bf16* Kbf  = Qbf + (size_t)NWH_*WS_*32;            // 192*800*32 bf16
    float*  Vf   = (float*)(Kbf + (size_t)NWH_*WS_*32);  // 192*800*24 f32
    __bf16* Vt   = (__bf16*)(Vf + (size_t)NWH_*WS_*24);  // 192*32*800 bf16
    float*  OWb  = (float*)(Vt + (size_t)NWH_*32*WS_);   // 2*25600*72 f32
    float*  att1 = Vf;                                   // alias: Vf dead after k_vt/k_attn

    float* out1 = (float*)d_out;               // [B,D,H,W]
    float* out2 = out1 + (size_t)B_*D_*N_;     // [B,N,96]

    k_diag<<<1, 128, 0, stream>>>(E_mat, F_mat, w_e, b_e, w_f, b_f, diag);
    k_conv<<<800, 256, 0, stream>>>(x, conv_w, conv_b, prelu_a, seqT);
    k_ln_qkv<<<3200, 256, 0, stream>>>(seqT, w_qkv, ln1_g, ln1_b, diag, Qbf, Kbf, Vf);
    k_vt<<<NWH_*13, 256, 0, stream>>>(Vf, Vt);
    k_attn<<<2400, 256, 0, stream>>>(Qbf, Kbf, Vt, OWb);
    k_tail<<<3200, 256, 0, stream>>>(seqT, OWb, w_out, b_out, ln2_g, ln2_b,
                                     ff_w1, ff_b1, ff_w2, ff_b2, w_fin, b_fin,
                                     att1, out2);
    k_highpass<<<800, 256, 0, stream>>>(seqT, att1, out1);
}

// Round 4
// 148.018 us; speedup vs baseline: 7.1960x; 2.1400x over previous
//
#include <hip/hip_runtime.h>
#include <hip/hip_bf16.h>

#define B_    2
#define CIN_  5
#define H_    160
#define W_    160
#define N_    25600        // H*W
#define D_    48
#define NW_   32
#define WS_   800
#define HEADS_ 3
#define DH_   24
#define INNER_ 72
#define NWH_  192          // B*NW*HEADS

typedef __bf16 bf16x8 __attribute__((ext_vector_type(8)));
typedef float  f32x4  __attribute__((ext_vector_type(4)));

#define MFMA(a,b,c) __builtin_amdgcn_mfma_f32_16x16x32_bf16((a),(b),(c),0,0,0)

// ---------------- K0: e_diag / f_diag precompute ----------------
__global__ void k_diag(const float* __restrict__ Em, const float* __restrict__ Fm,
                       const float* __restrict__ we, const float* __restrict__ be,
                       const float* __restrict__ wf, const float* __restrict__ bf,
                       float* __restrict__ diag) {
    int t = threadIdx.x;
    if (t < 72) {
        int h = t / 24, d = t % 24;
        float se = be[d], sf = bf[d];
        for (int w = 0; w < 30; ++w) {
            se += Em[(h*24+d)*30 + w] * we[d*30 + w];
            sf += Fm[(h*24+d)*30 + w] * wf[d*30 + w];
        }
        diag[t]      = se;
        diag[72 + t] = sf;
    }
}

// ---------------- K0b: weight prep -> zero-padded bf16 ----------------
__global__ __launch_bounds__(256) void k_wprep(const float* __restrict__ wqkv,
                                               const float* __restrict__ w_out,
                                               const float* __restrict__ fw1,
                                               const float* __restrict__ fw2,
                                               const float* __restrict__ wfin,
                                               __bf16* __restrict__ wqB,   // [224][64]
                                               __bf16* __restrict__ woB,   // [48][96]
                                               __bf16* __restrict__ f1B,   // [48][64]
                                               __bf16* __restrict__ f2B,   // [48][64]
                                               __bf16* __restrict__ wfB) { // [96][64]
    int t = blockIdx.x*256 + threadIdx.x, stride = gridDim.x*256;
    for (int i = t; i < 224*64; i += stride) { int o=i>>6, c=i&63; wqB[i] = (o<216 && c<48)? (__bf16)wqkv[o*48+c] : (__bf16)0.f; }
    for (int i = t; i < 48*96;  i += stride) { int o=i/96, c=i%96; woB[i] = (c<72)? (__bf16)w_out[o*72+c] : (__bf16)0.f; }
    for (int i = t; i < 48*64;  i += stride) { int o=i>>6, c=i&63; f1B[i] = (c<48)? (__bf16)fw1[o*48+c] : (__bf16)0.f; }
    for (int i = t; i < 48*64;  i += stride) { int o=i>>6, c=i&63; f2B[i] = (c<48)? (__bf16)fw2[o*48+c] : (__bf16)0.f; }
    for (int i = t; i < 96*64;  i += stride) { int o=i>>6, c=i&63; wfB[i] = (c<48)? (__bf16)wfin[o*48+c] : (__bf16)0.f; }
}

// ---------------- K1: conv3x3 + PReLU -> seqT [B,N,D] ----------------
__global__ __launch_bounds__(256) void k_conv(const float* __restrict__ x,
                                              const float* __restrict__ cw,
                                              const float* __restrict__ cb,
                                              const float* __restrict__ pa,
                                              float* __restrict__ seqT) {
    __shared__ float T[64][49];
    __shared__ float cwL[48*45];
    __shared__ float cbL[48];
    int t  = threadIdx.x;
    int blk = blockIdx.x;              // 0..799
    int b  = blk / 400;
    int n0 = (blk % 400) * 64;
    for (int f = t; f < 48*45; f += 256) cwL[f] = cw[f];
    if (t < 48) cbL[t] = cb[t];
    __syncthreads();

    int px = t & 63;
    int wv = t >> 6;                   // 0..3, handles oc [wv*12, wv*12+12)
    int n  = n0 + px;
    int y  = n / W_, xx = n % W_;
    float a = pa[0];

    float patch[45];
    #pragma unroll
    for (int ic = 0; ic < 5; ++ic)
      #pragma unroll
      for (int ky = 0; ky < 3; ++ky)
        #pragma unroll
        for (int kx = 0; kx < 3; ++kx) {
            int yy = y + ky - 1, xc = xx + kx - 1;
            float v = 0.f;
            if (yy >= 0 && yy < H_ && xc >= 0 && xc < W_)
                v = x[((size_t)(b*CIN_ + ic)*H_ + yy)*W_ + xc];
            patch[(ic*3+ky)*3+kx] = v;
        }
    for (int oi = 0; oi < 12; ++oi) {
        int oc = wv*12 + oi;
        float acc = cbL[oc];
        #pragma unroll
        for (int k = 0; k < 45; ++k) acc += patch[k] * cwL[oc*45 + k];
        acc = acc >= 0.f ? acc : a * acc;
        T[px][oc] = acc;
    }
    __syncthreads();
    for (int i = 0; i < 12; ++i) {
        int f = t + i*256;             // < 3072
        int p = f / 48, c = f % 48;
        seqT[(size_t)(b*N_ + n0 + p)*D_ + c] = T[p][c];
    }
}

// ---------------- K2: MFMA LN1 + QKV (wave = 32 rows) ----------------
__global__ __launch_bounds__(256) void k_qkv(const float* __restrict__ seqT,
                                             const __bf16* __restrict__ wqB,
                                             const float* __restrict__ g1,
                                             const float* __restrict__ b1,
                                             const float* __restrict__ diag,
                                             __bf16* __restrict__ Qbf,
                                             __bf16* __restrict__ Kbf,
                                             float* __restrict__ Vf) {
    __shared__ __bf16 xfer[4][2048];           // per-wave 32x64 bf16, swizzled
    int t = threadIdx.x, wv = t>>6, lane = t&63, g = lane>>4, s = lane&15;
    int row0 = (blockIdx.x*4 + wv) * 32;
    char* xb = (char*)&xfer[wv][0];

    int b = row0 / N_, nrem = row0 % N_;
    int w = nrem / WS_, i0 = nrem % WS_;       // 32 | 800: all rows same window
    size_t headbase = (size_t)((b*NW_ + w)*HEADS_);

    // load x tile in C-layout + LN1
    float xr[2][3][4];
    #pragma unroll
    for (int m = 0; m < 2; ++m)
      #pragma unroll
      for (int n = 0; n < 3; ++n)
        #pragma unroll
        for (int r = 0; r < 4; ++r)
          xr[m][n][r] = seqT[(size_t)(row0 + m*16 + g*4 + r)*48 + n*16 + s];

    float g1v[3], b1v[3];
    #pragma unroll
    for (int n = 0; n < 3; ++n) { g1v[n] = g1[n*16+s]; b1v[n] = b1[n*16+s]; }

    #pragma unroll
    for (int m = 0; m < 2; ++m)
      #pragma unroll
      for (int r = 0; r < 4; ++r) {
        float sm = xr[m][0][r] + xr[m][1][r] + xr[m][2][r];
        float sq = xr[m][0][r]*xr[m][0][r] + xr[m][1][r]*xr[m][1][r] + xr[m][2][r]*xr[m][2][r];
        #pragma unroll
        for (int msk = 1; msk < 16; msk <<= 1) { sm += __shfl_xor(sm, msk); sq += __shfl_xor(sq, msk); }
        float mean = sm * (1.f/48.f);
        float var  = sq * (1.f/48.f) - mean*mean;
        float rs   = rsqrtf(var + 1e-5f);
        int row = m*16 + g*4 + r;
        int sw  = ((g*4+r)&7) << 4;
        #pragma unroll
        for (int n = 0; n < 3; ++n) {
            float yn = (xr[m][n][r] - mean) * rs * g1v[n] + b1v[n];
            *(__bf16*)(xb + ((row*128 + (n*16+s)*2) ^ sw)) = (__bf16)yn;
        }
        *(__bf16*)(xb + ((row*128 + (48+s)*2) ^ sw)) = (__bf16)0.f;  // K-pad
      }

    // A-frags from LDS
    bf16x8 af[2][2];
    #pragma unroll
    for (int m = 0; m < 2; ++m)
      #pragma unroll
      for (int kc = 0; kc < 2; ++kc)
        af[m][kc] = *(const bf16x8*)(xb + (((m*16+s)*128 + kc*64 + g*16) ^ ((s&7)<<4)));

    const bf16x8* WQ4 = (const bf16x8*)wqB;
    const float SCALE = 0.20412414523193154f;   // 24^-0.5

    #pragma unroll 2
    for (int n = 0; n < 14; ++n) {
        bf16x8 wb0 = WQ4[(n*16+s)*8 + g];
        bf16x8 wb1 = WQ4[(n*16+s)*8 + 4 + g];
        f32x4 c0 = {0.f,0.f,0.f,0.f}, c1 = {0.f,0.f,0.f,0.f};
        c0 = MFMA(af[0][0], wb0, c0); c0 = MFMA(af[0][1], wb1, c0);
        c1 = MFMA(af[1][0], wb0, c1); c1 = MFMA(af[1][1], wb1, c1);
        int o = n*16 + s;
        if (o < 216) {
            int h = o/72, j = o%72, part = j/24, d = j%24;
            size_t rbase = (headbase + h)*WS_ + i0;
            float mul = (part==0) ? SCALE : ((part==1) ? diag[h*24+d] : diag[72+h*24+d]);
            #pragma unroll
            for (int m = 0; m < 2; ++m) {
                f32x4 c = m ? c1 : c0;
                #pragma unroll
                for (int r = 0; r < 4; ++r) {
                    size_t rq = rbase + m*16 + g*4 + r;
                    float val = c[r] * mul;
                    if      (part == 0) Qbf[rq*32 + d] = (__bf16)val;
                    else if (part == 1) Kbf[rq*32 + d] = (__bf16)val;
                    else                Vf [rq*24 + d] = val;
                }
            }
        }
    }
    // Q/K zero-pad cols 24..31 (32 rows x 24 slots = 768)
    #pragma unroll
    for (int it = 0; it < 12; ++it) {
        int idx = lane + it*64;
        int rl = idx/24, cc = idx%24;
        int hh = cc>>3, dd = 24 + (cc&7);
        size_t rq = (headbase + hh)*WS_ + i0 + rl;
        Qbf[rq*32 + dd] = (__bf16)0.f;
        Kbf[rq*32 + dd] = (__bf16)0.f;
    }
}

// ---------------- K2b: transpose V -> bf16 Vt[wh][32][800] (rows 24..31 zero) ----------------
__global__ __launch_bounds__(256) void k_vt(const float* __restrict__ Vf,
                                            __bf16* __restrict__ Vt) {
    __shared__ float L[64*25];
    int bk = blockIdx.x;
    int wh = bk / 13, tile = bk % 13;
    int n0 = tile * 64;
    int nt = (n0 + 64 <= WS_) ? 64 : (WS_ - n0);   // 64 or 32
    int t = threadIdx.x;
    size_t base = ((size_t)wh*WS_ + n0)*24;
    for (int f = t; f < nt*24; f += 256)
        L[(f/24)*25 + (f%24)] = Vf[base + f];
    __syncthreads();
    for (int e = t; e < 2048; e += 256) {
        int d = e >> 6, n = e & 63;
        if (n < nt)
            Vt[(size_t)wh*32*WS_ + (size_t)d*WS_ + n0 + n] =
                (d < 24) ? (__bf16)L[n*25 + d] : (__bf16)0.f;
    }
}

// ---------------- K3: MFMA windowed attention (1 wave = 16 queries) ----------------
__global__ __launch_bounds__(256) void k_attn(const __bf16* __restrict__ Qbf,
                                              const __bf16* __restrict__ Kbf,
                                              const __bf16* __restrict__ Vt,
                                              __bf16* __restrict__ OW) {
    __shared__ __bf16 Plds[4][16*40];          // per-wave 16x32 P tile, stride 40
    int t = threadIdx.x;
    int wv = t >> 6, lane = t & 63;
    int g = lane >> 4, s = lane & 15;
    int task = blockIdx.x * 4 + wv;            // 0..9599 exactly
    int wh = task / 50, qt = task % 50;
    int q0 = qt * 16;

    const bf16x8* Qp = (const bf16x8*)(Qbf + ((size_t)wh*WS_ + q0)*32);
    const bf16x8* Kp = (const bf16x8*)(Kbf + (size_t)wh*WS_*32);
    const bf16x8* Vp = (const bf16x8*)(Vt  + (size_t)wh*32*WS_);
    __bf16* myP = Plds[wv];

    bf16x8 qa = Qp[s*4 + g];

    f32x4 o0 = {0.f,0.f,0.f,0.f}, o1 = {0.f,0.f,0.f,0.f};
    float ps[4] = {0.f,0.f,0.f,0.f};

    for (int c = 0; c < 25; ++c) {
        bf16x8 ka0 = Kp[(c*32 +      s)*4 + g];
        bf16x8 ka1 = Kp[(c*32 + 16 + s)*4 + g];
        f32x4 s0 = {0.f,0.f,0.f,0.f}, s1 = {0.f,0.f,0.f,0.f};
        s0 = MFMA(qa, ka0, s0);
        s1 = MFMA(qa, ka1, s1);
        #pragma unroll
        for (int r = 0; r < 4; ++r) {
            float p0 = __expf(s0[r]);
            float p1 = __expf(s1[r]);
            ps[r] += p0 + p1;
            myP[(g*4+r)*40 +      s] = (__bf16)p0;
            myP[(g*4+r)*40 + 16 + s] = (__bf16)p1;
        }
        bf16x8 pa  = *(const bf16x8*)&myP[s*40 + 8*g];
        bf16x8 vb0 = Vp[(     s)*100 + c*4 + g];
        bf16x8 vb1 = Vp[(16 + s)*100 + c*4 + g];
        o0 = MFMA(pa, vb0, o0);
        o1 = MFMA(pa, vb1, o1);
    }

    #pragma unroll
    for (int r = 0; r < 4; ++r) {
        float v = ps[r];
        v += __shfl_xor(v, 1); v += __shfl_xor(v, 2);
        v += __shfl_xor(v, 4); v += __shfl_xor(v, 8);
        ps[r] = 1.f / v;
    }

    int bw = wh / 3, h = wh % 3;
    int b = bw >> 5, w = bw & 31;
    #pragma unroll
    for (int r = 0; r < 4; ++r) {
        int n = w*WS_ + q0 + g*4 + r;
        size_t addr = (size_t)(b*N_ + n)*96 + h*24;
        OW[addr + s] = (__bf16)(o0[r] * ps[r]);
        if (s < 8) OW[addr + 16 + s] = (__bf16)(o1[r] * ps[r]);
        if (h == 0) {                          // write K-pad cols 72..95
            size_t pbase = (size_t)(b*N_ + n)*96;
            OW[pbase + 72 + s] = (__bf16)0.f;
            if (s < 8) OW[pbase + 88 + s] = (__bf16)0.f;
        }
    }
}

// ---------------- K4: MFMA tail: to_out+res+LN2+MLP+res+final (wave = 32 rows) ----------------
__global__ __launch_bounds__(256) void k_tail(const float* __restrict__ seqT,
                                              const __bf16* __restrict__ OW,
                                              const __bf16* __restrict__ woB,
                                              const float* __restrict__ b_out,
                                              const float* __restrict__ g2,
                                              const float* __restrict__ b2,
                                              const __bf16* __restrict__ f1B,
                                              const float* __restrict__ fb1,
                                              const __bf16* __restrict__ f2B,
                                              const float* __restrict__ fb2,
                                              const __bf16* __restrict__ wfB,
                                              const float* __restrict__ bfin,
                                              float* __restrict__ att1,
                                              float* __restrict__ out2) {
    __shared__ __bf16 xfer[4][2048];
    int t = threadIdx.x, wv = t>>6, lane = t&63, g = lane>>4, s = lane&15;
    int row0 = (blockIdx.x*4 + wv) * 32;
    char* xb = (char*)&xfer[wv][0];

    const bf16x8* OW4 = (const bf16x8*)OW;
    const bf16x8* WO4 = (const bf16x8*)woB;
    const bf16x8* F14 = (const bf16x8*)f1B;
    const bf16x8* F24 = (const bf16x8*)f2B;
    const bf16x8* WF4 = (const bf16x8*)wfB;

    // ---- S1: att = ow · w_out^T ----
    bf16x8 aow[2][3];
    #pragma unroll
    for (int m = 0; m < 2; ++m)
      #pragma unroll
      for (int kc = 0; kc < 3; ++kc)
        aow[m][kc] = OW4[(size_t)(row0 + m*16 + s)*12 + kc*4 + g];

    f32x4 s2[2][3];
    #pragma unroll
    for (int n = 0; n < 3; ++n) {
        bf16x8 wb0 = WO4[(n*16+s)*12 + g];
        bf16x8 wb1 = WO4[(n*16+s)*12 + 4 + g];
        bf16x8 wb2 = WO4[(n*16+s)*12 + 8 + g];
        #pragma unroll
        for (int m = 0; m < 2; ++m) {
            f32x4 c = {0.f,0.f,0.f,0.f};
            c = MFMA(aow[m][0], wb0, c);
            c = MFMA(aow[m][1], wb1, c);
            c = MFMA(aow[m][2], wb2, c);
            s2[m][n] = c;
        }
    }
    float bov[3], g2v[3], b2v[3], f1bv[3], f2bv[3];
    #pragma unroll
    for (int n = 0; n < 3; ++n) {
        bov[n] = b_out[n*16+s]; g2v[n] = g2[n*16+s]; b2v[n] = b2[n*16+s];
        f1bv[n] = fb1[n*16+s];  f2bv[n] = fb2[n*16+s];
    }
    #pragma unroll
    for (int m = 0; m < 2; ++m)
      #pragma unroll
      for (int n = 0; n < 3; ++n)
        #pragma unroll
        for (int r = 0; r < 4; ++r)
          s2[m][n][r] += seqT[(size_t)(row0 + m*16 + g*4 + r)*48 + n*16 + s] + bov[n];

    // ---- LN2 -> yn -> LDS ----
    #pragma unroll
    for (int m = 0; m < 2; ++m)
      #pragma unroll
      for (int r = 0; r < 4; ++r) {
        float sm = s2[m][0][r] + s2[m][1][r] + s2[m][2][r];
        float sq = s2[m][0][r]*s2[m][0][r] + s2[m][1][r]*s2[m][1][r] + s2[m][2][r]*s2[m][2][r];
        #pragma unroll
        for (int msk = 1; msk < 16; msk <<= 1) { sm += __shfl_xor(sm, msk); sq += __shfl_xor(sq, msk); }
        float mean = sm * (1.f/48.f);
        float var  = sq * (1.f/48.f) - mean*mean;
        float rs   = rsqrtf(var + 1e-5f);
        int row = m*16 + g*4 + r;
        int sw  = ((g*4+r)&7) << 4;
        #pragma unroll
        for (int n = 0; n < 3; ++n) {
            float yn = (s2[m][n][r] - mean) * rs * g2v[n] + b2v[n];
            *(__bf16*)(xb + ((row*128 + (n*16+s)*2) ^ sw)) = (__bf16)yn;
        }
        *(__bf16*)(xb + ((row*128 + (48+s)*2) ^ sw)) = (__bf16)0.f;
      }

    bf16x8 af[2][2];
    f32x4 hh[2][3];

    // ---- ff1 ----
    #pragma unroll
    for (int m = 0; m < 2; ++m)
      #pragma unroll
      for (int kc = 0; kc < 2; ++kc)
        af[m][kc] = *(const bf16x8*)(xb + (((m*16+s)*128 + kc*64 + g*16) ^ ((s&7)<<4)));
    #pragma unroll
    for (int n = 0; n < 3; ++n) {
        bf16x8 wb0 = F14[(n*16+s)*8 + g];
        bf16x8 wb1 = F14[(n*16+s)*8 + 4 + g];
        #pragma unroll
        for (int m = 0; m < 2; ++m) {
            f32x4 c = {0.f,0.f,0.f,0.f};
            c = MFMA(af[m][0], wb0, c);
            c = MFMA(af[m][1], wb1, c);
            hh[m][n] = c;
        }
    }
    #pragma unroll
    for (int m = 0; m < 2; ++m)
      #pragma unroll
      for (int r = 0; r < 4; ++r) {
        int row = m*16 + g*4 + r;
        int sw  = ((g*4+r)&7) << 4;
        #pragma unroll
        for (int n = 0; n < 3; ++n) {
            float v = hh[m][n][r] + f1bv[n];
            v = v >= 0.f ? v : 0.01f*v;
            *(__bf16*)(xb + ((row*128 + (n*16+s)*2) ^ sw)) = (__bf16)v;
        }
        *(__bf16*)(xb + ((row*128 + (48+s)*2) ^ sw)) = (__bf16)0.f;
      }

    // ---- ff2 + residual -> att1, a1 -> LDS ----
    #pragma unroll
    for (int m = 0; m < 2; ++m)
      #pragma unroll
      for (int kc = 0; kc < 2; ++kc)
        af[m][kc] = *(const bf16x8*)(xb + (((m*16+s)*128 + kc*64 + g*16) ^ ((s&7)<<4)));
    #pragma unroll
    for (int n = 0; n < 3; ++n) {
        bf16x8 wb0 = F24[(n*16+s)*8 + g];
        bf16x8 wb1 = F24[(n*16+s)*8 + 4 + g];
        #pragma unroll
        for (int m = 0; m < 2; ++m) {
            f32x4 c = {0.f,0.f,0.f,0.f};
            c = MFMA(af[m][0], wb0, c);
            c = MFMA(af[m][1], wb1, c);
            hh[m][n] = c;
        }
    }
    #pragma unroll
    for (int m = 0; m < 2; ++m)
      #pragma unroll
      for (int r = 0; r < 4; ++r) {
        int row = m*16 + g*4 + r;
        int sw  = ((g*4+r)&7) << 4;
        #pragma unroll
        for (int n = 0; n < 3; ++n) {
            float a1v = s2[m][n][r] + hh[m][n][r] + f2bv[n];
            att1[(size_t)(row0 + row)*48 + n*16 + s] = a1v;
            *(__bf16*)(xb + ((row*128 + (n*16+s)*2) ^ sw)) = (__bf16)a1v;
        }
        *(__bf16*)(xb + ((row*128 + (48+s)*2) ^ sw)) = (__bf16)0.f;
      }

    // ---- final linear 48 -> 96 ----
    #pragma unroll
    for (int m = 0; m < 2; ++m)
      #pragma unroll
      for (int kc = 0; kc < 2; ++kc)
        af[m][kc] = *(const bf16x8*)(xb + (((m*16+s)*128 + kc*64 + g*16) ^ ((s&7)<<4)));
    #pragma unroll
    for (int n = 0; n < 6; ++n) {
        bf16x8 wb0 = WF4[(n*16+s)*8 + g];
        bf16x8 wb1 = WF4[(n*16+s)*8 + 4 + g];
        float bfv = bfin[n*16+s];
        #pragma unroll
        for (int m = 0; m < 2; ++m) {
            f32x4 c = {0.f,0.f,0.f,0.f};
            c = MFMA(af[m][0], wb0, c);
            c = MFMA(af[m][1], wb1, c);
            #pragma unroll
            for (int r = 0; r < 4; ++r)
                out2[(size_t)(row0 + m*16 + g*4 + r)*96 + n*16 + s] = c[r] + bfv;
        }
    }
}

// ---------------- K5: Highpass = seqT*(1+att1), transposed to [B,D,H,W] ----------------
__global__ __launch_bounds__(256) void k_highpass(const float* __restrict__ seqT,
                                                  const float* __restrict__ att1,
                                                  float* __restrict__ out1) {
    __shared__ float T[64][49];
    int blk = blockIdx.x;              // 0..799
    int b  = blk / 400;
    int n0 = (blk % 400) * 64;
    int t  = threadIdx.x;
    for (int i = 0; i < 12; ++i) {
        int f = t + i*256;             // < 3072
        int p = f / 48, c = f % 48;
        size_t idx = (size_t)(b*N_ + n0 + p)*D_ + c;
        T[p][c] = seqT[idx] * (1.f + att1[idx]);
    }
    __syncthreads();
    for (int i = 0; i < 12; ++i) {
        int g = t + i*256;
        int d = g / 64, nl = g % 64;
        out1[((size_t)b*D_ + d)*N_ + n0 + nl] = T[nl][d];
    }
}

extern "C" void kernel_launch(void* const* d_in, const int* in_sizes, int n_in,
                              void* d_out, int out_size, void* d_ws, size_t ws_size,
                              hipStream_t stream) {
    const float* x      = (const float*)d_in[0];
    const float* conv_w = (const float*)d_in[1];
    const float* conv_b = (const float*)d_in[2];
    const float* prelu_a= (const float*)d_in[3];
    const float* ln1_g  = (const float*)d_in[4];
    const float* ln1_b  = (const float*)d_in[5];
    const float* w_qkv  = (const float*)d_in[6];
    const float* E_mat  = (const float*)d_in[7];
    const float* F_mat  = (const float*)d_in[8];
    const float* w_e    = (const float*)d_in[9];
    const float* b_e    = (const float*)d_in[10];
    const float* w_f    = (const float*)d_in[11];
    const float* b_f    = (const float*)d_in[12];
    const float* w_out  = (const float*)d_in[13];
    const float* b_out  = (const float*)d_in[14];
    const float* ln2_g  = (const float*)d_in[15];
    const float* ln2_b  = (const float*)d_in[16];
    const float* ff_w1  = (const float*)d_in[17];
    const float* ff_b1  = (const float*)d_in[18];
    const float* ff_w2  = (const float*)d_in[19];
    const float* ff_b2  = (const float*)d_in[20];
    const float* w_fin  = (const float*)d_in[21];
    const float* b_fin  = (const float*)d_in[22];

    float* ws = (float*)d_ws;
    float*  seqT = ws;                                   // 2,457,600 f32
    float*  diag = seqT + (size_t)B_*N_*D_;              // 144 f32
    __bf16* Qbf  = (__bf16*)(diag + 144);                // 192*800*32 bf16
    __bf16* Kbf  = Qbf + (size_t)NWH_*WS_*32;            // 192*800*32 bf16
    float*  Vf   = (float*)(Kbf + (size_t)NWH_*WS_*32);  // 192*800*24 f32
    __bf16* Vt   = (__bf16*)(Vf + (size_t)NWH_*WS_*24);  // 192*32*800 bf16
    __bf16* OW   = Vt + (size_t)NWH_*32*WS_;             // 51200*96 bf16
    __bf16* wqB  = OW + (size_t)B_*N_*96;                // 224*64
    __bf16* woB  = wqB + 224*64;                         // 48*96
    __bf16* f1B  = woB + 48*96;                          // 48*64
    __bf16* f2B  = f1B + 48*64;                          // 48*64
    __bf16* wfB  = f2B + 48*64;                          // 96*64
    float*  att1 = Vf;                                   // alias: Vf dead after k_vt

    float* out1 = (float*)d_out;               // [B,D,H,W]
    float* out2 = out1 + (size_t)B_*D_*N_;     // [B,N,96]

    k_diag<<<1, 128, 0, stream>>>(E_mat, F_mat, w_e, b_e, w_f, b_f, diag);
    k_wprep<<<32, 256, 0, stream>>>(w_qkv, w_out, ff_w1, ff_w2, w_fin,
                                    wqB, woB, f1B, f2B, wfB);
    k_conv<<<800, 256, 0, stream>>>(x, conv_w, conv_b, prelu_a, seqT);
    k_qkv<<<400, 256, 0, stream>>>(seqT, wqB, ln1_g, ln1_b, diag, Qbf, Kbf, Vf);
    k_vt<<<NWH_*13, 256, 0, stream>>>(Vf, Vt);
    k_attn<<<2400, 256, 0, stream>>>(Qbf, Kbf, Vt, OW);
    k_tail<<<400, 256, 0, stream>>>(seqT, OW, woB, b_out, ln2_g, ln2_b,
                                    f1B, ff_b1, f2B, ff_b2, wfB, b_fin,
                                    att1, out2);
    k_highpass<<<800, 256, 0, stream>>>(seqT, att1, out1);
}

// Round 5
// 113.626 us; speedup vs baseline: 9.3741x; 1.3027x over previous
//
#include <hip/hip_runtime.h>
#include <hip/hip_bf16.h>

#define B_    2
#define CIN_  5
#define H_    160
#define W_    160
#define N_    25600        // H*W
#define D_    48
#define NW_   32
#define WS_   800
#define HEADS_ 3
#define DH_   24
#define INNER_ 72
#define NWH_  192          // B*NW*HEADS

typedef __bf16 bf16x8 __attribute__((ext_vector_type(8)));
typedef __bf16 bf16x2 __attribute__((ext_vector_type(2)));
typedef float  f32x4  __attribute__((ext_vector_type(4)));

#define MFMA(a,b,c) __builtin_amdgcn_mfma_f32_16x16x32_bf16((a),(b),(c),0,0,0)

__device__ __forceinline__ float fast_exp2(float x) {
#if __has_builtin(__builtin_amdgcn_exp2f)
    return __builtin_amdgcn_exp2f(x);
#else
    return exp2f(x);
#endif
}

// ---------------- K0: e_diag / f_diag precompute ----------------
__global__ void k_diag(const float* __restrict__ Em, const float* __restrict__ Fm,
                       const float* __restrict__ we, const float* __restrict__ be,
                       const float* __restrict__ wf, const float* __restrict__ bf,
                       float* __restrict__ diag) {
    int t = threadIdx.x;
    if (t < 72) {
        int h = t / 24, d = t % 24;
        float se = be[d], sf = bf[d];
        for (int w = 0; w < 30; ++w) {
            se += Em[(h*24+d)*30 + w] * we[d*30 + w];
            sf += Fm[(h*24+d)*30 + w] * wf[d*30 + w];
        }
        diag[t]      = se;
        diag[72 + t] = sf;
    }
}

// ---------------- K0b: weight prep -> zero-padded bf16 ----------------
__global__ __launch_bounds__(256) void k_wprep(const float* __restrict__ wqkv,
                                               const float* __restrict__ w_out,
                                               const float* __restrict__ fw1,
                                               const float* __restrict__ fw2,
                                               const float* __restrict__ wfin,
                                               __bf16* __restrict__ wqB,   // [224][64]
                                               __bf16* __restrict__ woB,   // [48][96]
                                               __bf16* __restrict__ f1B,   // [48][64]
                                               __bf16* __restrict__ f2B,   // [48][64]
                                               __bf16* __restrict__ wfB) { // [96][64]
    int t = blockIdx.x*256 + threadIdx.x, stride = gridDim.x*256;
    for (int i = t; i < 224*64; i += stride) { int o=i>>6, c=i&63; wqB[i] = (o<216 && c<48)? (__bf16)wqkv[o*48+c] : (__bf16)0.f; }
    for (int i = t; i < 48*96;  i += stride) { int o=i/96, c=i%96; woB[i] = (c<72)? (__bf16)w_out[o*72+c] : (__bf16)0.f; }
    for (int i = t; i < 48*64;  i += stride) { int o=i>>6, c=i&63; f1B[i] = (c<48)? (__bf16)fw1[o*48+c] : (__bf16)0.f; }
    for (int i = t; i < 48*64;  i += stride) { int o=i>>6, c=i&63; f2B[i] = (c<48)? (__bf16)fw2[o*48+c] : (__bf16)0.f; }
    for (int i = t; i < 96*64;  i += stride) { int o=i>>6, c=i&63; wfB[i] = (c<48)? (__bf16)wfin[o*48+c] : (__bf16)0.f; }
}

// ---------------- K1: conv3x3 + PReLU -> seqT [B,N,D] ----------------
__global__ __launch_bounds__(256) void k_conv(const float* __restrict__ x,
                                              const float* __restrict__ cw,
                                              const float* __restrict__ cb,
                                              const float* __restrict__ pa,
                                              float* __restrict__ seqT) {
    __shared__ float T[64][49];
    __shared__ float cwL[48*45];
    __shared__ float cbL[48];
    int t  = threadIdx.x;
    int blk = blockIdx.x;              // 0..799
    int b  = blk / 400;
    int n0 = (blk % 400) * 64;
    for (int f = t; f < 48*45; f += 256) cwL[f] = cw[f];
    if (t < 48) cbL[t] = cb[t];
    __syncthreads();

    int px = t & 63;
    int wv = t >> 6;                   // 0..3, handles oc [wv*12, wv*12+12)
    int n  = n0 + px;
    int y  = n / W_, xx = n % W_;
    float a = pa[0];

    float patch[45];
    #pragma unroll
    for (int ic = 0; ic < 5; ++ic)
      #pragma unroll
      for (int ky = 0; ky < 3; ++ky)
        #pragma unroll
        for (int kx = 0; kx < 3; ++kx) {
            int yy = y + ky - 1, xc = xx + kx - 1;
            float v = 0.f;
            if (yy >= 0 && yy < H_ && xc >= 0 && xc < W_)
                v = x[((size_t)(b*CIN_ + ic)*H_ + yy)*W_ + xc];
            patch[(ic*3+ky)*3+kx] = v;
        }
    for (int oi = 0; oi < 12; ++oi) {
        int oc = wv*12 + oi;
        float acc = cbL[oc];
        #pragma unroll
        for (int k = 0; k < 45; ++k) acc += patch[k] * cwL[oc*45 + k];
        acc = acc >= 0.f ? acc : a * acc;
        T[px][oc] = acc;
    }
    __syncthreads();
    for (int i = 0; i < 12; ++i) {
        int f = t + i*256;             // < 3072
        int p = f / 48, c = f % 48;
        seqT[(size_t)(b*N_ + n0 + p)*D_ + c] = T[p][c];
    }
}

// ---------------- K2: MFMA LN1 + QKV (wave = 32 rows) ----------------
__global__ __launch_bounds__(256) void k_qkv(const float* __restrict__ seqT,
                                             const __bf16* __restrict__ wqB,
                                             const float* __restrict__ g1,
                                             const float* __restrict__ b1,
                                             const float* __restrict__ diag,
                                             __bf16* __restrict__ Qbf,
                                             __bf16* __restrict__ Kbf,
                                             float* __restrict__ Vf) {
    __shared__ __bf16 xfer[4][2048];           // per-wave 32x64 bf16, swizzled
    int t = threadIdx.x, wv = t>>6, lane = t&63, g = lane>>4, s = lane&15;
    int row0 = (blockIdx.x*4 + wv) * 32;
    char* xb = (char*)&xfer[wv][0];

    int b = row0 / N_, nrem = row0 % N_;
    int w = nrem / WS_, i0 = nrem % WS_;       // 32 | 800: all rows same window
    size_t headbase = (size_t)((b*NW_ + w)*HEADS_);

    // load x tile in C-layout + LN1
    float xr[2][3][4];
    #pragma unroll
    for (int m = 0; m < 2; ++m)
      #pragma unroll
      for (int n = 0; n < 3; ++n)
        #pragma unroll
        for (int r = 0; r < 4; ++r)
          xr[m][n][r] = seqT[(size_t)(row0 + m*16 + g*4 + r)*48 + n*16 + s];

    float g1v[3], b1v[3];
    #pragma unroll
    for (int n = 0; n < 3; ++n) { g1v[n] = g1[n*16+s]; b1v[n] = b1[n*16+s]; }

    #pragma unroll
    for (int m = 0; m < 2; ++m)
      #pragma unroll
      for (int r = 0; r < 4; ++r) {
        float sm = xr[m][0][r] + xr[m][1][r] + xr[m][2][r];
        float sq = xr[m][0][r]*xr[m][0][r] + xr[m][1][r]*xr[m][1][r] + xr[m][2][r]*xr[m][2][r];
        #pragma unroll
        for (int msk = 1; msk < 16; msk <<= 1) { sm += __shfl_xor(sm, msk); sq += __shfl_xor(sq, msk); }
        float mean = sm * (1.f/48.f);
        float var  = sq * (1.f/48.f) - mean*mean;
        float rs   = rsqrtf(var + 1e-5f);
        int row = m*16 + g*4 + r;
        int sw  = ((g*4+r)&7) << 4;
        #pragma unroll
        for (int n = 0; n < 3; ++n) {
            float yn = (xr[m][n][r] - mean) * rs * g1v[n] + b1v[n];
            *(__bf16*)(xb + ((row*128 + (n*16+s)*2) ^ sw)) = (__bf16)yn;
        }
        *(__bf16*)(xb + ((row*128 + (48+s)*2) ^ sw)) = (__bf16)0.f;  // K-pad
      }

    // A-frags from LDS
    bf16x8 af[2][2];
    #pragma unroll
    for (int m = 0; m < 2; ++m)
      #pragma unroll
      for (int kc = 0; kc < 2; ++kc)
        af[m][kc] = *(const bf16x8*)(xb + (((m*16+s)*128 + kc*64 + g*16) ^ ((s&7)<<4)));

    const bf16x8* WQ4 = (const bf16x8*)wqB;
    // 24^-0.5 * log2(e): fold attention scale AND exp2 conversion into Q
    const float SCALE = 0.2944889919f;

    #pragma unroll 2
    for (int n = 0; n < 14; ++n) {
        bf16x8 wb0 = WQ4[(n*16+s)*8 + g];
        bf16x8 wb1 = WQ4[(n*16+s)*8 + 4 + g];
        f32x4 c0 = {0.f,0.f,0.f,0.f}, c1 = {0.f,0.f,0.f,0.f};
        c0 = MFMA(af[0][0], wb0, c0); c0 = MFMA(af[0][1], wb1, c0);
        c1 = MFMA(af[1][0], wb0, c1); c1 = MFMA(af[1][1], wb1, c1);
        int o = n*16 + s;
        if (o < 216) {
            int h = o/72, j = o%72, part = j/24, d = j%24;
            size_t rbase = (headbase + h)*WS_ + i0;
            float mul = (part==0) ? SCALE : ((part==1) ? diag[h*24+d] : diag[72+h*24+d]);
            #pragma unroll
            for (int m = 0; m < 2; ++m) {
                f32x4 c = m ? c1 : c0;
                #pragma unroll
                for (int r = 0; r < 4; ++r) {
                    size_t rq = rbase + m*16 + g*4 + r;
                    float val = c[r] * mul;
                    if      (part == 0) Qbf[rq*32 + d] = (__bf16)val;
                    else if (part == 1) Kbf[rq*32 + d] = (__bf16)val;
                    else                Vf [rq*24 + d] = val;
                }
            }
        }
    }
    // Q/K zero-pad cols 24..31 (32 rows x 24 slots = 768)
    #pragma unroll
    for (int it = 0; it < 12; ++it) {
        int idx = lane + it*64;
        int rl = idx/24, cc = idx%24;
        int hh = cc>>3, dd = 24 + (cc&7);
        size_t rq = (headbase + hh)*WS_ + i0 + rl;
        Qbf[rq*32 + dd] = (__bf16)0.f;
        Kbf[rq*32 + dd] = (__bf16)0.f;
    }
}

// ---------------- K2b: transpose V -> bf16 Vt[wh][32][800]; row 24 = ones ----------------
__global__ __launch_bounds__(256) void k_vt(const float* __restrict__ Vf,
                                            __bf16* __restrict__ Vt) {
    __shared__ float L[64*25];
    int bk = blockIdx.x;
    int wh = bk / 13, tile = bk % 13;
    int n0 = tile * 64;
    int nt = (n0 + 64 <= WS_) ? 64 : (WS_ - n0);   // 64 or 32
    int t = threadIdx.x;
    size_t base = ((size_t)wh*WS_ + n0)*24;
    for (int f = t; f < nt*24; f += 256)
        L[(f/24)*25 + (f%24)] = Vf[base + f];
    __syncthreads();
    for (int e = t; e < 2048; e += 256) {
        int d = e >> 6, n = e & 63;
        if (n < nt) {
            __bf16 v;
            if (d < 24)      v = (__bf16)L[n*25 + d];
            else if (d == 24) v = (__bf16)1.0f;      // ones row -> softmax denominator via MFMA
            else              v = (__bf16)0.f;
            Vt[(size_t)wh*32*WS_ + (size_t)d*WS_ + n0 + n] = v;
        }
    }
}

// ---------------- K3: MFMA windowed attention (1 wave = 80 queries) ----------------
__global__ __launch_bounds__(256) void k_attn(const __bf16* __restrict__ Qbf,
                                              const __bf16* __restrict__ Kbf,
                                              const __bf16* __restrict__ Vt,
                                              __bf16* __restrict__ OW) {
    __shared__ __bf16 Plds[4][5][16*40];       // per-wave 5x (16x32 P tile, stride 40)
    int t = threadIdx.x;
    int wv = t >> 6, lane = t & 63;
    int g = lane >> 4, s = lane & 15;
    int task = blockIdx.x * 4 + wv;            // 0..1919 exactly
    int wh = task / 10, qt = task % 10;
    int q0 = qt * 80;

    const bf16x8* Qp = (const bf16x8*)(Qbf + ((size_t)wh*WS_ + q0)*32);
    const bf16x8* Kp = (const bf16x8*)(Kbf + (size_t)wh*WS_*32);
    const bf16x8* Vp = (const bf16x8*)(Vt  + (size_t)wh*32*WS_);

    // 5 A-frags: row = lane&15 (query), k = (lane>>4)*8 + idx
    bf16x8 qa[5];
    #pragma unroll
    for (int i = 0; i < 5; ++i) qa[i] = Qp[(i*16 + s)*4 + g];

    f32x4 o[5][2];
    #pragma unroll
    for (int i = 0; i < 5; ++i) {
        o[i][0] = (f32x4){0.f,0.f,0.f,0.f};
        o[i][1] = (f32x4){0.f,0.f,0.f,0.f};
    }

    // prefetch chunk 0 (interleaved key mapping: ka0 <-> key 2s, ka1 <-> key 2s+1)
    bf16x8 ka0 = Kp[(2*s)*4 + g];
    bf16x8 ka1 = Kp[(2*s+1)*4 + g];
    bf16x8 vb0 = Vp[s*100 + g];
    bf16x8 vb1 = Vp[(16+s)*100 + g];

    for (int c = 0; c < 25; ++c) {
        int cn = (c + 1 < 25) ? c + 1 : 0;     // last-iter reload is harmless
        bf16x8 nk0 = Kp[(cn*32 + 2*s)*4 + g];
        bf16x8 nk1 = Kp[(cn*32 + 2*s+1)*4 + g];
        bf16x8 nv0 = Vp[s*100 + cn*4 + g];
        bf16x8 nv1 = Vp[(16+s)*100 + cn*4 + g];

        #pragma unroll
        for (int i = 0; i < 5; ++i) {
            f32x4 s0 = {0.f,0.f,0.f,0.f}, s1 = {0.f,0.f,0.f,0.f};
            s0 = MFMA(qa[i], ka0, s0);         // col s = key c*32+2s
            s1 = MFMA(qa[i], ka1, s1);         // col s = key c*32+2s+1
            __bf16* myP = &Plds[wv][i][0];
            // C layout: row(query) = g*4+r, col = s; packed write of (key 2s, key 2s+1)
            #pragma unroll
            for (int r = 0; r < 4; ++r) {
                bf16x2 pk;
                pk.x = (__bf16)fast_exp2(s0[r]);
                pk.y = (__bf16)fast_exp2(s1[r]);
                *(bf16x2*)&myP[(g*4+r)*40 + 2*s] = pk;
            }
            // A-frag P[row=s][keys 8g..8g+7] (natural key order)
            bf16x8 pa = *(const bf16x8*)&myP[s*40 + 8*g];
            o[i][0] = MFMA(pa, vb0, o[i][0]);  // d = s
            o[i][1] = MFMA(pa, vb1, o[i][1]);  // d = 16+s (row 24 = ones -> denom at s=8)
        }
        ka0 = nk0; ka1 = nk1; vb0 = nv0; vb1 = nv1;
    }

    int bw = wh / 3, h = wh % 3;
    int b = bw >> 5, w = bw & 31;
    #pragma unroll
    for (int i = 0; i < 5; ++i) {
        #pragma unroll
        for (int r = 0; r < 4; ++r) {
            float den = __shfl(o[i][1][r], (lane & 48) + 8);   // d=24 ones-column
            float inv = 1.f / den;
            int n = w*WS_ + q0 + i*16 + g*4 + r;
            size_t addr = (size_t)(b*N_ + n)*96 + h*24;
            OW[addr + s] = (__bf16)(o[i][0][r] * inv);
            if (s < 8) OW[addr + 16 + s] = (__bf16)(o[i][1][r] * inv);
            if (h == 0) {                      // write K-pad cols 72..95
                size_t pbase = (size_t)(b*N_ + n)*96;
                OW[pbase + 72 + s] = (__bf16)0.f;
                if (s < 8) OW[pbase + 88 + s] = (__bf16)0.f;
            }
        }
    }
}

// ---------------- K4: MFMA tail: to_out+res+LN2+MLP+res+final (wave = 32 rows) ----------------
__global__ __launch_bounds__(256) void k_tail(const float* __restrict__ seqT,
                                              const __bf16* __restrict__ OW,
                                              const __bf16* __restrict__ woB,
                                              const float* __restrict__ b_out,
                                              const float* __restrict__ g2,
                                              const float* __restrict__ b2,
                                              const __bf16* __restrict__ f1B,
                                              const float* __restrict__ fb1,
                                              const __bf16* __restrict__ f2B,
                                              const float* __restrict__ fb2,
                                              const __bf16* __restrict__ wfB,
                                              const float* __restrict__ bfin,
                                              float* __restrict__ att1,
                                              float* __restrict__ out2) {
    __shared__ __bf16 xfer[4][2048];
    int t = threadIdx.x, wv = t>>6, lane = t&63, g = lane>>4, s = lane&15;
    int row0 = (blockIdx.x*4 + wv) * 32;
    char* xb = (char*)&xfer[wv][0];

    const bf16x8* OW4 = (const bf16x8*)OW;
    const bf16x8* WO4 = (const bf16x8*)woB;
    const bf16x8* F14 = (const bf16x8*)f1B;
    const bf16x8* F24 = (const bf16x8*)f2B;
    const bf16x8* WF4 = (const bf16x8*)wfB;

    // ---- S1: att = ow · w_out^T ----
    bf16x8 aow[2][3];
    #pragma unroll
    for (int m = 0; m < 2; ++m)
      #pragma unroll
      for (int kc = 0; kc < 3; ++kc)
        aow[m][kc] = OW4[(size_t)(row0 + m*16 + s)*12 + kc*4 + g];

    f32x4 s2[2][3];
    #pragma unroll
    for (int n = 0; n < 3; ++n) {
        bf16x8 wb0 = WO4[(n*16+s)*12 + g];
        bf16x8 wb1 = WO4[(n*16+s)*12 + 4 + g];
        bf16x8 wb2 = WO4[(n*16+s)*12 + 8 + g];
        #pragma unroll
        for (int m = 0; m < 2; ++m) {
            f32x4 c = {0.f,0.f,0.f,0.f};
            c = MFMA(aow[m][0], wb0, c);
            c = MFMA(aow[m][1], wb1, c);
            c = MFMA(aow[m][2], wb2, c);
            s2[m][n] = c;
        }
    }
    float bov[3], g2v[3], b2v[3], f1bv[3], f2bv[3];
    #pragma unroll
    for (int n = 0; n < 3; ++n) {
        bov[n] = b_out[n*16+s]; g2v[n] = g2[n*16+s]; b2v[n] = b2[n*16+s];
        f1bv[n] = fb1[n*16+s];  f2bv[n] = fb2[n*16+s];
    }
    #pragma unroll
    for (int m = 0; m < 2; ++m)
      #pragma unroll
      for (int n = 0; n < 3; ++n)
        #pragma unroll
        for (int r = 0; r < 4; ++r)
          s2[m][n][r] += seqT[(size_t)(row0 + m*16 + g*4 + r)*48 + n*16 + s] + bov[n];

    // ---- LN2 -> yn -> LDS ----
    #pragma unroll
    for (int m = 0; m < 2; ++m)
      #pragma unroll
      for (int r = 0; r < 4; ++r) {
        float sm = s2[m][0][r] + s2[m][1][r] + s2[m][2][r];
        float sq = s2[m][0][r]*s2[m][0][r] + s2[m][1][r]*s2[m][1][r] + s2[m][2][r]*s2[m][2][r];
        #pragma unroll
        for (int msk = 1; msk < 16; msk <<= 1) { sm += __shfl_xor(sm, msk); sq += __shfl_xor(sq, msk); }
        float mean = sm * (1.f/48.f);
        float var  = sq * (1.f/48.f) - mean*mean;
        float rs   = rsqrtf(var + 1e-5f);
        int row = m*16 + g*4 + r;
        int sw  = ((g*4+r)&7) << 4;
        #pragma unroll
        for (int n = 0; n < 3; ++n) {
            float yn = (s2[m][n][r] - mean) * rs * g2v[n] + b2v[n];
            *(__bf16*)(xb + ((row*128 + (n*16+s)*2) ^ sw)) = (__bf16)yn;
        }
        *(__bf16*)(xb + ((row*128 + (48+s)*2) ^ sw)) = (__bf16)0.f;
      }

    bf16x8 af[2][2];
    f32x4 hh[2][3];

    // ---- ff1 ----
    #pragma unroll
    for (int m = 0; m < 2; ++m)
      #pragma unroll
      for (int kc = 0; kc < 2; ++kc)
        af[m][kc] = *(const bf16x8*)(xb + (((m*16+s)*128 + kc*64 + g*16) ^ ((s&7)<<4)));
    #pragma unroll
    for (int n = 0; n < 3; ++n) {
        bf16x8 wb0 = F14[(n*16+s)*8 + g];
        bf16x8 wb1 = F14[(n*16+s)*8 + 4 + g];
        #pragma unroll
        for (int m = 0; m < 2; ++m) {
            f32x4 c = {0.f,0.f,0.f,0.f};
            c = MFMA(af[m][0], wb0, c);
            c = MFMA(af[m][1], wb1, c);
            hh[m][n] = c;
        }
    }
    #pragma unroll
    for (int m = 0; m < 2; ++m)
      #pragma unroll
      for (int r = 0; r < 4; ++r) {
        int row = m*16 + g*4 + r;
        int sw  = ((g*4+r)&7) << 4;
        #pragma unroll
        for (int n = 0; n < 3; ++n) {
            float v = hh[m][n][r] + f1bv[n];
            v = v >= 0.f ? v : 0.01f*v;
            *(__bf16*)(xb + ((row*128 + (n*16+s)*2) ^ sw)) = (__bf16)v;
        }
        *(__bf16*)(xb + ((row*128 + (48+s)*2) ^ sw)) = (__bf16)0.f;
      }

    // ---- ff2 + residual -> att1, a1 -> LDS ----
    #pragma unroll
    for (int m = 0; m < 2; ++m)
      #pragma unroll
      for (int kc = 0; kc < 2; ++kc)
        af[m][kc] = *(const bf16x8*)(xb + (((m*16+s)*128 + kc*64 + g*16) ^ ((s&7)<<4)));
    #pragma unroll
    for (int n = 0; n < 3; ++n) {
        bf16x8 wb0 = F24[(n*16+s)*8 + g];
        bf16x8 wb1 = F24[(n*16+s)*8 + 4 + g];
        #pragma unroll
        for (int m = 0; m < 2; ++m) {
            f32x4 c = {0.f,0.f,0.f,0.f};
            c = MFMA(af[m][0], wb0, c);
            c = MFMA(af[m][1], wb1, c);
            hh[m][n] = c;
        }
    }
    #pragma unroll
    for (int m = 0; m < 2; ++m)
      #pragma unroll
      for (int r = 0; r < 4; ++r) {
        int row = m*16 + g*4 + r;
        int sw  = ((g*4+r)&7) << 4;
        #pragma unroll
        for (int n = 0; n < 3; ++n) {
            float a1v = s2[m][n][r] + hh[m][n][r] + f2bv[n];
            att1[(size_t)(row0 + row)*48 + n*16 + s] = a1v;
            *(__bf16*)(xb + ((row*128 + (n*16+s)*2) ^ sw)) = (__bf16)a1v;
        }
        *(__bf16*)(xb + ((row*128 + (48+s)*2) ^ sw)) = (__bf16)0.f;
      }

    // ---- final linear 48 -> 96 ----
    #pragma unroll
    for (int m = 0; m < 2; ++m)
      #pragma unroll
      for (int kc = 0; kc < 2; ++kc)
        af[m][kc] = *(const bf16x8*)(xb + (((m*16+s)*128 + kc*64 + g*16) ^ ((s&7)<<4)));
    #pragma unroll
    for (int n = 0; n < 6; ++n) {
        bf16x8 wb0 = WF4[(n*16+s)*8 + g];
        bf16x8 wb1 = WF4[(n*16+s)*8 + 4 + g];
        float bfv = bfin[n*16+s];
        #pragma unroll
        for (int m = 0; m < 2; ++m) {
            f32x4 c = {0.f,0.f,0.f,0.f};
            c = MFMA(af[m][0], wb0, c);
            c = MFMA(af[m][1], wb1, c);
            #pragma unroll
            for (int r = 0; r < 4; ++r)
                out2[(size_t)(row0 + m*16 + g*4 + r)*96 + n*16 + s] = c[r] + bfv;
        }
    }
}

// ---------------- K5: Highpass = seqT*(1+att1), transposed to [B,D,H,W] ----------------
__global__ __launch_bounds__(256) void k_highpass(const float* __restrict__ seqT,
                                                  const float* __restrict__ att1,
                                                  float* __restrict__ out1) {
    __shared__ float T[64][49];
    int blk = blockIdx.x;              // 0..799
    int b  = blk / 400;
    int n0 = (blk % 400) * 64;
    int t  = threadIdx.x;
    for (int i = 0; i < 12; ++i) {
        int f = t + i*256;             // < 3072
        int p = f / 48, c = f % 48;
        size_t idx = (size_t)(b*N_ + n0 + p)*D_ + c;
        T[p][c] = seqT[idx] * (1.f + att1[idx]);
    }
    __syncthreads();
    for (int i = 0; i < 12; ++i) {
        int g = t + i*256;
        int d = g / 64, nl = g % 64;
        out1[((size_t)b*D_ + d)*N_ + n0 + nl] = T[nl][d];
    }
}

extern "C" void kernel_launch(void* const* d_in, const int* in_sizes, int n_in,
                              void* d_out, int out_size, void* d_ws, size_t ws_size,
                              hipStream_t stream) {
    const float* x      = (const float*)d_in[0];
    const float* conv_w = (const float*)d_in[1];
    const float* conv_b = (const float*)d_in[2];
    const float* prelu_a= (const float*)d_in[3];
    const float* ln1_g  = (const float*)d_in[4];
    const float* ln1_b  = (const float*)d_in[5];
    const float* w_qkv  = (const float*)d_in[6];
    const float* E_mat  = (const float*)d_in[7];
    const float* F_mat  = (const float*)d_in[8];
    const float* w_e    = (const float*)d_in[9];
    const float* b_e    = (const float*)d_in[10];
    const float* w_f    = (const float*)d_in[11];
    const float* b_f    = (const float*)d_in[12];
    const float* w_out  = (const float*)d_in[13];
    const float* b_out  = (const float*)d_in[14];
    const float* ln2_g  = (const float*)d_in[15];
    const float* ln2_b  = (const float*)d_in[16];
    const float* ff_w1  = (const float*)d_in[17];
    const float* ff_b1  = (const float*)d_in[18];
    const float* ff_w2  = (const float*)d_in[19];
    const float* ff_b2  = (const float*)d_in[20];
    const float* w_fin  = (const float*)d_in[21];
    const float* b_fin  = (const float*)d_in[22];

    float* ws = (float*)d_ws;
    float*  seqT = ws;                                   // 2,457,600 f32
    float*  diag = seqT + (size_t)B_*N_*D_;              // 144 f32
    __bf16* Qbf  = (__bf16*)(diag + 144);                // 192*800*32 bf16
    __bf16* Kbf  = Qbf + (size_t)NWH_*WS_*32;            // 192*800*32 bf16
    float*  Vf   = (float*)(Kbf + (size_t)NWH_*WS_*32);  // 192*800*24 f32
    __bf16* Vt   = (__bf16*)(Vf + (size_t)NWH_*WS_*24);  // 192*32*800 bf16
    __bf16* OW   = Vt + (size_t)NWH_*32*WS_;             // 51200*96 bf16
    __bf16* wqB  = OW + (size_t)B_*N_*96;                // 224*64
    __bf16* woB  = wqB + 224*64;                         // 48*96
    __bf16* f1B  = woB + 48*96;                          // 48*64
    __bf16* f2B  = f1B + 48*64;                          // 48*64
    __bf16* wfB  = f2B + 48*64;                          // 96*64
    float*  att1 = Vf;                                   // alias: Vf dead after k_vt

    float* out1 = (float*)d_out;               // [B,D,H,W]
    float* out2 = out1 + (size_t)B_*D_*N_;     // [B,N,96]

    k_diag<<<1, 128, 0, stream>>>(E_mat, F_mat, w_e, b_e, w_f, b_f, diag);
    k_wprep<<<32, 256, 0, stream>>>(w_qkv, w_out, ff_w1, ff_w2, w_fin,
                                    wqB, woB, f1B, f2B, wfB);
    k_conv<<<800, 256, 0, stream>>>(x, conv_w, conv_b, prelu_a, seqT);
    k_qkv<<<400, 256, 0, stream>>>(seqT, wqB, ln1_g, ln1_b, diag, Qbf, Kbf, Vf);
    k_vt<<<NWH_*13, 256, 0, stream>>>(Vf, Vt);
    k_attn<<<480, 256, 0, stream>>>(Qbf, Kbf, Vt, OW);
    k_tail<<<400, 256, 0, stream>>>(seqT, OW, woB, b_out, ln2_g, ln2_b,
                                    f1B, ff_b1, f2B, ff_b2, wfB, b_fin,
                                    att1, out2);
    k_highpass<<<800, 256, 0, stream>>>(seqT, att1, out1);
}

// Round 6
// 108.618 us; speedup vs baseline: 9.8063x; 1.0461x over previous
//
#include <hip/hip_runtime.h>
#include <hip/hip_bf16.h>

#define B_    2
#define CIN_  5
#define H_    160
#define W_    160
#define N_    25600        // H*W
#define D_    48
#define NW_   32
#define WS_   800
#define HEADS_ 3
#define DH_   24
#define INNER_ 72
#define NWH_  192          // B*NW*HEADS

typedef __bf16 bf16x8 __attribute__((ext_vector_type(8)));
typedef float  f32x4  __attribute__((ext_vector_type(4)));

#define MFMA(a,b,c) __builtin_amdgcn_mfma_f32_16x16x32_bf16((a),(b),(c),0,0,0)

__device__ __forceinline__ float fast_exp2(float x) {
#if __has_builtin(__builtin_amdgcn_exp2f)
    return __builtin_amdgcn_exp2f(x);
#else
    return exp2f(x);
#endif
}

// ---------------- K0: e_diag / f_diag precompute ----------------
__global__ void k_diag(const float* __restrict__ Em, const float* __restrict__ Fm,
                       const float* __restrict__ we, const float* __restrict__ be,
                       const float* __restrict__ wf, const float* __restrict__ bf,
                       float* __restrict__ diag) {
    int t = threadIdx.x;
    if (t < 72) {
        int h = t / 24, d = t % 24;
        float se = be[d], sf = bf[d];
        for (int w = 0; w < 30; ++w) {
            se += Em[(h*24+d)*30 + w] * we[d*30 + w];
            sf += Fm[(h*24+d)*30 + w] * wf[d*30 + w];
        }
        diag[t]      = se;
        diag[72 + t] = sf;
    }
}

// ---------------- K0b: weight prep -> zero-padded bf16 ----------------
__global__ __launch_bounds__(256) void k_wprep(const float* __restrict__ wqkv,
                                               const float* __restrict__ w_out,
                                               const float* __restrict__ fw1,
                                               const float* __restrict__ fw2,
                                               const float* __restrict__ wfin,
                                               __bf16* __restrict__ wqB,   // [224][64]
                                               __bf16* __restrict__ woB,   // [48][96]
                                               __bf16* __restrict__ f1B,   // [48][64]
                                               __bf16* __restrict__ f2B,   // [48][64]
                                               __bf16* __restrict__ wfB) { // [96][64]
    int t = blockIdx.x*256 + threadIdx.x, stride = gridDim.x*256;
    for (int i = t; i < 224*64; i += stride) { int o=i>>6, c=i&63; wqB[i] = (o<216 && c<48)? (__bf16)wqkv[o*48+c] : (__bf16)0.f; }
    for (int i = t; i < 48*96;  i += stride) { int o=i/96, c=i%96; woB[i] = (c<72)? (__bf16)w_out[o*72+c] : (__bf16)0.f; }
    for (int i = t; i < 48*64;  i += stride) { int o=i>>6, c=i&63; f1B[i] = (c<48)? (__bf16)fw1[o*48+c] : (__bf16)0.f; }
    for (int i = t; i < 48*64;  i += stride) { int o=i>>6, c=i&63; f2B[i] = (c<48)? (__bf16)fw2[o*48+c] : (__bf16)0.f; }
    for (int i = t; i < 96*64;  i += stride) { int o=i>>6, c=i&63; wfB[i] = (c<48)? (__bf16)wfin[o*48+c] : (__bf16)0.f; }
}

// ---------------- K1: conv3x3 + PReLU -> seqT [B,N,D] ----------------
__global__ __launch_bounds__(256) void k_conv(const float* __restrict__ x,
                                              const float* __restrict__ cw,
                                              const float* __restrict__ cb,
                                              const float* __restrict__ pa,
                                              float* __restrict__ seqT) {
    __shared__ float T[64][49];
    __shared__ float cwL[48*45];
    __shared__ float cbL[48];
    int t  = threadIdx.x;
    int blk = blockIdx.x;              // 0..799
    int b  = blk / 400;
    int n0 = (blk % 400) * 64;
    for (int f = t; f < 48*45; f += 256) cwL[f] = cw[f];
    if (t < 48) cbL[t] = cb[t];
    __syncthreads();

    int px = t & 63;
    int wv = t >> 6;                   // 0..3, handles oc [wv*12, wv*12+12)
    int n  = n0 + px;
    int y  = n / W_, xx = n % W_;
    float a = pa[0];

    float patch[45];
    #pragma unroll
    for (int ic = 0; ic < 5; ++ic)
      #pragma unroll
      for (int ky = 0; ky < 3; ++ky)
        #pragma unroll
        for (int kx = 0; kx < 3; ++kx) {
            int yy = y + ky - 1, xc = xx + kx - 1;
            float v = 0.f;
            if (yy >= 0 && yy < H_ && xc >= 0 && xc < W_)
                v = x[((size_t)(b*CIN_ + ic)*H_ + yy)*W_ + xc];
            patch[(ic*3+ky)*3+kx] = v;
        }
    for (int oi = 0; oi < 12; ++oi) {
        int oc = wv*12 + oi;
        float acc = cbL[oc];
        #pragma unroll
        for (int k = 0; k < 45; ++k) acc += patch[k] * cwL[oc*45 + k];
        acc = acc >= 0.f ? acc : a * acc;
        T[px][oc] = acc;
    }
    __syncthreads();
    for (int i = 0; i < 12; ++i) {
        int f = t + i*256;             // < 3072
        int p = f / 48, c = f % 48;
        seqT[(size_t)(b*N_ + n0 + p)*D_ + c] = T[p][c];
    }
}

// ---------------- K2: MFMA LN1 + QKV (wave = 32 rows) ----------------
// K rows permuted within each 32-key chunk: key j -> pos 16*((j>>2)&1) + 4*(j>>3) + (j&3)
// so that swapped-QKT MFMA output registers ARE the PV A-fragment (see k_attn).
// V written directly transposed (bf16 Vt[wh][32][800], row 24 = ones, 25..31 = 0).
__global__ __launch_bounds__(256) void k_qkv(const float* __restrict__ seqT,
                                             const __bf16* __restrict__ wqB,
                                             const float* __restrict__ g1,
                                             const float* __restrict__ b1,
                                             const float* __restrict__ diag,
                                             __bf16* __restrict__ Qbf,
                                             __bf16* __restrict__ Kbf,
                                             __bf16* __restrict__ Vt) {
    __shared__ __bf16 xfer[4][2048];           // per-wave 32x64 bf16, swizzled
    int t = threadIdx.x, wv = t>>6, lane = t&63, g = lane>>4, s = lane&15;
    int row0 = (blockIdx.x*4 + wv) * 32;
    char* xb = (char*)&xfer[wv][0];

    int b = row0 / N_, nrem = row0 % N_;
    int w = nrem / WS_, i0 = nrem % WS_;       // 32 | 800: all rows same window
    size_t headbase = (size_t)((b*NW_ + w)*HEADS_);

    // load x tile in C-layout + LN1
    float xr[2][3][4];
    #pragma unroll
    for (int m = 0; m < 2; ++m)
      #pragma unroll
      for (int n = 0; n < 3; ++n)
        #pragma unroll
        for (int r = 0; r < 4; ++r)
          xr[m][n][r] = seqT[(size_t)(row0 + m*16 + g*4 + r)*48 + n*16 + s];

    float g1v[3], b1v[3];
    #pragma unroll
    for (int n = 0; n < 3; ++n) { g1v[n] = g1[n*16+s]; b1v[n] = b1[n*16+s]; }

    #pragma unroll
    for (int m = 0; m < 2; ++m)
      #pragma unroll
      for (int r = 0; r < 4; ++r) {
        float sm = xr[m][0][r] + xr[m][1][r] + xr[m][2][r];
        float sq = xr[m][0][r]*xr[m][0][r] + xr[m][1][r]*xr[m][1][r] + xr[m][2][r]*xr[m][2][r];
        #pragma unroll
        for (int msk = 1; msk < 16; msk <<= 1) { sm += __shfl_xor(sm, msk); sq += __shfl_xor(sq, msk); }
        float mean = sm * (1.f/48.f);
        float var  = sq * (1.f/48.f) - mean*mean;
        float rs   = rsqrtf(var + 1e-5f);
        int row = m*16 + g*4 + r;
        int sw  = ((g*4+r)&7) << 4;
        #pragma unroll
        for (int n = 0; n < 3; ++n) {
            float yn = (xr[m][n][r] - mean) * rs * g1v[n] + b1v[n];
            *(__bf16*)(xb + ((row*128 + (n*16+s)*2) ^ sw)) = (__bf16)yn;
        }
        *(__bf16*)(xb + ((row*128 + (48+s)*2) ^ sw)) = (__bf16)0.f;  // K-pad
      }

    // A-frags from LDS
    bf16x8 af[2][2];
    #pragma unroll
    for (int m = 0; m < 2; ++m)
      #pragma unroll
      for (int kc = 0; kc < 2; ++kc)
        af[m][kc] = *(const bf16x8*)(xb + (((m*16+s)*128 + kc*64 + g*16) ^ ((s&7)<<4)));

    const bf16x8* WQ4 = (const bf16x8*)wqB;
    // 24^-0.5 * log2(e): fold attention scale AND exp2 conversion into Q
    const float SCALE = 0.2944889919f;

    #pragma unroll 2
    for (int n = 0; n < 14; ++n) {
        bf16x8 wb0 = WQ4[(n*16+s)*8 + g];
        bf16x8 wb1 = WQ4[(n*16+s)*8 + 4 + g];
        f32x4 c0 = {0.f,0.f,0.f,0.f}, c1 = {0.f,0.f,0.f,0.f};
        c0 = MFMA(af[0][0], wb0, c0); c0 = MFMA(af[0][1], wb1, c0);
        c1 = MFMA(af[1][0], wb0, c1); c1 = MFMA(af[1][1], wb1, c1);
        int o = n*16 + s;
        if (o < 216) {
            int h = o/72, j = o%72, part = j/24, d = j%24;
            size_t rbase = (headbase + h)*WS_ + i0;
            float mul = (part==0) ? SCALE : ((part==1) ? diag[h*24+d] : diag[72+h*24+d]);
            #pragma unroll
            for (int m = 0; m < 2; ++m) {
                f32x4 c = m ? c1 : c0;
                #pragma unroll
                for (int r = 0; r < 4; ++r) {
                    float val = c[r] * mul;
                    if (part == 0) {
                        size_t rq = rbase + m*16 + g*4 + r;
                        Qbf[rq*32 + d] = (__bf16)val;
                    } else if (part == 1) {
                        // permuted key position within the 32-row chunk
                        int p5 = 16*(g&1) + 8*m + 4*(g>>1) + r;
                        size_t rq = rbase + p5;
                        Kbf[rq*32 + d] = (__bf16)val;
                    } else {
                        // direct transposed V write: Vt[wh][d][i0+rowlocal]
                        Vt[(headbase + h)*((size_t)32*WS_) + (size_t)d*WS_
                           + i0 + m*16 + g*4 + r] = (__bf16)val;
                    }
                }
            }
        }
    }
    // Q/K zero-pad cols 24..31, Vt pad rows 24..31 (row 24 = ones)
    #pragma unroll
    for (int it = 0; it < 12; ++it) {
        int idx = lane + it*64;
        int rl = idx/24, cc = idx%24;
        int hh = cc>>3, dd = 24 + (cc&7);
        size_t rq = (headbase + hh)*WS_ + i0 + rl;
        Qbf[rq*32 + dd] = (__bf16)0.f;
        Kbf[rq*32 + dd] = (__bf16)0.f;
        Vt[(headbase + hh)*((size_t)32*WS_) + (size_t)dd*WS_ + i0 + rl] =
            (dd == 24) ? (__bf16)1.0f : (__bf16)0.f;
    }
}

// ---------------- K3: MFMA windowed attention, register-resident P ----------------
// Swapped QK^T: S = MFMA(K, Q) -> lane (g,s) holds scores for query s,
// keys (permuted) = hardware-k slots 8g..8g+7. After exp2, that register IS
// the PV A-fragment. No LDS, no cross-lane traffic until the final epilogue.
__global__ __launch_bounds__(256) void k_attn(const __bf16* __restrict__ Qbf,
                                              const __bf16* __restrict__ Kbf,
                                              const __bf16* __restrict__ Vt,
                                              __bf16* __restrict__ OW) {
    int t = threadIdx.x;
    int wv = t >> 6, lane = t & 63;
    int g = lane >> 4, s = lane & 15;
    int task = blockIdx.x * 4 + wv;            // 0..1919 exactly
    int wh = task / 10, qt = task % 10;
    int q0 = qt * 80;

    const bf16x8* Qp = (const bf16x8*)(Qbf + ((size_t)wh*WS_ + q0)*32);
    const bf16x8* Kp = (const bf16x8*)(Kbf + (size_t)wh*WS_*32);
    const bf16x8* Vp = (const bf16x8*)(Vt  + (size_t)wh*32*WS_);

    // Q as B-operand: col = query = lane&15
    bf16x8 qb[5];
    #pragma unroll
    for (int i = 0; i < 5; ++i) qb[i] = Qp[(i*16 + s)*4 + g];

    f32x4 o[5][2];
    #pragma unroll
    for (int i = 0; i < 5; ++i) {
        o[i][0] = (f32x4){0.f,0.f,0.f,0.f};
        o[i][1] = (f32x4){0.f,0.f,0.f,0.f};
    }

    // prefetch chunk 0
    bf16x8 ka0 = Kp[s*4 + g];
    bf16x8 ka1 = Kp[(16 + s)*4 + g];
    bf16x8 vb0 = Vp[s*100 + g];
    bf16x8 vb1 = Vp[(16+s)*100 + g];

    for (int c = 0; c < 25; ++c) {
        int cn = (c + 1 < 25) ? c + 1 : 0;     // last-iter reload is harmless
        bf16x8 nk0 = Kp[(cn*32 + s)*4 + g];
        bf16x8 nk1 = Kp[(cn*32 + 16 + s)*4 + g];
        bf16x8 nv0 = Vp[s*100 + cn*4 + g];
        bf16x8 nv1 = Vp[(16+s)*100 + cn*4 + g];

        #pragma unroll
        for (int i = 0; i < 5; ++i) {
            f32x4 s0 = {0.f,0.f,0.f,0.f}, s1 = {0.f,0.f,0.f,0.f};
            s0 = MFMA(ka0, qb[i], s0);         // C[m=T0 row 4g+r][n=query s]
            s1 = MFMA(ka1, qb[i], s1);         // C[m=T1 row 4g+r][n=query s]
            // K permutation => s0[r] ~ key 8g+r, s1[r] ~ key 8g+4+r:
            // exactly A-frag slots (row=s=query, k=8g+idx)
            bf16x8 pa;
            #pragma unroll
            for (int r = 0; r < 4; ++r) {
                pa[r]     = (__bf16)fast_exp2(s0[r]);
                pa[r + 4] = (__bf16)fast_exp2(s1[r]);
            }
            o[i][0] = MFMA(pa, vb0, o[i][0]);  // O[q=4g+r][d=s]
            o[i][1] = MFMA(pa, vb1, o[i][1]);  // d=16+s (row 24 ones -> denom at s=8)
        }
        ka0 = nk0; ka1 = nk1; vb0 = nv0; vb1 = nv1;
    }

    int bw = wh / 3, h = wh % 3;
    int b = bw >> 5, w = bw & 31;
    #pragma unroll
    for (int i = 0; i < 5; ++i) {
        #pragma unroll
        for (int r = 0; r < 4; ++r) {
            float den = __shfl(o[i][1][r], (lane & 48) + 8);   // d=24 ones-column
            float inv = 1.f / den;
            int n = w*WS_ + q0 + i*16 + g*4 + r;
            size_t addr = (size_t)(b*N_ + n)*96 + h*24;
            OW[addr + s] = (__bf16)(o[i][0][r] * inv);
            if (s < 8) OW[addr + 16 + s] = (__bf16)(o[i][1][r] * inv);
            if (h == 0) {                      // write K-pad cols 72..95
                size_t pbase = (size_t)(b*N_ + n)*96;
                OW[pbase + 72 + s] = (__bf16)0.f;
                if (s < 8) OW[pbase + 88 + s] = (__bf16)0.f;
            }
        }
    }
}

// ---------------- K4: MFMA tail: to_out+res+LN2+MLP+res+final (wave = 32 rows) ----------------
__global__ __launch_bounds__(256) void k_tail(const float* __restrict__ seqT,
                                              const __bf16* __restrict__ OW,
                                              const __bf16* __restrict__ woB,
                                              const float* __restrict__ b_out,
                                              const float* __restrict__ g2,
                                              const float* __restrict__ b2,
                                              const __bf16* __restrict__ f1B,
                                              const float* __restrict__ fb1,
                                              const __bf16* __restrict__ f2B,
                                              const float* __restrict__ fb2,
                                              const __bf16* __restrict__ wfB,
                                              const float* __restrict__ bfin,
                                              float* __restrict__ att1,
                                              float* __restrict__ out2) {
    __shared__ __bf16 xfer[4][2048];
    int t = threadIdx.x, wv = t>>6, lane = t&63, g = lane>>4, s = lane&15;
    int row0 = (blockIdx.x*4 + wv) * 32;
    char* xb = (char*)&xfer[wv][0];

    const bf16x8* OW4 = (const bf16x8*)OW;
    const bf16x8* WO4 = (const bf16x8*)woB;
    const bf16x8* F14 = (const bf16x8*)f1B;
    const bf16x8* F24 = (const bf16x8*)f2B;
    const bf16x8* WF4 = (const bf16x8*)wfB;

    // ---- S1: att = ow · w_out^T ----
    bf16x8 aow[2][3];
    #pragma unroll
    for (int m = 0; m < 2; ++m)
      #pragma unroll
      for (int kc = 0; kc < 3; ++kc)
        aow[m][kc] = OW4[(size_t)(row0 + m*16 + s)*12 + kc*4 + g];

    f32x4 s2[2][3];
    #pragma unroll
    for (int n = 0; n < 3; ++n) {
        bf16x8 wb0 = WO4[(n*16+s)*12 + g];
        bf16x8 wb1 = WO4[(n*16+s)*12 + 4 + g];
        bf16x8 wb2 = WO4[(n*16+s)*12 + 8 + g];
        #pragma unroll
        for (int m = 0; m < 2; ++m) {
            f32x4 c = {0.f,0.f,0.f,0.f};
            c = MFMA(aow[m][0], wb0, c);
            c = MFMA(aow[m][1], wb1, c);
            c = MFMA(aow[m][2], wb2, c);
            s2[m][n] = c;
        }
    }
    float bov[3], g2v[3], b2v[3], f1bv[3], f2bv[3];
    #pragma unroll
    for (int n = 0; n < 3; ++n) {
        bov[n] = b_out[n*16+s]; g2v[n] = g2[n*16+s]; b2v[n] = b2[n*16+s];
        f1bv[n] = fb1[n*16+s];  f2bv[n] = fb2[n*16+s];
    }
    #pragma unroll
    for (int m = 0; m < 2; ++m)
      #pragma unroll
      for (int n = 0; n < 3; ++n)
        #pragma unroll
        for (int r = 0; r < 4; ++r)
          s2[m][n][r] += seqT[(size_t)(row0 + m*16 + g*4 + r)*48 + n*16 + s] + bov[n];

    // ---- LN2 -> yn -> LDS ----
    #pragma unroll
    for (int m = 0; m < 2; ++m)
      #pragma unroll
      for (int r = 0; r < 4; ++r) {
        float sm = s2[m][0][r] + s2[m][1][r] + s2[m][2][r];
        float sq = s2[m][0][r]*s2[m][0][r] + s2[m][1][r]*s2[m][1][r] + s2[m][2][r]*s2[m][2][r];
        #pragma unroll
        for (int msk = 1; msk < 16; msk <<= 1) { sm += __shfl_xor(sm, msk); sq += __shfl_xor(sq, msk); }
        float mean = sm * (1.f/48.f);
        float var  = sq * (1.f/48.f) - mean*mean;
        float rs   = rsqrtf(var + 1e-5f);
        int row = m*16 + g*4 + r;
        int sw  = ((g*4+r)&7) << 4;
        #pragma unroll
        for (int n = 0; n < 3; ++n) {
            float yn = (s2[m][n][r] - mean) * rs * g2v[n] + b2v[n];
            *(__bf16*)(xb + ((row*128 + (n*16+s)*2) ^ sw)) = (__bf16)yn;
        }
        *(__bf16*)(xb + ((row*128 + (48+s)*2) ^ sw)) = (__bf16)0.f;
      }

    bf16x8 af[2][2];
    f32x4 hh[2][3];

    // ---- ff1 ----
    #pragma unroll
    for (int m = 0; m < 2; ++m)
      #pragma unroll
      for (int kc = 0; kc < 2; ++kc)
        af[m][kc] = *(const bf16x8*)(xb + (((m*16+s)*128 + kc*64 + g*16) ^ ((s&7)<<4)));
    #pragma unroll
    for (int n = 0; n < 3; ++n) {
        bf16x8 wb0 = F14[(n*16+s)*8 + g];
        bf16x8 wb1 = F14[(n*16+s)*8 + 4 + g];
        #pragma unroll
        for (int m = 0; m < 2; ++m) {
            f32x4 c = {0.f,0.f,0.f,0.f};
            c = MFMA(af[m][0], wb0, c);
            c = MFMA(af[m][1], wb1, c);
            hh[m][n] = c;
        }
    }
    #pragma unroll
    for (int m = 0; m < 2; ++m)
      #pragma unroll
      for (int r = 0; r < 4; ++r) {
        int row = m*16 + g*4 + r;
        int sw  = ((g*4+r)&7) << 4;
        #pragma unroll
        for (int n = 0; n < 3; ++n) {
            float v = hh[m][n][r] + f1bv[n];
            v = v >= 0.f ? v : 0.01f*v;
            *(__bf16*)(xb + ((row*128 + (n*16+s)*2) ^ sw)) = (__bf16)v;
        }
        *(__bf16*)(xb + ((row*128 + (48+s)*2) ^ sw)) = (__bf16)0.f;
      }

    // ---- ff2 + residual -> att1, a1 -> LDS ----
    #pragma unroll
    for (int m = 0; m < 2; ++m)
      #pragma unroll
      for (int kc = 0; kc < 2; ++kc)
        af[m][kc] = *(const bf16x8*)(xb + (((m*16+s)*128 + kc*64 + g*16) ^ ((s&7)<<4)));
    #pragma unroll
    for (int n = 0; n < 3; ++n) {
        bf16x8 wb0 = F24[(n*16+s)*8 + g];
        bf16x8 wb1 = F24[(n*16+s)*8 + 4 + g];
        #pragma unroll
        for (int m = 0; m < 2; ++m) {
            f32x4 c = {0.f,0.f,0.f,0.f};
            c = MFMA(af[m][0], wb0, c);
            c = MFMA(af[m][1], wb1, c);
            hh[m][n] = c;
        }
    }
    #pragma unroll
    for (int m = 0; m < 2; ++m)
      #pragma unroll
      for (int r = 0; r < 4; ++r) {
        int row = m*16 + g*4 + r;
        int sw  = ((g*4+r)&7) << 4;
        #pragma unroll
        for (int n = 0; n < 3; ++n) {
            float a1v = s2[m][n][r] + hh[m][n][r] + f2bv[n];
            att1[(size_t)(row0 + row)*48 + n*16 + s] = a1v;
            *(__bf16*)(xb + ((row*128 + (n*16+s)*2) ^ sw)) = (__bf16)a1v;
        }
        *(__bf16*)(xb + ((row*128 + (48+s)*2) ^ sw)) = (__bf16)0.f;
      }

    // ---- final linear 48 -> 96 ----
    #pragma unroll
    for (int m = 0; m < 2; ++m)
      #pragma unroll
      for (int kc = 0; kc < 2; ++kc)
        af[m][kc] = *(const bf16x8*)(xb + (((m*16+s)*128 + kc*64 + g*16) ^ ((s&7)<<4)));
    #pragma unroll
    for (int n = 0; n < 6; ++n) {
        bf16x8 wb0 = WF4[(n*16+s)*8 + g];
        bf16x8 wb1 = WF4[(n*16+s)*8 + 4 + g];
        float bfv = bfin[n*16+s];
        #pragma unroll
        for (int m = 0; m < 2; ++m) {
            f32x4 c = {0.f,0.f,0.f,0.f};
            c = MFMA(af[m][0], wb0, c);
            c = MFMA(af[m][1], wb1, c);
            #pragma unroll
            for (int r = 0; r < 4; ++r)
                out2[(size_t)(row0 + m*16 + g*4 + r)*96 + n*16 + s] = c[r] + bfv;
        }
    }
}

// ---------------- K5: Highpass = seqT*(1+att1), transposed to [B,D,H,W] ----------------
__global__ __launch_bounds__(256) void k_highpass(const float* __restrict__ seqT,
                                                  const float* __restrict__ att1,
                                                  float* __restrict__ out1) {
    __shared__ float T[64][49];
    int blk = blockIdx.x;              // 0..799
    int b  = blk / 400;
    int n0 = (blk % 400) * 64;
    int t  = threadIdx.x;
    for (int i = 0; i < 12; ++i) {
        int f = t + i*256;             // < 3072
        int p = f / 48, c = f % 48;
        size_t idx = (size_t)(b*N_ + n0 + p)*D_ + c;
        T[p][c] = seqT[idx] * (1.f + att1[idx]);
    }
    __syncthreads();
    for (int i = 0; i < 12; ++i) {
        int g = t + i*256;
        int d = g / 64, nl = g % 64;
        out1[((size_t)b*D_ + d)*N_ + n0 + nl] = T[nl][d];
    }
}

extern "C" void kernel_launch(void* const* d_in, const int* in_sizes, int n_in,
                              void* d_out, int out_size, void* d_ws, size_t ws_size,
                              hipStream_t stream) {
    const float* x      = (const float*)d_in[0];
    const float* conv_w = (const float*)d_in[1];
    const float* conv_b = (const float*)d_in[2];
    const float* prelu_a= (const float*)d_in[3];
    const float* ln1_g  = (const float*)d_in[4];
    const float* ln1_b  = (const float*)d_in[5];
    const float* w_qkv  = (const float*)d_in[6];
    const float* E_mat  = (const float*)d_in[7];
    const float* F_mat  = (const float*)d_in[8];
    const float* w_e    = (const float*)d_in[9];
    const float* b_e    = (const float*)d_in[10];
    const float* w_f    = (const float*)d_in[11];
    const float* b_f    = (const float*)d_in[12];
    const float* w_out  = (const float*)d_in[13];
    const float* b_out  = (const float*)d_in[14];
    const float* ln2_g  = (const float*)d_in[15];
    const float* ln2_b  = (const float*)d_in[16];
    const float* ff_w1  = (const float*)d_in[17];
    const float* ff_b1  = (const float*)d_in[18];
    const float* ff_w2  = (const float*)d_in[19];
    const float* ff_b2  = (const float*)d_in[20];
    const float* w_fin  = (const float*)d_in[21];
    const float* b_fin  = (const float*)d_in[22];

    float* ws = (float*)d_ws;
    float*  seqT = ws;                                   // 2,457,600 f32
    float*  diag = seqT + (size_t)B_*N_*D_;              // 144 f32
    __bf16* Qbf  = (__bf16*)(diag + 144);                // 192*800*32 bf16
    __bf16* Kbf  = Qbf + (size_t)NWH_*WS_*32;            // 192*800*32 bf16 (row-permuted)
    __bf16* Vt   = Kbf + (size_t)NWH_*WS_*32;            // 192*32*800 bf16
    __bf16* OW   = Vt + (size_t)NWH_*32*WS_;             // 51200*96 bf16
    __bf16* wqB  = OW + (size_t)B_*N_*96;                // 224*64
    __bf16* woB  = wqB + 224*64;                         // 48*96
    __bf16* f1B  = woB + 48*96;                          // 48*64
    __bf16* f2B  = f1B + 48*64;                          // 48*64
    __bf16* wfB  = f2B + 48*64;                          // 96*64
    float*  att1 = (float*)(wfB + 96*64 + 64);           // 2,457,600 f32

    float* out1 = (float*)d_out;               // [B,D,H,W]
    float* out2 = out1 + (size_t)B_*D_*N_;     // [B,N,96]

    k_diag<<<1, 128, 0, stream>>>(E_mat, F_mat, w_e, b_e, w_f, b_f, diag);
    k_wprep<<<32, 256, 0, stream>>>(w_qkv, w_out, ff_w1, ff_w2, w_fin,
                                    wqB, woB, f1B, f2B, wfB);
    k_conv<<<800, 256, 0, stream>>>(x, conv_w, conv_b, prelu_a, seqT);
    k_qkv<<<400, 256, 0, stream>>>(seqT, wqB, ln1_g, ln1_b, diag, Qbf, Kbf, Vt);
    k_attn<<<480, 256, 0, stream>>>(Qbf, Kbf, Vt, OW);
    k_tail<<<400, 256, 0, stream>>>(seqT, OW, woB, b_out, ln2_g, ln2_b,
                                    f1B, ff_b1, f2B, ff_b2, wfB, b_fin,
                                    att1, out2);
    k_highpass<<<800, 256, 0, stream>>>(seqT, att1, out1);
}

// Round 7
// 100.375 us; speedup vs baseline: 10.6116x; 1.0821x over previous
//
#include <hip/hip_runtime.h>
#include <hip/hip_bf16.h>

#define B_    2
#define CIN_  5
#define H_    160
#define W_    160
#define N_    25600        // H*W
#define D_    48
#define NW_   32
#define WS_   800
#define HEADS_ 3
#define DH_   24
#define INNER_ 72
#define NWH_  192          // B*NW*HEADS

typedef __bf16 bf16x8 __attribute__((ext_vector_type(8)));
typedef float  f32x4  __attribute__((ext_vector_type(4)));

#define MFMA(a,b,c) __builtin_amdgcn_mfma_f32_16x16x32_bf16((a),(b),(c),0,0,0)

__device__ __forceinline__ float fast_exp2(float x) {
#if __has_builtin(__builtin_amdgcn_exp2f)
    return __builtin_amdgcn_exp2f(x);
#else
    return exp2f(x);
#endif
}

// ---------------- K0: weight prep -> zero-padded bf16 (+ e/f diag) ----------------
__global__ __launch_bounds__(256) void k_wprep(const float* __restrict__ wqkv,
                                               const float* __restrict__ w_out,
                                               const float* __restrict__ fw1,
                                               const float* __restrict__ fw2,
                                               const float* __restrict__ wfin,
                                               const float* __restrict__ Em,
                                               const float* __restrict__ Fm,
                                               const float* __restrict__ we,
                                               const float* __restrict__ be,
                                               const float* __restrict__ wf,
                                               const float* __restrict__ bf,
                                               float* __restrict__ diag,
                                               __bf16* __restrict__ wqB,   // [224][64]
                                               __bf16* __restrict__ woB,   // [48][96]
                                               __bf16* __restrict__ f1B,   // [48][64]
                                               __bf16* __restrict__ f2B,   // [48][64]
                                               __bf16* __restrict__ wfB) { // [96][64]
    if (blockIdx.x == 0 && threadIdx.x < 72) {
        int tt = threadIdx.x;
        int h = tt / 24, d = tt % 24;
        float se = be[d], sf = bf[d];
        for (int w = 0; w < 30; ++w) {
            se += Em[(h*24+d)*30 + w] * we[d*30 + w];
            sf += Fm[(h*24+d)*30 + w] * wf[d*30 + w];
        }
        diag[tt]      = se;
        diag[72 + tt] = sf;
    }
    int t = blockIdx.x*256 + threadIdx.x, stride = gridDim.x*256;
    for (int i = t; i < 224*64; i += stride) { int o=i>>6, c=i&63; wqB[i] = (o<216 && c<48)? (__bf16)wqkv[o*48+c] : (__bf16)0.f; }
    for (int i = t; i < 48*96;  i += stride) { int o=i/96, c=i%96; woB[i] = (c<72)? (__bf16)w_out[o*72+c] : (__bf16)0.f; }
    for (int i = t; i < 48*64;  i += stride) { int o=i>>6, c=i&63; f1B[i] = (c<48)? (__bf16)fw1[o*48+c] : (__bf16)0.f; }
    for (int i = t; i < 48*64;  i += stride) { int o=i>>6, c=i&63; f2B[i] = (c<48)? (__bf16)fw2[o*48+c] : (__bf16)0.f; }
    for (int i = t; i < 96*64;  i += stride) { int o=i>>6, c=i&63; wfB[i] = (c<48)? (__bf16)wfin[o*48+c] : (__bf16)0.f; }
}

// ---------------- K1: conv3x3 + PReLU -> seqT [B,N,D] ----------------
__global__ __launch_bounds__(256) void k_conv(const float* __restrict__ x,
                                              const float* __restrict__ cw,
                                              const float* __restrict__ cb,
                                              const float* __restrict__ pa,
                                              float* __restrict__ seqT) {
    __shared__ float T[64][49];
    __shared__ float cwL[48*45];
    __shared__ float cbL[48];
    int t  = threadIdx.x;
    int blk = blockIdx.x;              // 0..799
    int b  = blk / 400;
    int n0 = (blk % 400) * 64;
    for (int f = t; f < 48*45; f += 256) cwL[f] = cw[f];
    if (t < 48) cbL[t] = cb[t];
    __syncthreads();

    int px = t & 63;
    int wv = t >> 6;                   // 0..3, handles oc [wv*12, wv*12+12)
    int n  = n0 + px;
    int y  = n / W_, xx = n % W_;
    float a = pa[0];

    float patch[45];
    #pragma unroll
    for (int ic = 0; ic < 5; ++ic)
      #pragma unroll
      for (int ky = 0; ky < 3; ++ky)
        #pragma unroll
        for (int kx = 0; kx < 3; ++kx) {
            int yy = y + ky - 1, xc = xx + kx - 1;
            float v = 0.f;
            if (yy >= 0 && yy < H_ && xc >= 0 && xc < W_)
                v = x[((size_t)(b*CIN_ + ic)*H_ + yy)*W_ + xc];
            patch[(ic*3+ky)*3+kx] = v;
        }
    for (int oi = 0; oi < 12; ++oi) {
        int oc = wv*12 + oi;
        float acc = cbL[oc];
        #pragma unroll
        for (int k = 0; k < 45; ++k) acc += patch[k] * cwL[oc*45 + k];
        acc = acc >= 0.f ? acc : a * acc;
        T[px][oc] = acc;
    }
    __syncthreads();
    for (int i = 0; i < 12; ++i) {
        int f = t + i*256;             // < 3072
        int p = f / 48, c = f % 48;
        seqT[(size_t)(b*N_ + n0 + p)*D_ + c] = T[p][c];
    }
}

// ---------------- K2: MFMA LN1 + QKV (wave = 32 rows) ----------------
// K rows permuted within each 32-key chunk: key j -> pos 16*((j>>2)&1) + 4*(j>>3) + (j&3)
// so that swapped-QKT MFMA output registers ARE the PV A-fragment (see k_attn).
// V written directly transposed (bf16 Vt[wh][32][800], row 24 = ones, 25..31 = 0).
__global__ __launch_bounds__(256) void k_qkv(const float* __restrict__ seqT,
                                             const __bf16* __restrict__ wqB,
                                             const float* __restrict__ g1,
                                             const float* __restrict__ b1,
                                             const float* __restrict__ diag,
                                             __bf16* __restrict__ Qbf,
                                             __bf16* __restrict__ Kbf,
                                             __bf16* __restrict__ Vt) {
    __shared__ __bf16 xfer[4][2048];           // per-wave 32x64 bf16, swizzled
    int t = threadIdx.x, wv = t>>6, lane = t&63, g = lane>>4, s = lane&15;
    int row0 = (blockIdx.x*4 + wv) * 32;
    char* xb = (char*)&xfer[wv][0];

    int b = row0 / N_, nrem = row0 % N_;
    int w = nrem / WS_, i0 = nrem % WS_;       // 32 | 800: all rows same window
    size_t headbase = (size_t)((b*NW_ + w)*HEADS_);

    // load x tile in C-layout + LN1
    float xr[2][3][4];
    #pragma unroll
    for (int m = 0; m < 2; ++m)
      #pragma unroll
      for (int n = 0; n < 3; ++n)
        #pragma unroll
        for (int r = 0; r < 4; ++r)
          xr[m][n][r] = seqT[(size_t)(row0 + m*16 + g*4 + r)*48 + n*16 + s];

    float g1v[3], b1v[3];
    #pragma unroll
    for (int n = 0; n < 3; ++n) { g1v[n] = g1[n*16+s]; b1v[n] = b1[n*16+s]; }

    #pragma unroll
    for (int m = 0; m < 2; ++m)
      #pragma unroll
      for (int r = 0; r < 4; ++r) {
        float sm = xr[m][0][r] + xr[m][1][r] + xr[m][2][r];
        float sq = xr[m][0][r]*xr[m][0][r] + xr[m][1][r]*xr[m][1][r] + xr[m][2][r]*xr[m][2][r];
        #pragma unroll
        for (int msk = 1; msk < 16; msk <<= 1) { sm += __shfl_xor(sm, msk); sq += __shfl_xor(sq, msk); }
        float mean = sm * (1.f/48.f);
        float var  = sq * (1.f/48.f) - mean*mean;
        float rs   = rsqrtf(var + 1e-5f);
        int row = m*16 + g*4 + r;
        int sw  = ((g*4+r)&7) << 4;
        #pragma unroll
        for (int n = 0; n < 3; ++n) {
            float yn = (xr[m][n][r] - mean) * rs * g1v[n] + b1v[n];
            *(__bf16*)(xb + ((row*128 + (n*16+s)*2) ^ sw)) = (__bf16)yn;
        }
        *(__bf16*)(xb + ((row*128 + (48+s)*2) ^ sw)) = (__bf16)0.f;  // K-pad
      }

    // A-frags from LDS
    bf16x8 af[2][2];
    #pragma unroll
    for (int m = 0; m < 2; ++m)
      #pragma unroll
      for (int kc = 0; kc < 2; ++kc)
        af[m][kc] = *(const bf16x8*)(xb + (((m*16+s)*128 + kc*64 + g*16) ^ ((s&7)<<4)));

    const bf16x8* WQ4 = (const bf16x8*)wqB;
    // 24^-0.5 * log2(e): fold attention scale AND exp2 conversion into Q
    const float SCALE = 0.2944889919f;

    #pragma unroll 2
    for (int n = 0; n < 14; ++n) {
        bf16x8 wb0 = WQ4[(n*16+s)*8 + g];
        bf16x8 wb1 = WQ4[(n*16+s)*8 + 4 + g];
        f32x4 c0 = {0.f,0.f,0.f,0.f}, c1 = {0.f,0.f,0.f,0.f};
        c0 = MFMA(af[0][0], wb0, c0); c0 = MFMA(af[0][1], wb1, c0);
        c1 = MFMA(af[1][0], wb0, c1); c1 = MFMA(af[1][1], wb1, c1);
        int o = n*16 + s;
        if (o < 216) {
            int h = o/72, j = o%72, part = j/24, d = j%24;
            size_t rbase = (headbase + h)*WS_ + i0;
            float mul = (part==0) ? SCALE : ((part==1) ? diag[h*24+d] : diag[72+h*24+d]);
            #pragma unroll
            for (int m = 0; m < 2; ++m) {
                f32x4 c = m ? c1 : c0;
                #pragma unroll
                for (int r = 0; r < 4; ++r) {
                    float val = c[r] * mul;
                    if (part == 0) {
                        size_t rq = rbase + m*16 + g*4 + r;
                        Qbf[rq*32 + d] = (__bf16)val;
                    } else if (part == 1) {
                        // permuted key position within the 32-row chunk
                        int p5 = 16*(g&1) + 8*m + 4*(g>>1) + r;
                        size_t rq = rbase + p5;
                        Kbf[rq*32 + d] = (__bf16)val;
                    } else {
                        // direct transposed V write: Vt[wh][d][i0+rowlocal]
                        Vt[(headbase + h)*((size_t)32*WS_) + (size_t)d*WS_
                           + i0 + m*16 + g*4 + r] = (__bf16)val;
                    }
                }
            }
        }
    }
    // Q/K zero-pad cols 24..31, Vt pad rows 24..31 (row 24 = ones)
    #pragma unroll
    for (int it = 0; it < 12; ++it) {
        int idx = lane + it*64;
        int rl = idx/24, cc = idx%24;
        int hh = cc>>3, dd = 24 + (cc&7);
        size_t rq = (headbase + hh)*WS_ + i0 + rl;
        Qbf[rq*32 + dd] = (__bf16)0.f;
        Kbf[rq*32 + dd] = (__bf16)0.f;
        Vt[(headbase + hh)*((size_t)32*WS_) + (size_t)dd*WS_ + i0 + rl] =
            (dd == 24) ? (__bf16)1.0f : (__bf16)0.f;
    }
}

// ---------------- K3: MFMA attention, register-resident P, split-K wave pairs ----------------
// Task (wh, 80 queries) handled by 2 waves: wave half 0 -> chunks 0..12,
// half 1 -> chunks 13..24. Unnormalized O partials (incl. ones-column denom)
// combined through LDS, then normalized and written by half 0.
__global__ __launch_bounds__(256, 4) void k_attn(const __bf16* __restrict__ Qbf,
                                                 const __bf16* __restrict__ Kbf,
                                                 const __bf16* __restrict__ Vt,
                                                 __bf16* __restrict__ OW) {
    __shared__ float red[2][5][2][4][64];      // 20 KB: [task-in-block][i][j][r][lane]
    int t = threadIdx.x;
    int wv = t >> 6, lane = t & 63;
    int g = lane >> 4, s = lane & 15;
    int half = wv & 1, tsk = wv >> 1;
    int task = blockIdx.x * 2 + tsk;           // 0..1919 exactly
    int wh = task / 10, qt = task % 10;
    int q0 = qt * 80;

    const bf16x8* Qp = (const bf16x8*)(Qbf + ((size_t)wh*WS_ + q0)*32);
    const bf16x8* Kp = (const bf16x8*)(Kbf + (size_t)wh*WS_*32);
    const bf16x8* Vp = (const bf16x8*)(Vt  + (size_t)wh*32*WS_);

    // Q as B-operand: col = query = lane&15
    bf16x8 qb[5];
    #pragma unroll
    for (int i = 0; i < 5; ++i) qb[i] = Qp[(i*16 + s)*4 + g];

    f32x4 o[5][2];
    #pragma unroll
    for (int i = 0; i < 5; ++i) {
        o[i][0] = (f32x4){0.f,0.f,0.f,0.f};
        o[i][1] = (f32x4){0.f,0.f,0.f,0.f};
    }

    int c0 = half ? 13 : 0;
    int c1 = half ? 25 : 13;

    // prefetch first chunk
    bf16x8 ka0 = Kp[(c0*32 + s)*4 + g];
    bf16x8 ka1 = Kp[(c0*32 + 16 + s)*4 + g];
    bf16x8 vb0 = Vp[s*100 + c0*4 + g];
    bf16x8 vb1 = Vp[(16+s)*100 + c0*4 + g];

    for (int c = c0; c < c1; ++c) {
        int cn = (c + 1 < c1) ? c + 1 : c0;    // last-iter reload is harmless
        bf16x8 nk0 = Kp[(cn*32 + s)*4 + g];
        bf16x8 nk1 = Kp[(cn*32 + 16 + s)*4 + g];
        bf16x8 nv0 = Vp[s*100 + cn*4 + g];
        bf16x8 nv1 = Vp[(16+s)*100 + cn*4 + g];

        #pragma unroll
        for (int i = 0; i < 5; ++i) {
            f32x4 s0 = {0.f,0.f,0.f,0.f}, s1 = {0.f,0.f,0.f,0.f};
            s0 = MFMA(ka0, qb[i], s0);         // C[m=T0 row 4g+r][n=query s]
            s1 = MFMA(ka1, qb[i], s1);         // C[m=T1 row 4g+r][n=query s]
            // K permutation => s0[r] ~ key 8g+r, s1[r] ~ key 8g+4+r:
            // exactly A-frag slots (row=s=query, k=8g+idx)
            bf16x8 pa;
            #pragma unroll
            for (int r = 0; r < 4; ++r) {
                pa[r]     = (__bf16)fast_exp2(s0[r]);
                pa[r + 4] = (__bf16)fast_exp2(s1[r]);
            }
            o[i][0] = MFMA(pa, vb0, o[i][0]);  // O[q=4g+r][d=s]
            o[i][1] = MFMA(pa, vb1, o[i][1]);  // d=16+s (row 24 ones -> denom at s=8)
        }
        ka0 = nk0; ka1 = nk1; vb0 = nv0; vb1 = nv1;
    }

    // combine halves through LDS
    if (half) {
        #pragma unroll
        for (int i = 0; i < 5; ++i)
          #pragma unroll
          for (int j = 0; j < 2; ++j)
            #pragma unroll
            for (int r = 0; r < 4; ++r)
              red[tsk][i][j][r][lane] = o[i][j][r];
    }
    __syncthreads();
    if (!half) {
        #pragma unroll
        for (int i = 0; i < 5; ++i)
          #pragma unroll
          for (int j = 0; j < 2; ++j)
            #pragma unroll
            for (int r = 0; r < 4; ++r)
              o[i][j][r] += red[tsk][i][j][r][lane];

        int bw = wh / 3, h = wh % 3;
        int b = bw >> 5, w = bw & 31;
        #pragma unroll
        for (int i = 0; i < 5; ++i) {
            #pragma unroll
            for (int r = 0; r < 4; ++r) {
                float den = __shfl(o[i][1][r], (lane & 48) + 8);   // d=24 ones-column
                float inv = 1.f / den;
                int n = w*WS_ + q0 + i*16 + g*4 + r;
                size_t addr = (size_t)(b*N_ + n)*96 + h*24;
                OW[addr + s] = (__bf16)(o[i][0][r] * inv);
                if (s < 8) OW[addr + 16 + s] = (__bf16)(o[i][1][r] * inv);
                if (h == 0) {                  // write K-pad cols 72..95
                    size_t pbase = (size_t)(b*N_ + n)*96;
                    OW[pbase + 72 + s] = (__bf16)0.f;
                    if (s < 8) OW[pbase + 88 + s] = (__bf16)0.f;
                }
            }
        }
    }
}

// ---------------- K4: MFMA tail + fused Highpass (wave = 32 rows) ----------------
__global__ __launch_bounds__(256) void k_tail(const float* __restrict__ seqT,
                                              const __bf16* __restrict__ OW,
                                              const __bf16* __restrict__ woB,
                                              const float* __restrict__ b_out,
                                              const float* __restrict__ g2,
                                              const float* __restrict__ b2,
                                              const __bf16* __restrict__ f1B,
                                              const float* __restrict__ fb1,
                                              const __bf16* __restrict__ f2B,
                                              const float* __restrict__ fb2,
                                              const __bf16* __restrict__ wfB,
                                              const float* __restrict__ bfin,
                                              float* __restrict__ out1,
                                              float* __restrict__ out2) {
    __shared__ __bf16 xfer[4][2048];
    int t = threadIdx.x, wv = t>>6, lane = t&63, g = lane>>4, s = lane&15;
    int row0 = (blockIdx.x*4 + wv) * 32;
    char* xb = (char*)&xfer[wv][0];

    int b = row0 / N_;
    int nbase = row0 % N_;

    const bf16x8* OW4 = (const bf16x8*)OW;
    const bf16x8* WO4 = (const bf16x8*)woB;
    const bf16x8* F14 = (const bf16x8*)f1B;
    const bf16x8* F24 = (const bf16x8*)f2B;
    const bf16x8* WF4 = (const bf16x8*)wfB;

    // ---- S1: att = ow · w_out^T ----
    bf16x8 aow[2][3];
    #pragma unroll
    for (int m = 0; m < 2; ++m)
      #pragma unroll
      for (int kc = 0; kc < 3; ++kc)
        aow[m][kc] = OW4[(size_t)(row0 + m*16 + s)*12 + kc*4 + g];

    f32x4 s2[2][3];
    #pragma unroll
    for (int n = 0; n < 3; ++n) {
        bf16x8 wb0 = WO4[(n*16+s)*12 + g];
        bf16x8 wb1 = WO4[(n*16+s)*12 + 4 + g];
        bf16x8 wb2 = WO4[(n*16+s)*12 + 8 + g];
        #pragma unroll
        for (int m = 0; m < 2; ++m) {
            f32x4 c = {0.f,0.f,0.f,0.f};
            c = MFMA(aow[m][0], wb0, c);
            c = MFMA(aow[m][1], wb1, c);
            c = MFMA(aow[m][2], wb2, c);
            s2[m][n] = c;
        }
    }
    float bov[3], g2v[3], b2v[3], f1bv[3], f2bv[3];
    #pragma unroll
    for (int n = 0; n < 3; ++n) {
        bov[n] = b_out[n*16+s]; g2v[n] = g2[n*16+s]; b2v[n] = b2[n*16+s];
        f1bv[n] = fb1[n*16+s];  f2bv[n] = fb2[n*16+s];
    }
    // keep raw seqT values for the fused Highpass
    float sv[2][3][4];
    #pragma unroll
    for (int m = 0; m < 2; ++m)
      #pragma unroll
      for (int n = 0; n < 3; ++n)
        #pragma unroll
        for (int r = 0; r < 4; ++r) {
          sv[m][n][r] = seqT[(size_t)(row0 + m*16 + g*4 + r)*48 + n*16 + s];
          s2[m][n][r] += sv[m][n][r] + bov[n];
        }

    // ---- LN2 -> yn -> LDS ----
    #pragma unroll
    for (int m = 0; m < 2; ++m)
      #pragma unroll
      for (int r = 0; r < 4; ++r) {
        float sm = s2[m][0][r] + s2[m][1][r] + s2[m][2][r];
        float sq = s2[m][0][r]*s2[m][0][r] + s2[m][1][r]*s2[m][1][r] + s2[m][2][r]*s2[m][2][r];
        #pragma unroll
        for (int msk = 1; msk < 16; msk <<= 1) { sm += __shfl_xor(sm, msk); sq += __shfl_xor(sq, msk); }
        float mean = sm * (1.f/48.f);
        float var  = sq * (1.f/48.f) - mean*mean;
        float rs   = rsqrtf(var + 1e-5f);
        int row = m*16 + g*4 + r;
        int sw  = ((g*4+r)&7) << 4;
        #pragma unroll
        for (int n = 0; n < 3; ++n) {
            float yn = (s2[m][n][r] - mean) * rs * g2v[n] + b2v[n];
            *(__bf16*)(xb + ((row*128 + (n*16+s)*2) ^ sw)) = (__bf16)yn;
        }
        *(__bf16*)(xb + ((row*128 + (48+s)*2) ^ sw)) = (__bf16)0.f;
      }

    bf16x8 af[2][2];
    f32x4 hh[2][3];

    // ---- ff1 ----
    #pragma unroll
    for (int m = 0; m < 2; ++m)
      #pragma unroll
      for (int kc = 0; kc < 2; ++kc)
        af[m][kc] = *(const bf16x8*)(xb + (((m*16+s)*128 + kc*64 + g*16) ^ ((s&7)<<4)));
    #pragma unroll
    for (int n = 0; n < 3; ++n) {
        bf16x8 wb0 = F14[(n*16+s)*8 + g];
        bf16x8 wb1 = F14[(n*16+s)*8 + 4 + g];
        #pragma unroll
        for (int m = 0; m < 2; ++m) {
            f32x4 c = {0.f,0.f,0.f,0.f};
            c = MFMA(af[m][0], wb0, c);
            c = MFMA(af[m][1], wb1, c);
            hh[m][n] = c;
        }
    }
    #pragma unroll
    for (int m = 0; m < 2; ++m)
      #pragma unroll
      for (int r = 0; r < 4; ++r) {
        int row = m*16 + g*4 + r;
        int sw  = ((g*4+r)&7) << 4;
        #pragma unroll
        for (int n = 0; n < 3; ++n) {
            float v = hh[m][n][r] + f1bv[n];
            v = v >= 0.f ? v : 0.01f*v;
            *(__bf16*)(xb + ((row*128 + (n*16+s)*2) ^ sw)) = (__bf16)v;
        }
        *(__bf16*)(xb + ((row*128 + (48+s)*2) ^ sw)) = (__bf16)0.f;
      }

    // ---- ff2 + residual -> a1 -> LDS; fused Highpass out1 write ----
    #pragma unroll
    for (int m = 0; m < 2; ++m)
      #pragma unroll
      for (int kc = 0; kc < 2; ++kc)
        af[m][kc] = *(const bf16x8*)(xb + (((m*16+s)*128 + kc*64 + g*16) ^ ((s&7)<<4)));
    #pragma unroll
    for (int n = 0; n < 3; ++n) {
        bf16x8 wb0 = F24[(n*16+s)*8 + g];
        bf16x8 wb1 = F24[(n*16+s)*8 + 4 + g];
        #pragma unroll
        for (int m = 0; m < 2; ++m) {
            f32x4 c = {0.f,0.f,0.f,0.f};
            c = MFMA(af[m][0], wb0, c);
            c = MFMA(af[m][1], wb1, c);
            hh[m][n] = c;
        }
    }
    #pragma unroll
    for (int m = 0; m < 2; ++m)
      #pragma unroll
      for (int r = 0; r < 4; ++r) {
        int row = m*16 + g*4 + r;
        int sw  = ((g*4+r)&7) << 4;
        #pragma unroll
        for (int n = 0; n < 3; ++n) {
            float a1v = s2[m][n][r] + hh[m][n][r] + f2bv[n];
            // Highpass1 = E * (1 + a1), transposed to [B, D, H*W]
            out1[((size_t)b*D_ + (n*16+s))*N_ + nbase + row] =
                sv[m][n][r] * (1.f + a1v);
            *(__bf16*)(xb + ((row*128 + (n*16+s)*2) ^ sw)) = (__bf16)a1v;
        }
        *(__bf16*)(xb + ((row*128 + (48+s)*2) ^ sw)) = (__bf16)0.f;
      }

    // ---- final linear 48 -> 96 ----
    #pragma unroll
    for (int m = 0; m < 2; ++m)
      #pragma unroll
      for (int kc = 0; kc < 2; ++kc)
        af[m][kc] = *(const bf16x8*)(xb + (((m*16+s)*128 + kc*64 + g*16) ^ ((s&7)<<4)));
    #pragma unroll
    for (int n = 0; n < 6; ++n) {
        bf16x8 wb0 = WF4[(n*16+s)*8 + g];
        bf16x8 wb1 = WF4[(n*16+s)*8 + 4 + g];
        float bfv = bfin[n*16+s];
        #pragma unroll
        for (int m = 0; m < 2; ++m) {
            f32x4 c = {0.f,0.f,0.f,0.f};
            c = MFMA(af[m][0], wb0, c);
            c = MFMA(af[m][1], wb1, c);
            #pragma unroll
            for (int r = 0; r < 4; ++r)
                out2[(size_t)(row0 + m*16 + g*4 + r)*96 + n*16 + s] = c[r] + bfv;
        }
    }
}

extern "C" void kernel_launch(void* const* d_in, const int* in_sizes, int n_in,
                              void* d_out, int out_size, void* d_ws, size_t ws_size,
                              hipStream_t stream) {
    const float* x      = (const float*)d_in[0];
    const float* conv_w = (const float*)d_in[1];
    const float* conv_b = (const float*)d_in[2];
    const float* prelu_a= (const float*)d_in[3];
    const float* ln1_g  = (const float*)d_in[4];
    const float* ln1_b  = (const float*)d_in[5];
    const float* w_qkv  = (const float*)d_in[6];
    const float* E_mat  = (const float*)d_in[7];
    const float* F_mat  = (const float*)d_in[8];
    const float* w_e    = (const float*)d_in[9];
    const float* b_e    = (const float*)d_in[10];
    const float* w_f    = (const float*)d_in[11];
    const float* b_f    = (const float*)d_in[12];
    const float* w_out  = (const float*)d_in[13];
    const float* b_out  = (const float*)d_in[14];
    const float* ln2_g  = (const float*)d_in[15];
    const float* ln2_b  = (const float*)d_in[16];
    const float* ff_w1  = (const float*)d_in[17];
    const float* ff_b1  = (const float*)d_in[18];
    const float* ff_w2  = (const float*)d_in[19];
    const float* ff_b2  = (const float*)d_in[20];
    const float* w_fin  = (const float*)d_in[21];
    const float* b_fin  = (const float*)d_in[22];

    float* ws = (float*)d_ws;
    float*  seqT = ws;                                   // 2,457,600 f32
    float*  diag = seqT + (size_t)B_*N_*D_;              // 144 f32
    __bf16* Qbf  = (__bf16*)(diag + 144);                // 192*800*32 bf16
    __bf16* Kbf  = Qbf + (size_t)NWH_*WS_*32;            // 192*800*32 bf16 (row-permuted)
    __bf16* Vt   = Kbf + (size_t)NWH_*WS_*32;            // 192*32*800 bf16
    __bf16* OW   = Vt + (size_t)NWH_*32*WS_;             // 51200*96 bf16
    __bf16* wqB  = OW + (size_t)B_*N_*96;                // 224*64
    __bf16* woB  = wqB + 224*64;                         // 48*96
    __bf16* f1B  = woB + 48*96;                          // 48*64
    __bf16* f2B  = f1B + 48*64;                          // 48*64
    __bf16* wfB  = f2B + 48*64;                          // 96*64

    float* out1 = (float*)d_out;               // [B,D,H,W]
    float* out2 = out1 + (size_t)B_*D_*N_;     // [B,N,96]

    k_wprep<<<32, 256, 0, stream>>>(w_qkv, w_out, ff_w1, ff_w2, w_fin,
                                    E_mat, F_mat, w_e, b_e, w_f, b_f, diag,
                                    wqB, woB, f1B, f2B, wfB);
    k_conv<<<800, 256, 0, stream>>>(x, conv_w, conv_b, prelu_a, seqT);
    k_qkv<<<400, 256, 0, stream>>>(seqT, wqB, ln1_g, ln1_b, diag, Qbf, Kbf, Vt);
    k_attn<<<960, 256, 0, stream>>>(Qbf, Kbf, Vt, OW);
    k_tail<<<400, 256, 0, stream>>>(seqT, OW, woB, b_out, ln2_g, ln2_b,
                                    f1B, ff_b1, f2B, ff_b2, wfB, b_fin,
                                    out1, out2);
}

// Round 8
// 89.958 us; speedup vs baseline: 11.8404x; 1.1158x over previous
//
#include <hip/hip_runtime.h>
#include <hip/hip_bf16.h>

#define B_    2
#define CIN_  5
#define H_    160
#define W_    160
#define N_    25600        // H*W
#define D_    48
#define NW_   32
#define WS_   800
#define HEADS_ 3
#define DH_   24
#define INNER_ 72
#define NWH_  192          // B*NW*HEADS

typedef __bf16 bf16x8 __attribute__((ext_vector_type(8)));
typedef float  f32x4  __attribute__((ext_vector_type(4)));

#define MFMA(a,b,c) __builtin_amdgcn_mfma_f32_16x16x32_bf16((a),(b),(c),0,0,0)

__device__ __forceinline__ float fast_exp2(float x) {
#if __has_builtin(__builtin_amdgcn_exp2f)
    return __builtin_amdgcn_exp2f(x);
#else
    return exp2f(x);
#endif
}

__device__ __forceinline__ unsigned pack_bf16(float lo, float hi) {
    __bf16 l = (__bf16)lo, h = (__bf16)hi;
    unsigned short ul = __builtin_bit_cast(unsigned short, l);
    unsigned short uh = __builtin_bit_cast(unsigned short, h);
    return ((unsigned)uh << 16) | (unsigned)ul;
}

// ---------------- K0: weight prep -> padded/reordered bf16 (+ e/f diag) ----------------
// wqB: [9 groups (part,head)][32 rows: d = t*16+s, d>=24 zero][64 cols]
// woB: [48][96] with k-dim in OW phys order: p = h*32 + 2*s' + j <-> logical h*24 + j*16 + s'
__global__ __launch_bounds__(256) void k_wprep(const float* __restrict__ wqkv,
                                               const float* __restrict__ w_out,
                                               const float* __restrict__ fw1,
                                               const float* __restrict__ fw2,
                                               const float* __restrict__ wfin,
                                               const float* __restrict__ Em,
                                               const float* __restrict__ Fm,
                                               const float* __restrict__ we,
                                               const float* __restrict__ be,
                                               const float* __restrict__ wf,
                                               const float* __restrict__ bf,
                                               float* __restrict__ diag,
                                               __bf16* __restrict__ wqB,   // [288][64]
                                               __bf16* __restrict__ woB,   // [48][96]
                                               __bf16* __restrict__ f1B,   // [48][64]
                                               __bf16* __restrict__ f2B,   // [48][64]
                                               __bf16* __restrict__ wfB) { // [96][64]
    if (blockIdx.x == 0 && threadIdx.x < 72) {
        int tt = threadIdx.x;
        int h = tt / 24, d = tt % 24;
        float se = be[d], sf = bf[d];
        for (int w = 0; w < 30; ++w) {
            se += Em[(h*24+d)*30 + w] * we[d*30 + w];
            sf += Fm[(h*24+d)*30 + w] * wf[d*30 + w];
        }
        diag[tt]      = se;
        diag[72 + tt] = sf;
    }
    int t = blockIdx.x*256 + threadIdx.x, stride = gridDim.x*256;
    for (int i = t; i < 288*64; i += stride) {
        int grow = i>>6, c = i&63;
        int gg = grow>>5, q = grow&31, tt = q>>4, sp = q&15, d = tt*16+sp;
        int part = gg/3, head = gg%3;
        wqB[i] = (d<24 && c<48) ? (__bf16)wqkv[(head*72 + part*24 + d)*48 + c] : (__bf16)0.f;
    }
    for (int i = t; i < 48*96;  i += stride) {
        int o = i/96, p = i%96;
        int h = p>>5, q = p&31, j = q&1, sp = q>>1, d = j*16+sp;
        woB[i] = (d<24) ? (__bf16)w_out[o*72 + h*24 + d] : (__bf16)0.f;
    }
    for (int i = t; i < 48*64;  i += stride) { int o=i>>6, c=i&63; f1B[i] = (c<48)? (__bf16)fw1[o*48+c] : (__bf16)0.f; }
    for (int i = t; i < 48*64;  i += stride) { int o=i>>6, c=i&63; f2B[i] = (c<48)? (__bf16)fw2[o*48+c] : (__bf16)0.f; }
    for (int i = t; i < 96*64;  i += stride) { int o=i>>6, c=i&63; wfB[i] = (c<48)? (__bf16)wfin[o*48+c] : (__bf16)0.f; }
}

// ---------------- K1: conv3x3 + PReLU -> seqT [B,N,D] ----------------
__global__ __launch_bounds__(256) void k_conv(const float* __restrict__ x,
                                              const float* __restrict__ cw,
                                              const float* __restrict__ cb,
                                              const float* __restrict__ pa,
                                              float* __restrict__ seqT) {
    __shared__ float T[64][49];
    __shared__ float cwL[48*45];
    __shared__ float cbL[48];
    int t  = threadIdx.x;
    int blk = blockIdx.x;              // 0..799
    int b  = blk / 400;
    int n0 = (blk % 400) * 64;
    for (int f = t; f < 48*45; f += 256) cwL[f] = cw[f];
    if (t < 48) cbL[t] = cb[t];
    __syncthreads();

    int px = t & 63;
    int wv = t >> 6;                   // 0..3, handles oc [wv*12, wv*12+12)
    int n  = n0 + px;
    int y  = n / W_, xx = n % W_;
    float a = pa[0];

    float patch[45];
    #pragma unroll
    for (int ic = 0; ic < 5; ++ic)
      #pragma unroll
      for (int ky = 0; ky < 3; ++ky)
        #pragma unroll
        for (int kx = 0; kx < 3; ++kx) {
            int yy = y + ky - 1, xc = xx + kx - 1;
            float v = 0.f;
            if (yy >= 0 && yy < H_ && xc >= 0 && xc < W_)
                v = x[((size_t)(b*CIN_ + ic)*H_ + yy)*W_ + xc];
            patch[(ic*3+ky)*3+kx] = v;
        }
    for (int oi = 0; oi < 12; ++oi) {
        int oc = wv*12 + oi;
        float acc = cbL[oc];
        #pragma unroll
        for (int k = 0; k < 45; ++k) acc += patch[k] * cwL[oc*45 + k];
        acc = acc >= 0.f ? acc : a * acc;
        T[px][oc] = acc;
    }
    __syncthreads();
    for (int i = 0; i < 12; ++i) {
        int f = t + i*256;             // < 3072
        int p = f / 48, c = f % 48;
        seqT[(size_t)(b*N_ + n0 + p)*D_ + c] = T[p][c];
    }
}

// ---------------- K2: MFMA LN1 + QKV (wave = 32 rows), packed dword stores ----------------
// Q/K cols d-interleaved: phys p = 2s+parity <-> logical d = parity*16+s (Q,K share map).
// K rows permuted within chunk: (m,g,r) -> 16*(g&1)+8m+4*(g>>1)+r (attn PV A-frag layout).
// V written transposed (Vt[wh][32][800], logical d rows; row 24 = ones, 25..31 = 0).
__global__ __launch_bounds__(256) void k_qkv(const float* __restrict__ seqT,
                                             const __bf16* __restrict__ wqB,
                                             const float* __restrict__ g1,
                                             const float* __restrict__ b1,
                                             const float* __restrict__ diag,
                                             __bf16* __restrict__ Qbf,
                                             __bf16* __restrict__ Kbf,
                                             __bf16* __restrict__ Vt) {
    __shared__ __bf16 xfer[4][2048];           // per-wave 32x64 bf16, swizzled
    int t = threadIdx.x, wv = t>>6, lane = t&63, g = lane>>4, s = lane&15;
    int row0 = (blockIdx.x*4 + wv) * 32;
    char* xb = (char*)&xfer[wv][0];

    int b = row0 / N_, nrem = row0 % N_;
    int w = nrem / WS_, i0 = nrem % WS_;       // 32 | 800: all rows same window
    size_t headbase = (size_t)((b*NW_ + w)*HEADS_);

    // load x tile in C-layout + LN1
    float xr[2][3][4];
    #pragma unroll
    for (int m = 0; m < 2; ++m)
      #pragma unroll
      for (int n = 0; n < 3; ++n)
        #pragma unroll
        for (int r = 0; r < 4; ++r)
          xr[m][n][r] = seqT[(size_t)(row0 + m*16 + g*4 + r)*48 + n*16 + s];

    float g1v[3], b1v[3];
    #pragma unroll
    for (int n = 0; n < 3; ++n) { g1v[n] = g1[n*16+s]; b1v[n] = b1[n*16+s]; }

    #pragma unroll
    for (int m = 0; m < 2; ++m)
      #pragma unroll
      for (int r = 0; r < 4; ++r) {
        float sm = xr[m][0][r] + xr[m][1][r] + xr[m][2][r];
        float sq = xr[m][0][r]*xr[m][0][r] + xr[m][1][r]*xr[m][1][r] + xr[m][2][r]*xr[m][2][r];
        #pragma unroll
        for (int msk = 1; msk < 16; msk <<= 1) { sm += __shfl_xor(sm, msk); sq += __shfl_xor(sq, msk); }
        float mean = sm * (1.f/48.f);
        float var  = sq * (1.f/48.f) - mean*mean;
        float rs   = rsqrtf(var + 1e-5f);
        int row = m*16 + g*4 + r;
        int sw  = ((g*4+r)&7) << 4;
        #pragma unroll
        for (int n = 0; n < 3; ++n) {
            float yn = (xr[m][n][r] - mean) * rs * g1v[n] + b1v[n];
            *(__bf16*)(xb + ((row*128 + (n*16+s)*2) ^ sw)) = (__bf16)yn;
        }
        *(__bf16*)(xb + ((row*128 + (48+s)*2) ^ sw)) = (__bf16)0.f;  // K-pad
      }

    // A-frags from LDS
    bf16x8 af[2][2];
    #pragma unroll
    for (int m = 0; m < 2; ++m)
      #pragma unroll
      for (int kc = 0; kc < 2; ++kc)
        af[m][kc] = *(const bf16x8*)(xb + (((m*16+s)*128 + kc*64 + g*16) ^ ((s&7)<<4)));

    const bf16x8* WQ4 = (const bf16x8*)wqB;
    // 24^-0.5 * log2(e): fold attention scale AND exp2 conversion into Q
    const float SCALE = 0.2944889919f;

    // per-lane diag values (even col = d s, odd col = d 16+s)
    float dke[3], dko[3], dve[3], dvo[3];
    #pragma unroll
    for (int h = 0; h < 3; ++h) {
        dke[h] = diag[h*24 + s];
        dko[h] = (s < 8) ? diag[h*24 + 16 + s] : 0.f;
        dve[h] = diag[72 + h*24 + s];
        dvo[h] = (s < 8) ? diag[72 + h*24 + 16 + s] : 0.f;
    }

    unsigned* Qd = (unsigned*)Qbf;
    unsigned* Kd = (unsigned*)Kbf;

    #pragma unroll
    for (int gg = 0; gg < 9; ++gg) {
        int part = gg / 3, head = gg % 3;
        bf16x8 we0 = WQ4[(gg*32 +      s)*8 +     g];
        bf16x8 we1 = WQ4[(gg*32 +      s)*8 + 4 + g];
        bf16x8 wo0 = WQ4[(gg*32 + 16 + s)*8 +     g];
        bf16x8 wo1 = WQ4[(gg*32 + 16 + s)*8 + 4 + g];
        f32x4 ce[2], co[2];
        #pragma unroll
        for (int m = 0; m < 2; ++m) {
            f32x4 c = {0.f,0.f,0.f,0.f};
            c = MFMA(af[m][0], we0, c); c = MFMA(af[m][1], we1, c);
            ce[m] = c;
            f32x4 d = {0.f,0.f,0.f,0.f};
            d = MFMA(af[m][0], wo0, d); d = MFMA(af[m][1], wo1, d);
            co[m] = d;
        }
        size_t rbase = (headbase + head)*WS_ + i0;
        if (part == 0) {
            #pragma unroll
            for (int m = 0; m < 2; ++m)
              #pragma unroll
              for (int r = 0; r < 4; ++r)
                Qd[(rbase + m*16 + g*4 + r)*16 + s] =
                    pack_bf16(ce[m][r]*SCALE, co[m][r]*SCALE);
        } else if (part == 1) {
            #pragma unroll
            for (int m = 0; m < 2; ++m)
              #pragma unroll
              for (int r = 0; r < 4; ++r) {
                int p5 = 16*(g&1) + 8*m + 4*(g>>1) + r;
                Kd[(rbase + p5)*16 + s] =
                    pack_bf16(ce[m][r]*dke[head], co[m][r]*dko[head]);
              }
        } else {
            size_t vbase = (headbase + head)*((size_t)32*WS_) + i0;
            #pragma unroll
            for (int m = 0; m < 2; ++m)
              #pragma unroll
              for (int r = 0; r < 4; ++r) {
                int row = m*16 + g*4 + r;
                Vt[vbase + (size_t)s*WS_ + row] = (__bf16)(ce[m][r]*dve[head]);
                if (s < 8)
                    Vt[vbase + (size_t)(16+s)*WS_ + row] = (__bf16)(co[m][r]*dvo[head]);
              }
        }
    }
    // Vt pad rows 24..31 (ones at 24), packed u32
    unsigned* Vd = (unsigned*)Vt;
    #pragma unroll
    for (int it = 0; it < 6; ++it) {
        int idx = it*64 + lane;           // 0..383 = 3 heads x 8 rows x 16 col-pairs
        int h = idx >> 7, rem = idx & 127;
        int dd = 24 + (rem >> 4), cp = rem & 15;
        size_t ubase = (((headbase + h)*((size_t)32*WS_) + (size_t)dd*WS_ + i0) >> 1);
        Vd[ubase + cp] = (dd == 24) ? 0x3F803F80u : 0u;
    }
}

// ---------------- K3: MFMA attention, register-resident P, split-K wave pairs ----------------
__global__ __launch_bounds__(256, 4) void k_attn(const __bf16* __restrict__ Qbf,
                                                 const __bf16* __restrict__ Kbf,
                                                 const __bf16* __restrict__ Vt,
                                                 __bf16* __restrict__ OW) {
    __shared__ float red[2][5][2][4][64];      // 20 KB
    int t = threadIdx.x;
    int wv = t >> 6, lane = t & 63;
    int g = lane >> 4, s = lane & 15;
    int half = wv & 1, tsk = wv >> 1;
    int task = blockIdx.x * 2 + tsk;           // 0..1919 exactly
    int wh = task / 10, qt = task % 10;
    int q0 = qt * 80;

    const bf16x8* Qp = (const bf16x8*)(Qbf + ((size_t)wh*WS_ + q0)*32);
    const bf16x8* Kp = (const bf16x8*)(Kbf + (size_t)wh*WS_*32);
    const bf16x8* Vp = (const bf16x8*)(Vt  + (size_t)wh*32*WS_);

    // Q as B-operand: col = query = lane&15
    bf16x8 qb[5];
    #pragma unroll
    for (int i = 0; i < 5; ++i) qb[i] = Qp[(i*16 + s)*4 + g];

    f32x4 o[5][2];
    #pragma unroll
    for (int i = 0; i < 5; ++i) {
        o[i][0] = (f32x4){0.f,0.f,0.f,0.f};
        o[i][1] = (f32x4){0.f,0.f,0.f,0.f};
    }

    int c0 = half ? 13 : 0;
    int c1 = half ? 25 : 13;

    // prefetch first chunk
    bf16x8 ka0 = Kp[(c0*32 + s)*4 + g];
    bf16x8 ka1 = Kp[(c0*32 + 16 + s)*4 + g];
    bf16x8 vb0 = Vp[s*100 + c0*4 + g];
    bf16x8 vb1 = Vp[(16+s)*100 + c0*4 + g];

    for (int c = c0; c < c1; ++c) {
        int cn = (c + 1 < c1) ? c + 1 : c0;    // last-iter reload is harmless
        bf16x8 nk0 = Kp[(cn*32 + s)*4 + g];
        bf16x8 nk1 = Kp[(cn*32 + 16 + s)*4 + g];
        bf16x8 nv0 = Vp[s*100 + cn*4 + g];
        bf16x8 nv1 = Vp[(16+s)*100 + cn*4 + g];

        #pragma unroll
        for (int i = 0; i < 5; ++i) {
            f32x4 s0 = {0.f,0.f,0.f,0.f}, s1 = {0.f,0.f,0.f,0.f};
            s0 = MFMA(ka0, qb[i], s0);         // C[m=T0 row 4g+r][n=query s]
            s1 = MFMA(ka1, qb[i], s1);         // C[m=T1 row 4g+r][n=query s]
            bf16x8 pa;
            #pragma unroll
            for (int r = 0; r < 4; ++r) {
                pa[r]     = (__bf16)fast_exp2(s0[r]);
                pa[r + 4] = (__bf16)fast_exp2(s1[r]);
            }
            o[i][0] = MFMA(pa, vb0, o[i][0]);  // O[q=4g+r][d=s]
            o[i][1] = MFMA(pa, vb1, o[i][1]);  // d=16+s (row 24 ones -> denom at s=8)
        }
        ka0 = nk0; ka1 = nk1; vb0 = nv0; vb1 = nv1;
    }

    // combine halves through LDS
    if (half) {
        #pragma unroll
        for (int i = 0; i < 5; ++i)
          #pragma unroll
          for (int j = 0; j < 2; ++j)
            #pragma unroll
            for (int r = 0; r < 4; ++r)
              red[tsk][i][j][r][lane] = o[i][j][r];
    }
    __syncthreads();
    if (!half) {
        #pragma unroll
        for (int i = 0; i < 5; ++i)
          #pragma unroll
          for (int j = 0; j < 2; ++j)
            #pragma unroll
            for (int r = 0; r < 4; ++r)
              o[i][j][r] += red[tsk][i][j][r][lane];

        int bw = wh / 3, h = wh % 3;
        int b = bw >> 5, w = bw & 31;
        unsigned* OWd = (unsigned*)OW;
        #pragma unroll
        for (int i = 0; i < 5; ++i) {
            #pragma unroll
            for (int r = 0; r < 4; ++r) {
                float den = __shfl(o[i][1][r], (lane & 48) + 8);   // ones-column
                float inv = 1.f / den;
                int n = w*WS_ + q0 + i*16 + g*4 + r;
                // OW phys col pair (h*32 + 2s, +1); den slot lands on zero woB row
                OWd[(size_t)(b*N_ + n)*48 + h*16 + s] =
                    pack_bf16(o[i][0][r]*inv, o[i][1][r]*inv);
            }
        }
    }
}

// ---------------- K4: MFMA tail + fused Highpass (wave = 32 rows) ----------------
__global__ __launch_bounds__(256) void k_tail(const float* __restrict__ seqT,
                                              const __bf16* __restrict__ OW,
                                              const __bf16* __restrict__ woB,
                                              const float* __restrict__ b_out,
                                              const float* __restrict__ g2,
                                              const float* __restrict__ b2,
                                              const __bf16* __restrict__ f1B,
                                              const float* __restrict__ fb1,
                                              const __bf16* __restrict__ f2B,
                                              const float* __restrict__ fb2,
                                              const __bf16* __restrict__ wfB,
                                              const float* __restrict__ bfin,
                                              float* __restrict__ out1,
                                              float* __restrict__ out2) {
    __shared__ __bf16 xfer[4][2048];
    __shared__ float hp[4][32][49];            // Highpass staging, padded stride
    int t = threadIdx.x, wv = t>>6, lane = t&63, g = lane>>4, s = lane&15;
    int row0 = (blockIdx.x*4 + wv) * 32;
    char* xb = (char*)&xfer[wv][0];

    int b = row0 / N_;
    int nbase = row0 % N_;

    const bf16x8* OW4 = (const bf16x8*)OW;
    const bf16x8* WO4 = (const bf16x8*)woB;
    const bf16x8* F14 = (const bf16x8*)f1B;
    const bf16x8* F24 = (const bf16x8*)f2B;
    const bf16x8* WF4 = (const bf16x8*)wfB;

    // ---- S1: att = ow · w_out^T (k-dim in OW phys order) ----
    bf16x8 aow[2][3];
    #pragma unroll
    for (int m = 0; m < 2; ++m)
      #pragma unroll
      for (int kc = 0; kc < 3; ++kc)
        aow[m][kc] = OW4[(size_t)(row0 + m*16 + s)*12 + kc*4 + g];

    f32x4 s2[2][3];
    #pragma unroll
    for (int n = 0; n < 3; ++n) {
        bf16x8 wb0 = WO4[(n*16+s)*12 + g];
        bf16x8 wb1 = WO4[(n*16+s)*12 + 4 + g];
        bf16x8 wb2 = WO4[(n*16+s)*12 + 8 + g];
        #pragma unroll
        for (int m = 0; m < 2; ++m) {
            f32x4 c = {0.f,0.f,0.f,0.f};
            c = MFMA(aow[m][0], wb0, c);
            c = MFMA(aow[m][1], wb1, c);
            c = MFMA(aow[m][2], wb2, c);
            s2[m][n] = c;
        }
    }
    float bov[3], g2v[3], b2v[3], f1bv[3], f2bv[3];
    #pragma unroll
    for (int n = 0; n < 3; ++n) {
        bov[n] = b_out[n*16+s]; g2v[n] = g2[n*16+s]; b2v[n] = b2[n*16+s];
        f1bv[n] = fb1[n*16+s];  f2bv[n] = fb2[n*16+s];
    }
    // keep raw seqT values for the fused Highpass
    float sv[2][3][4];
    #pragma unroll
    for (int m = 0; m < 2; ++m)
      #pragma unroll
      for (int n = 0; n < 3; ++n)
        #pragma unroll
        for (int r = 0; r < 4; ++r) {
          sv[m][n][r] = seqT[(size_t)(row0 + m*16 + g*4 + r)*48 + n*16 + s];
          s2[m][n][r] += sv[m][n][r] + bov[n];
        }

    // ---- LN2 -> yn -> LDS ----
    #pragma unroll
    for (int m = 0; m < 2; ++m)
      #pragma unroll
      for (int r = 0; r < 4; ++r) {
        float sm = s2[m][0][r] + s2[m][1][r] + s2[m][2][r];
        float sq = s2[m][0][r]*s2[m][0][r] + s2[m][1][r]*s2[m][1][r] + s2[m][2][r]*s2[m][2][r];
        #pragma unroll
        for (int msk = 1; msk < 16; msk <<= 1) { sm += __shfl_xor(sm, msk); sq += __shfl_xor(sq, msk); }
        float mean = sm * (1.f/48.f);
        float var  = sq * (1.f/48.f) - mean*mean;
        float rs   = rsqrtf(var + 1e-5f);
        int row = m*16 + g*4 + r;
        int sw  = ((g*4+r)&7) << 4;
        #pragma unroll
        for (int n = 0; n < 3; ++n) {
            float yn = (s2[m][n][r] - mean) * rs * g2v[n] + b2v[n];
            *(__bf16*)(xb + ((row*128 + (n*16+s)*2) ^ sw)) = (__bf16)yn;
        }
        *(__bf16*)(xb + ((row*128 + (48+s)*2) ^ sw)) = (__bf16)0.f;
      }

    bf16x8 af[2][2];
    f32x4 hh[2][3];

    // ---- ff1 ----
    #pragma unroll
    for (int m = 0; m < 2; ++m)
      #pragma unroll
      for (int kc = 0; kc < 2; ++kc)
        af[m][kc] = *(const bf16x8*)(xb + (((m*16+s)*128 + kc*64 + g*16) ^ ((s&7)<<4)));
    #pragma unroll
    for (int n = 0; n < 3; ++n) {
        bf16x8 wb0 = F14[(n*16+s)*8 + g];
        bf16x8 wb1 = F14[(n*16+s)*8 + 4 + g];
        #pragma unroll
        for (int m = 0; m < 2; ++m) {
            f32x4 c = {0.f,0.f,0.f,0.f};
            c = MFMA(af[m][0], wb0, c);
            c = MFMA(af[m][1], wb1, c);
            hh[m][n] = c;
        }
    }
    #pragma unroll
    for (int m = 0; m < 2; ++m)
      #pragma unroll
      for (int r = 0; r < 4; ++r) {
        int row = m*16 + g*4 + r;
        int sw  = ((g*4+r)&7) << 4;
        #pragma unroll
        for (int n = 0; n < 3; ++n) {
            float v = hh[m][n][r] + f1bv[n];
            v = v >= 0.f ? v : 0.01f*v;
            *(__bf16*)(xb + ((row*128 + (n*16+s)*2) ^ sw)) = (__bf16)v;
        }
        *(__bf16*)(xb + ((row*128 + (48+s)*2) ^ sw)) = (__bf16)0.f;
      }

    // ---- ff2 + residual -> a1 -> LDS; Highpass values -> hp staging ----
    #pragma unroll
    for (int m = 0; m < 2; ++m)
      #pragma unroll
      for (int kc = 0; kc < 2; ++kc)
        af[m][kc] = *(const bf16x8*)(xb + (((m*16+s)*128 + kc*64 + g*16) ^ ((s&7)<<4)));
    #pragma unroll
    for (int n = 0; n < 3; ++n) {
        bf16x8 wb0 = F24[(n*16+s)*8 + g];
        bf16x8 wb1 = F24[(n*16+s)*8 + 4 + g];
        #pragma unroll
        for (int m = 0; m < 2; ++m) {
            f32x4 c = {0.f,0.f,0.f,0.f};
            c = MFMA(af[m][0], wb0, c);
            c = MFMA(af[m][1], wb1, c);
            hh[m][n] = c;
        }
    }
    #pragma unroll
    for (int m = 0; m < 2; ++m)
      #pragma unroll
      for (int r = 0; r < 4; ++r) {
        int row = m*16 + g*4 + r;
        int sw  = ((g*4+r)&7) << 4;
        #pragma unroll
        for (int n = 0; n < 3; ++n) {
            float a1v = s2[m][n][r] + hh[m][n][r] + f2bv[n];
            hp[wv][row][n*16+s] = sv[m][n][r] * (1.f + a1v);
            *(__bf16*)(xb + ((row*128 + (n*16+s)*2) ^ sw)) = (__bf16)a1v;
        }
        *(__bf16*)(xb + ((row*128 + (48+s)*2) ^ sw)) = (__bf16)0.f;
      }

    // coalesced Highpass flush: out1[ch][nbase+row], 16B per lane
    #pragma unroll
    for (int it = 0; it < 6; ++it) {
        int flat = it*256 + lane*4;
        int ch = flat >> 5, row = flat & 31;
        float4 v = { hp[wv][row][ch], hp[wv][row+1][ch],
                     hp[wv][row+2][ch], hp[wv][row+3][ch] };
        *(float4*)&out1[((size_t)b*D_ + ch)*N_ + nbase + row] = v;
    }

    // ---- final linear 48 -> 96 ----
    #pragma unroll
    for (int m = 0; m < 2; ++m)
      #pragma unroll
      for (int kc = 0; kc < 2; ++kc)
        af[m][kc] = *(const bf16x8*)(xb + (((m*16+s)*128 + kc*64 + g*16) ^ ((s&7)<<4)));
    #pragma unroll
    for (int n = 0; n < 6; ++n) {
        bf16x8 wb0 = WF4[(n*16+s)*8 + g];
        bf16x8 wb1 = WF4[(n*16+s)*8 + 4 + g];
        float bfv = bfin[n*16+s];
        #pragma unroll
        for (int m = 0; m < 2; ++m) {
            f32x4 c = {0.f,0.f,0.f,0.f};
            c = MFMA(af[m][0], wb0, c);
            c = MFMA(af[m][1], wb1, c);
            #pragma unroll
            for (int r = 0; r < 4; ++r)
                out2[(size_t)(row0 + m*16 + g*4 + r)*96 + n*16 + s] = c[r] + bfv;
        }
    }
}

extern "C" void kernel_launch(void* const* d_in, const int* in_sizes, int n_in,
                              void* d_out, int out_size, void* d_ws, size_t ws_size,
                              hipStream_t stream) {
    const float* x      = (const float*)d_in[0];
    const float* conv_w = (const float*)d_in[1];
    const float* conv_b = (const float*)d_in[2];
    const float* prelu_a= (const float*)d_in[3];
    const float* ln1_g  = (const float*)d_in[4];
    const float* ln1_b  = (const float*)d_in[5];
    const float* w_qkv  = (const float*)d_in[6];
    const float* E_mat  = (const float*)d_in[7];
    const float* F_mat  = (const float*)d_in[8];
    const float* w_e    = (const float*)d_in[9];
    const float* b_e    = (const float*)d_in[10];
    const float* w_f    = (const float*)d_in[11];
    const float* b_f    = (const float*)d_in[12];
    const float* w_out  = (const float*)d_in[13];
    const float* b_out  = (const float*)d_in[14];
    const float* ln2_g  = (const float*)d_in[15];
    const float* ln2_b  = (const float*)d_in[16];
    const float* ff_w1  = (const float*)d_in[17];
    const float* ff_b1  = (const float*)d_in[18];
    const float* ff_w2  = (const float*)d_in[19];
    const float* ff_b2  = (const float*)d_in[20];
    const float* w_fin  = (const float*)d_in[21];
    const float* b_fin  = (const float*)d_in[22];

    float* ws = (float*)d_ws;
    float*  seqT = ws;                                   // 2,457,600 f32
    float*  diag = seqT + (size_t)B_*N_*D_;              // 144 f32
    __bf16* Qbf  = (__bf16*)(diag + 144);                // 192*800*32 bf16 (d-interleaved)
    __bf16* Kbf  = Qbf + (size_t)NWH_*WS_*32;            // 192*800*32 bf16 (row-permuted, d-interleaved)
    __bf16* Vt   = Kbf + (size_t)NWH_*WS_*32;            // 192*32*800 bf16
    __bf16* OW   = Vt + (size_t)NWH_*32*WS_;             // 51200*96 bf16 (phys col order)
    __bf16* wqB  = OW + (size_t)B_*N_*96;                // 288*64
    __bf16* woB  = wqB + 288*64;                         // 48*96
    __bf16* f1B  = woB + 48*96;                          // 48*64
    __bf16* f2B  = f1B + 48*64;                          // 48*64
    __bf16* wfB  = f2B + 48*64;                          // 96*64

    float* out1 = (float*)d_out;               // [B,D,H,W]
    float* out2 = out1 + (size_t)B_*D_*N_;     // [B,N,96]

    k_wprep<<<32, 256, 0, stream>>>(w_qkv, w_out, ff_w1, ff_w2, w_fin,
                                    E_mat, F_mat, w_e, b_e, w_f, b_f, diag,
                                    wqB, woB, f1B, f2B, wfB);
    k_conv<<<800, 256, 0, stream>>>(x, conv_w, conv_b, prelu_a, seqT);
    k_qkv<<<400, 256, 0, stream>>>(seqT, wqB, ln1_g, ln1_b, diag, Qbf, Kbf, Vt);
    k_attn<<<960, 256, 0, stream>>>(Qbf, Kbf, Vt, OW);
    k_tail<<<400, 256, 0, stream>>>(seqT, OW, woB, b_out, ln2_g, ln2_b,
                                    f1B, ff_b1, f2B, ff_b2, wfB, b_fin,
                                    out1, out2);
}

// Round 9
// 87.856 us; speedup vs baseline: 12.1237x; 1.0239x over previous
//
#include <hip/hip_runtime.h>
#include <hip/hip_bf16.h>

#define B_    2
#define CIN_  5
#define H_    160
#define W_    160
#define N_    25600        // H*W
#define D_    48
#define NW_   32
#define WS_   800
#define HEADS_ 3
#define DH_   24
#define INNER_ 72
#define NWH_  192          // B*NW*HEADS

typedef __bf16 bf16x8 __attribute__((ext_vector_type(8)));
typedef float  f32x4  __attribute__((ext_vector_type(4)));

#define MFMA(a,b,c) __builtin_amdgcn_mfma_f32_16x16x32_bf16((a),(b),(c),0,0,0)

__device__ __forceinline__ float fast_exp2(float x) {
#if __has_builtin(__builtin_amdgcn_exp2f)
    return __builtin_amdgcn_exp2f(x);
#else
    return exp2f(x);
#endif
}

__device__ __forceinline__ unsigned pack_bf16(float lo, float hi) {
    __bf16 l = (__bf16)lo, h = (__bf16)hi;
    unsigned short ul = __builtin_bit_cast(unsigned short, l);
    unsigned short uh = __builtin_bit_cast(unsigned short, h);
    return ((unsigned)uh << 16) | (unsigned)ul;
}

// ---------------- K0: weight prep -> padded/reordered bf16 (+ e/f diag) ----------------
// wqB: [9 groups (part,head)][32 rows: d = t*16+s, d>=24 zero][64 cols]
// woB: [48][96] with k-dim in OW phys order: p = h*32 + 2*s' + j <-> logical h*24 + j*16 + s'
__global__ __launch_bounds__(256) void k_wprep(const float* __restrict__ wqkv,
                                               const float* __restrict__ w_out,
                                               const float* __restrict__ fw1,
                                               const float* __restrict__ fw2,
                                               const float* __restrict__ wfin,
                                               const float* __restrict__ Em,
                                               const float* __restrict__ Fm,
                                               const float* __restrict__ we,
                                               const float* __restrict__ be,
                                               const float* __restrict__ wf,
                                               const float* __restrict__ bf,
                                               float* __restrict__ diag,
                                               __bf16* __restrict__ wqB,   // [288][64]
                                               __bf16* __restrict__ woB,   // [48][96]
                                               __bf16* __restrict__ f1B,   // [48][64]
                                               __bf16* __restrict__ f2B,   // [48][64]
                                               __bf16* __restrict__ wfB) { // [96][64]
    if (blockIdx.x == 0 && threadIdx.x < 72) {
        int tt = threadIdx.x;
        int h = tt / 24, d = tt % 24;
        float se = be[d], sf = bf[d];
        for (int w = 0; w < 30; ++w) {
            se += Em[(h*24+d)*30 + w] * we[d*30 + w];
            sf += Fm[(h*24+d)*30 + w] * wf[d*30 + w];
        }
        diag[tt]      = se;
        diag[72 + tt] = sf;
    }
    int t = blockIdx.x*256 + threadIdx.x, stride = gridDim.x*256;
    for (int i = t; i < 288*64; i += stride) {
        int grow = i>>6, c = i&63;
        int gg = grow>>5, q = grow&31, tt = q>>4, sp = q&15, d = tt*16+sp;
        int part = gg/3, head = gg%3;
        wqB[i] = (d<24 && c<48) ? (__bf16)wqkv[(head*72 + part*24 + d)*48 + c] : (__bf16)0.f;
    }
    for (int i = t; i < 48*96;  i += stride) {
        int o = i/96, p = i%96;
        int h = p>>5, q = p&31, j = q&1, sp = q>>1, d = j*16+sp;
        woB[i] = (d<24) ? (__bf16)w_out[o*72 + h*24 + d] : (__bf16)0.f;
    }
    for (int i = t; i < 48*64;  i += stride) { int o=i>>6, c=i&63; f1B[i] = (c<48)? (__bf16)fw1[o*48+c] : (__bf16)0.f; }
    for (int i = t; i < 48*64;  i += stride) { int o=i>>6, c=i&63; f2B[i] = (c<48)? (__bf16)fw2[o*48+c] : (__bf16)0.f; }
    for (int i = t; i < 96*64;  i += stride) { int o=i>>6, c=i&63; wfB[i] = (c<48)? (__bf16)wfin[o*48+c] : (__bf16)0.f; }
}

// ---------------- K1: fused conv3x3+PReLU + LN1 + QKV (block = 64 rows, 2 waves) ----------------
// Conv results live in LDS tile T; LN1/QKV consume them directly (no seqT read).
// seqT still written once for k_tail's residual/Highpass.
// Q/K cols d-interleaved: phys p = 2s+parity <-> logical d = parity*16+s.
// K rows permuted within chunk: (m,g,r) -> 16*(g&1)+8m+4*(g>>1)+r (attn PV A-frag layout).
// V written transposed (Vt[wh][32][800]; row 24 = ones, 25..31 = 0).
__global__ __launch_bounds__(128) void k_cqkv(const float* __restrict__ x,
                                              const float* __restrict__ cw,
                                              const float* __restrict__ cb,
                                              const float* __restrict__ pa,
                                              const __bf16* __restrict__ wqB,
                                              const float* __restrict__ g1,
                                              const float* __restrict__ b1,
                                              const float* __restrict__ diag,
                                              float* __restrict__ seqT,
                                              __bf16* __restrict__ Qbf,
                                              __bf16* __restrict__ Kbf,
                                              __bf16* __restrict__ Vt) {
    __shared__ float T[64][49];
    __shared__ float cwL[48*45];
    __shared__ float cbL[48];
    __shared__ __bf16 xfer[2][2048];           // per-wave 32x64 bf16, swizzled
    int t = threadIdx.x;                       // 0..127
    int blk = blockIdx.x;                      // 0..799
    int b = blk / 400;
    int n0 = (blk % 400) * 64;

    for (int f = t; f < 48*45; f += 128) cwL[f] = cw[f];
    if (t < 48) cbL[t] = cb[t];
    __syncthreads();

    // ---- conv phase: 2 threads per pixel (24 oc each) ----
    {
        int px = t & 63;
        int hf = t >> 6;
        int n  = n0 + px;
        int y  = n / W_, xx = n % W_;
        float a = pa[0];
        float patch[45];
        #pragma unroll
        for (int ic = 0; ic < 5; ++ic)
          #pragma unroll
          for (int ky = 0; ky < 3; ++ky)
            #pragma unroll
            for (int kx = 0; kx < 3; ++kx) {
                int yy = y + ky - 1, xc = xx + kx - 1;
                float v = 0.f;
                if (yy >= 0 && yy < H_ && xc >= 0 && xc < W_)
                    v = x[((size_t)(b*CIN_ + ic)*H_ + yy)*W_ + xc];
                patch[(ic*3+ky)*3+kx] = v;
            }
        for (int oi = 0; oi < 24; ++oi) {
            int oc = hf*24 + oi;
            float acc = cbL[oc];
            #pragma unroll
            for (int k = 0; k < 45; ++k) acc += patch[k] * cwL[oc*45 + k];
            acc = acc >= 0.f ? acc : a * acc;
            T[px][oc] = acc;
        }
    }
    __syncthreads();

    // ---- flush seqT (64*48 floats, 24/thread, coalesced) ----
    for (int i = 0; i < 24; ++i) {
        int f = t + i*128;
        int p = f / 48, c = f % 48;
        seqT[(size_t)(b*N_ + n0 + p)*D_ + c] = T[p][c];
    }

    // ---- LN1 + QKV phase (per wave: 32 rows) ----
    int wv = t >> 6, lane = t & 63, g = lane>>4, s = lane&15;
    int grow0 = blk*64 + wv*32;                // global linear row
    char* xb = (char*)&xfer[wv][0];
    int rloc0 = wv*32;

    int nrem = grow0 % N_;
    int w = nrem / WS_, i0 = nrem % WS_;       // 32 | 800: all rows same window
    size_t headbase = (size_t)((b*NW_ + w)*HEADS_);

    float xr[2][3][4];
    #pragma unroll
    for (int m = 0; m < 2; ++m)
      #pragma unroll
      for (int n = 0; n < 3; ++n)
        #pragma unroll
        for (int r = 0; r < 4; ++r)
          xr[m][n][r] = T[rloc0 + m*16 + g*4 + r][n*16 + s];

    float g1v[3], b1v[3];
    #pragma unroll
    for (int n = 0; n < 3; ++n) { g1v[n] = g1[n*16+s]; b1v[n] = b1[n*16+s]; }

    #pragma unroll
    for (int m = 0; m < 2; ++m)
      #pragma unroll
      for (int r = 0; r < 4; ++r) {
        float sm = xr[m][0][r] + xr[m][1][r] + xr[m][2][r];
        float sq = xr[m][0][r]*xr[m][0][r] + xr[m][1][r]*xr[m][1][r] + xr[m][2][r]*xr[m][2][r];
        #pragma unroll
        for (int msk = 1; msk < 16; msk <<= 1) { sm += __shfl_xor(sm, msk); sq += __shfl_xor(sq, msk); }
        float mean = sm * (1.f/48.f);
        float var  = sq * (1.f/48.f) - mean*mean;
        float rs   = rsqrtf(var + 1e-5f);
        int row = m*16 + g*4 + r;
        int sw  = ((g*4+r)&7) << 4;
        #pragma unroll
        for (int n = 0; n < 3; ++n) {
            float yn = (xr[m][n][r] - mean) * rs * g1v[n] + b1v[n];
            *(__bf16*)(xb + ((row*128 + (n*16+s)*2) ^ sw)) = (__bf16)yn;
        }
        *(__bf16*)(xb + ((row*128 + (48+s)*2) ^ sw)) = (__bf16)0.f;  // K-pad
      }

    bf16x8 af[2][2];
    #pragma unroll
    for (int m = 0; m < 2; ++m)
      #pragma unroll
      for (int kc = 0; kc < 2; ++kc)
        af[m][kc] = *(const bf16x8*)(xb + (((m*16+s)*128 + kc*64 + g*16) ^ ((s&7)<<4)));

    const bf16x8* WQ4 = (const bf16x8*)wqB;
    // 24^-0.5 * log2(e): fold attention scale AND exp2 conversion into Q
    const float SCALE = 0.2944889919f;

    float dke[3], dko[3], dve[3], dvo[3];
    #pragma unroll
    for (int h = 0; h < 3; ++h) {
        dke[h] = diag[h*24 + s];
        dko[h] = (s < 8) ? diag[h*24 + 16 + s] : 0.f;
        dve[h] = diag[72 + h*24 + s];
        dvo[h] = (s < 8) ? diag[72 + h*24 + 16 + s] : 0.f;
    }

    unsigned* Qd = (unsigned*)Qbf;
    unsigned* Kd = (unsigned*)Kbf;

    #pragma unroll
    for (int gg = 0; gg < 9; ++gg) {
        int part = gg / 3, head = gg % 3;
        bf16x8 we0 = WQ4[(gg*32 +      s)*8 +     g];
        bf16x8 we1 = WQ4[(gg*32 +      s)*8 + 4 + g];
        bf16x8 wo0 = WQ4[(gg*32 + 16 + s)*8 +     g];
        bf16x8 wo1 = WQ4[(gg*32 + 16 + s)*8 + 4 + g];
        f32x4 ce[2], co[2];
        #pragma unroll
        for (int m = 0; m < 2; ++m) {
            f32x4 c = {0.f,0.f,0.f,0.f};
            c = MFMA(af[m][0], we0, c); c = MFMA(af[m][1], we1, c);
            ce[m] = c;
            f32x4 d = {0.f,0.f,0.f,0.f};
            d = MFMA(af[m][0], wo0, d); d = MFMA(af[m][1], wo1, d);
            co[m] = d;
        }
        size_t rbase = (headbase + head)*WS_ + i0;
        if (part == 0) {
            #pragma unroll
            for (int m = 0; m < 2; ++m)
              #pragma unroll
              for (int r = 0; r < 4; ++r)
                Qd[(rbase + m*16 + g*4 + r)*16 + s] =
                    pack_bf16(ce[m][r]*SCALE, co[m][r]*SCALE);
        } else if (part == 1) {
            #pragma unroll
            for (int m = 0; m < 2; ++m)
              #pragma unroll
              for (int r = 0; r < 4; ++r) {
                int p5 = 16*(g&1) + 8*m + 4*(g>>1) + r;
                Kd[(rbase + p5)*16 + s] =
                    pack_bf16(ce[m][r]*dke[head], co[m][r]*dko[head]);
              }
        } else {
            size_t vbase = (headbase + head)*((size_t)32*WS_) + i0;
            #pragma unroll
            for (int m = 0; m < 2; ++m)
              #pragma unroll
              for (int r = 0; r < 4; ++r) {
                int row = m*16 + g*4 + r;
                Vt[vbase + (size_t)s*WS_ + row] = (__bf16)(ce[m][r]*dve[head]);
                if (s < 8)
                    Vt[vbase + (size_t)(16+s)*WS_ + row] = (__bf16)(co[m][r]*dvo[head]);
              }
        }
    }
    // Vt pad rows 24..31 (ones at 24), packed u32 — per wave: 3 heads x 8 rows x 16 pairs / 64 lanes
    unsigned* Vd = (unsigned*)Vt;
    #pragma unroll
    for (int it = 0; it < 6; ++it) {
        int idx = it*64 + lane;           // 0..383
        int h = idx >> 7, rem = idx & 127;
        int dd = 24 + (rem >> 4), cp = rem & 15;
        size_t ubase = (((headbase + h)*((size_t)32*WS_) + (size_t)dd*WS_ + i0) >> 1);
        Vd[ubase + cp] = (dd == 24) ? 0x3F803F80u : 0u;
    }
}

// ---------------- K3: MFMA attention, register-resident P, split-K wave pairs ----------------
__global__ __launch_bounds__(256, 4) void k_attn(const __bf16* __restrict__ Qbf,
                                                 const __bf16* __restrict__ Kbf,
                                                 const __bf16* __restrict__ Vt,
                                                 __bf16* __restrict__ OW) {
    __shared__ float red[2][5][2][4][64];      // 20 KB
    int t = threadIdx.x;
    int wv = t >> 6, lane = t & 63;
    int g = lane >> 4, s = lane & 15;
    int half = wv & 1, tsk = wv >> 1;
    int task = blockIdx.x * 2 + tsk;           // 0..1919 exactly
    int wh = task / 10, qt = task % 10;
    int q0 = qt * 80;

    const bf16x8* Qp = (const bf16x8*)(Qbf + ((size_t)wh*WS_ + q0)*32);
    const bf16x8* Kp = (const bf16x8*)(Kbf + (size_t)wh*WS_*32);
    const bf16x8* Vp = (const bf16x8*)(Vt  + (size_t)wh*32*WS_);

    // Q as B-operand: col = query = lane&15
    bf16x8 qb[5];
    #pragma unroll
    for (int i = 0; i < 5; ++i) qb[i] = Qp[(i*16 + s)*4 + g];

    f32x4 o[5][2];
    #pragma unroll
    for (int i = 0; i < 5; ++i) {
        o[i][0] = (f32x4){0.f,0.f,0.f,0.f};
        o[i][1] = (f32x4){0.f,0.f,0.f,0.f};
    }

    // combining wave (half 0) gets one chunk less: 12 vs 13
    int c0 = half ? 12 : 0;
    int c1 = half ? 25 : 12;

    // prefetch first chunk
    bf16x8 ka0 = Kp[(c0*32 + s)*4 + g];
    bf16x8 ka1 = Kp[(c0*32 + 16 + s)*4 + g];
    bf16x8 vb0 = Vp[s*100 + c0*4 + g];
    bf16x8 vb1 = Vp[(16+s)*100 + c0*4 + g];

    for (int c = c0; c < c1; ++c) {
        int cn = (c + 1 < c1) ? c + 1 : c0;    // last-iter reload is harmless
        bf16x8 nk0 = Kp[(cn*32 + s)*4 + g];
        bf16x8 nk1 = Kp[(cn*32 + 16 + s)*4 + g];
        bf16x8 nv0 = Vp[s*100 + cn*4 + g];
        bf16x8 nv1 = Vp[(16+s)*100 + cn*4 + g];

        #pragma unroll
        for (int i = 0; i < 5; ++i) {
            f32x4 s0 = {0.f,0.f,0.f,0.f}, s1 = {0.f,0.f,0.f,0.f};
            s0 = MFMA(ka0, qb[i], s0);         // C[m=T0 row 4g+r][n=query s]
            s1 = MFMA(ka1, qb[i], s1);         // C[m=T1 row 4g+r][n=query s]
            bf16x8 pa;
            #pragma unroll
            for (int r = 0; r < 4; ++r) {
                pa[r]     = (__bf16)fast_exp2(s0[r]);
                pa[r + 4] = (__bf16)fast_exp2(s1[r]);
            }
            o[i][0] = MFMA(pa, vb0, o[i][0]);  // O[q=4g+r][d=s]
            o[i][1] = MFMA(pa, vb1, o[i][1]);  // d=16+s (row 24 ones -> denom at s=8)
        }
        ka0 = nk0; ka1 = nk1; vb0 = nv0; vb1 = nv1;
    }

    // combine halves through LDS
    if (half) {
        #pragma unroll
        for (int i = 0; i < 5; ++i)
          #pragma unroll
          for (int j = 0; j < 2; ++j)
            #pragma unroll
            for (int r = 0; r < 4; ++r)
              red[tsk][i][j][r][lane] = o[i][j][r];
    }
    __syncthreads();
    if (!half) {
        #pragma unroll
        for (int i = 0; i < 5; ++i)
          #pragma unroll
          for (int j = 0; j < 2; ++j)
            #pragma unroll
            for (int r = 0; r < 4; ++r)
              o[i][j][r] += red[tsk][i][j][r][lane];

        int bw = wh / 3, h = wh % 3;
        int b = bw >> 5, w = bw & 31;
        unsigned* OWd = (unsigned*)OW;
        #pragma unroll
        for (int i = 0; i < 5; ++i) {
            #pragma unroll
            for (int r = 0; r < 4; ++r) {
                float den = __shfl(o[i][1][r], (lane & 48) + 8);   // ones-column
                float inv = 1.f / den;
                int n = w*WS_ + q0 + i*16 + g*4 + r;
                // OW phys col pair (h*32 + 2s, +1); den slot lands on zero woB row
                OWd[(size_t)(b*N_ + n)*48 + h*16 + s] =
                    pack_bf16(o[i][0][r]*inv, o[i][1][r]*inv);
            }
        }
    }
}

// ---------------- K4: MFMA tail + fused Highpass (wave = 32 rows) ----------------
__global__ __launch_bounds__(256) void k_tail(const float* __restrict__ seqT,
                                              const __bf16* __restrict__ OW,
                                              const __bf16* __restrict__ woB,
                                              const float* __restrict__ b_out,
                                              const float* __restrict__ g2,
                                              const float* __restrict__ b2,
                                              const __bf16* __restrict__ f1B,
                                              const float* __restrict__ fb1,
                                              const __bf16* __restrict__ f2B,
                                              const float* __restrict__ fb2,
                                              const __bf16* __restrict__ wfB,
                                              const float* __restrict__ bfin,
                                              float* __restrict__ out1,
                                              float* __restrict__ out2) {
    __shared__ __bf16 xfer[4][2048];
    __shared__ float hp[4][32][49];            // Highpass staging, padded stride
    int t = threadIdx.x, wv = t>>6, lane = t&63, g = lane>>4, s = lane&15;
    int row0 = (blockIdx.x*4 + wv) * 32;
    char* xb = (char*)&xfer[wv][0];

    int b = row0 / N_;
    int nbase = row0 % N_;

    const bf16x8* OW4 = (const bf16x8*)OW;
    const bf16x8* WO4 = (const bf16x8*)woB;
    const bf16x8* F14 = (const bf16x8*)f1B;
    const bf16x8* F24 = (const bf16x8*)f2B;
    const bf16x8* WF4 = (const bf16x8*)wfB;

    // ---- S1: att = ow · w_out^T (k-dim in OW phys order) ----
    bf16x8 aow[2][3];
    #pragma unroll
    for (int m = 0; m < 2; ++m)
      #pragma unroll
      for (int kc = 0; kc < 3; ++kc)
        aow[m][kc] = OW4[(size_t)(row0 + m*16 + s)*12 + kc*4 + g];

    f32x4 s2[2][3];
    #pragma unroll
    for (int n = 0; n < 3; ++n) {
        bf16x8 wb0 = WO4[(n*16+s)*12 + g];
        bf16x8 wb1 = WO4[(n*16+s)*12 + 4 + g];
        bf16x8 wb2 = WO4[(n*16+s)*12 + 8 + g];
        #pragma unroll
        for (int m = 0; m < 2; ++m) {
            f32x4 c = {0.f,0.f,0.f,0.f};
            c = MFMA(aow[m][0], wb0, c);
            c = MFMA(aow[m][1], wb1, c);
            c = MFMA(aow[m][2], wb2, c);
            s2[m][n] = c;
        }
    }
    float bov[3], g2v[3], b2v[3], f1bv[3], f2bv[3];
    #pragma unroll
    for (int n = 0; n < 3; ++n) {
        bov[n] = b_out[n*16+s]; g2v[n] = g2[n*16+s]; b2v[n] = b2[n*16+s];
        f1bv[n] = fb1[n*16+s];  f2bv[n] = fb2[n*16+s];
    }
    // keep raw seqT values for the fused Highpass
    float sv[2][3][4];
    #pragma unroll
    for (int m = 0; m < 2; ++m)
      #pragma unroll
      for (int n = 0; n < 3; ++n)
        #pragma unroll
        for (int r = 0; r < 4; ++r) {
          sv[m][n][r] = seqT[(size_t)(row0 + m*16 + g*4 + r)*48 + n*16 + s];
          s2[m][n][r] += sv[m][n][r] + bov[n];
        }

    // ---- LN2 -> yn -> LDS ----
    #pragma unroll
    for (int m = 0; m < 2; ++m)
      #pragma unroll
      for (int r = 0; r < 4; ++r) {
        float sm = s2[m][0][r] + s2[m][1][r] + s2[m][2][r];
        float sq = s2[m][0][r]*s2[m][0][r] + s2[m][1][r]*s2[m][1][r] + s2[m][2][r]*s2[m][2][r];
        #pragma unroll
        for (int msk = 1; msk < 16; msk <<= 1) { sm += __shfl_xor(sm, msk); sq += __shfl_xor(sq, msk); }
        float mean = sm * (1.f/48.f);
        float var  = sq * (1.f/48.f) - mean*mean;
        float rs   = rsqrtf(var + 1e-5f);
        int row = m*16 + g*4 + r;
        int sw  = ((g*4+r)&7) << 4;
        #pragma unroll
        for (int n = 0; n < 3; ++n) {
            float yn = (s2[m][n][r] - mean) * rs * g2v[n] + b2v[n];
            *(__bf16*)(xb + ((row*128 + (n*16+s)*2) ^ sw)) = (__bf16)yn;
        }
        *(__bf16*)(xb + ((row*128 + (48+s)*2) ^ sw)) = (__bf16)0.f;
      }

    bf16x8 af[2][2];
    f32x4 hh[2][3];

    // ---- ff1 ----
    #pragma unroll
    for (int m = 0; m < 2; ++m)
      #pragma unroll
      for (int kc = 0; kc < 2; ++kc)
        af[m][kc] = *(const bf16x8*)(xb + (((m*16+s)*128 + kc*64 + g*16) ^ ((s&7)<<4)));
    #pragma unroll
    for (int n = 0; n < 3; ++n) {
        bf16x8 wb0 = F14[(n*16+s)*8 + g];
        bf16x8 wb1 = F14[(n*16+s)*8 + 4 + g];
        #pragma unroll
        for (int m = 0; m < 2; ++m) {
            f32x4 c = {0.f,0.f,0.f,0.f};
            c = MFMA(af[m][0], wb0, c);
            c = MFMA(af[m][1], wb1, c);
            hh[m][n] = c;
        }
    }
    #pragma unroll
    for (int m = 0; m < 2; ++m)
      #pragma unroll
      for (int r = 0; r < 4; ++r) {
        int row = m*16 + g*4 + r;
        int sw  = ((g*4+r)&7) << 4;
        #pragma unroll
        for (int n = 0; n < 3; ++n) {
            float v = hh[m][n][r] + f1bv[n];
            v = v >= 0.f ? v : 0.01f*v;
            *(__bf16*)(xb + ((row*128 + (n*16+s)*2) ^ sw)) = (__bf16)v;
        }
        *(__bf16*)(xb + ((row*128 + (48+s)*2) ^ sw)) = (__bf16)0.f;
      }

    // ---- ff2 + residual -> a1 -> LDS; Highpass values -> hp staging ----
    #pragma unroll
    for (int m = 0; m < 2; ++m)
      #pragma unroll
      for (int kc = 0; kc < 2; ++kc)
        af[m][kc] = *(const bf16x8*)(xb + (((m*16+s)*128 + kc*64 + g*16) ^ ((s&7)<<4)));
    #pragma unroll
    for (int n = 0; n < 3; ++n) {
        bf16x8 wb0 = F24[(n*16+s)*8 + g];
        bf16x8 wb1 = F24[(n*16+s)*8 + 4 + g];
        #pragma unroll
        for (int m = 0; m < 2; ++m) {
            f32x4 c = {0.f,0.f,0.f,0.f};
            c = MFMA(af[m][0], wb0, c);
            c = MFMA(af[m][1], wb1, c);
            hh[m][n] = c;
        }
    }
    #pragma unroll
    for (int m = 0; m < 2; ++m)
      #pragma unroll
      for (int r = 0; r < 4; ++r) {
        int row = m*16 + g*4 + r;
        int sw  = ((g*4+r)&7) << 4;
        #pragma unroll
        for (int n = 0; n < 3; ++n) {
            float a1v = s2[m][n][r] + hh[m][n][r] + f2bv[n];
            hp[wv][row][n*16+s] = sv[m][n][r] * (1.f + a1v);
            *(__bf16*)(xb + ((row*128 + (n*16+s)*2) ^ sw)) = (__bf16)a1v;
        }
        *(__bf16*)(xb + ((row*128 + (48+s)*2) ^ sw)) = (__bf16)0.f;
      }

    // coalesced Highpass flush: out1[ch][nbase+row], 16B per lane
    #pragma unroll
    for (int it = 0; it < 6; ++it) {
        int flat = it*256 + lane*4;
        int ch = flat >> 5, row = flat & 31;
        float4 v = { hp[wv][row][ch], hp[wv][row+1][ch],
                     hp[wv][row+2][ch], hp[wv][row+3][ch] };
        *(float4*)&out1[((size_t)b*D_ + ch)*N_ + nbase + row] = v;
    }

    // ---- final linear 48 -> 96 ----
    #pragma unroll
    for (int m = 0; m < 2; ++m)
      #pragma unroll
      for (int kc = 0; kc < 2; ++kc)
        af[m][kc] = *(const bf16x8*)(xb + (((m*16+s)*128 + kc*64 + g*16) ^ ((s&7)<<4)));
    #pragma unroll
    for (int n = 0; n < 6; ++n) {
        bf16x8 wb0 = WF4[(n*16+s)*8 + g];
        bf16x8 wb1 = WF4[(n*16+s)*8 + 4 + g];
        float bfv = bfin[n*16+s];
        #pragma unroll
        for (int m = 0; m < 2; ++m) {
            f32x4 c = {0.f,0.f,0.f,0.f};
            c = MFMA(af[m][0], wb0, c);
            c = MFMA(af[m][1], wb1, c);
            #pragma unroll
            for (int r = 0; r < 4; ++r)
                out2[(size_t)(row0 + m*16 + g*4 + r)*96 + n*16 + s] = c[r] + bfv;
        }
    }
}

extern "C" void kernel_launch(void* const* d_in, const int* in_sizes, int n_in,
                              void* d_out, int out_size, void* d_ws, size_t ws_size,
                              hipStream_t stream) {
    const float* x      = (const float*)d_in[0];
    const float* conv_w = (const float*)d_in[1];
    const float* conv_b = (const float*)d_in[2];
    const float* prelu_a= (const float*)d_in[3];
    const float* ln1_g  = (const float*)d_in[4];
    const float* ln1_b  = (const float*)d_in[5];
    const float* w_qkv  = (const float*)d_in[6];
    const float* E_mat  = (const float*)d_in[7];
    const float* F_mat  = (const float*)d_in[8];
    const float* w_e    = (const float*)d_in[9];
    const float* b_e    = (const float*)d_in[10];
    const float* w_f    = (const float*)d_in[11];
    const float* b_f    = (const float*)d_in[12];
    const float* w_out  = (const float*)d_in[13];
    const float* b_out  = (const float*)d_in[14];
    const float* ln2_g  = (const float*)d_in[15];
    const float* ln2_b  = (const float*)d_in[16];
    const float* ff_w1  = (const float*)d_in[17];
    const float* ff_b1  = (const float*)d_in[18];
    const float* ff_w2  = (const float*)d_in[19];
    const float* ff_b2  = (const float*)d_in[20];
    const float* w_fin  = (const float*)d_in[21];
    const float* b_fin  = (const float*)d_in[22];

    float* ws = (float*)d_ws;
    float*  seqT = ws;                                   // 2,457,600 f32
    float*  diag = seqT + (size_t)B_*N_*D_;              // 144 f32
    __bf16* Qbf  = (__bf16*)(diag + 144);                // 192*800*32 bf16 (d-interleaved)
    __bf16* Kbf  = Qbf + (size_t)NWH_*WS_*32;            // 192*800*32 bf16 (row-permuted, d-interleaved)
    __bf16* Vt   = Kbf + (size_t)NWH_*WS_*32;            // 192*32*800 bf16
    __bf16* OW   = Vt + (size_t)NWH_*32*WS_;             // 51200*96 bf16 (phys col order)
    __bf16* wqB  = OW + (size_t)B_*N_*96;                // 288*64
    __bf16* woB  = wqB + 288*64;                         // 48*96
    __bf16* f1B  = woB + 48*96;                          // 48*64
    __bf16* f2B  = f1B + 48*64;                          // 48*64
    __bf16* wfB  = f2B + 48*64;                          // 96*64

    float* out1 = (float*)d_out;               // [B,D,H,W]
    float* out2 = out1 + (size_t)B_*D_*N_;     // [B,N,96]

    k_wprep<<<32, 256, 0, stream>>>(w_qkv, w_out, ff_w1, ff_w2, w_fin,
                                    E_mat, F_mat, w_e, b_e, w_f, b_f, diag,
                                    wqB, woB, f1B, f2B, wfB);
    k_cqkv<<<800, 128, 0, stream>>>(x, conv_w, conv_b, prelu_a,
                                    wqB, ln1_g, ln1_b, diag, seqT, Qbf, Kbf, Vt);
    k_attn<<<960, 256, 0, stream>>>(Qbf, Kbf, Vt, OW);
    k_tail<<<400, 256, 0, stream>>>(seqT, OW, woB, b_out, ln2_g, ln2_b,
                                    f1B, ff_b1, f2B, ff_b2, wfB, b_fin,
                                    out1, out2);
}